// Round 2
// baseline (322.511 us; speedup 1.0000x reference)
//
#include <hip/hip_runtime.h>
#include <math.h>

typedef short bf16x8 __attribute__((ext_vector_type(8)));
typedef float f32x4 __attribute__((ext_vector_type(4)));
typedef unsigned int u32x2 __attribute__((ext_vector_type(2)));
typedef unsigned int u32x4 __attribute__((ext_vector_type(4)));

#define MFMA_BF16(A,B,C) __builtin_amdgcn_mfma_f32_16x16x32_bf16(A,B,C,0,0,0)

__device__ __forceinline__ unsigned short f2b(float x) {
    union { float f; unsigned int u; } v; v.f = x;
    unsigned int r = v.u + 0x7FFFu + ((v.u >> 16) & 1u);
    return (unsigned short)(r >> 16);
}

// packed f32x2 -> bf16x2 (RNE), single instruction
__device__ __forceinline__ unsigned int cvtpk(float lo, float hi) {
    unsigned int r;
    asm("v_cvt_pk_bf16_f32 %0, %1, %2" : "=v"(r) : "v"(lo), "v"(hi));
    return r;
}

// async global->LDS DMA, 16B per lane; LDS dest = wave-uniform base + lane*16
__device__ __forceinline__ void gload16(const unsigned short* g, unsigned short* l) {
    __builtin_amdgcn_global_load_lds(
        (const __attribute__((address_space(1))) unsigned int*)(g),
        (__attribute__((address_space(3))) unsigned int*)(l),
        16, 0, 0);
}
// 4B per lane variant; LDS dest = base + lane*4
__device__ __forceinline__ void gload4(const int* g, int* l) {
    __builtin_amdgcn_global_load_lds(
        (const __attribute__((address_space(1))) unsigned int*)(g),
        (__attribute__((address_space(3))) unsigned int*)(l),
        4, 0, 0);
}

// ---------------------------------------------------------------------------
// fp32 -> bf16 convert (flat)
// ---------------------------------------------------------------------------
__global__ __launch_bounds__(256) void conv_bf16(const float* __restrict__ s,
                                                 unsigned short* __restrict__ d, int n)
{
    int i = blockIdx.x * blockDim.x + threadIdx.x;
    int stride = gridDim.x * blockDim.x;
    for (int idx = i * 4; idx < n; idx += stride * 4) {
        float4 v = *(const float4*)(s + idx);
        ushort4 o;
        o.x = f2b(v.x); o.y = f2b(v.y); o.z = f2b(v.z); o.w = f2b(v.w);
        *(ushort4*)(d + idx) = o;
    }
}

// ---------------------------------------------------------------------------
// Fused weight transpose+convert: Wq|Wk|Wv (fp32, [2048][C]) -> bf16 [C][2048]
// ---------------------------------------------------------------------------
__global__ __launch_bounds__(256) void transp_conv_qkv(const float* __restrict__ Wq,
                                                       const float* __restrict__ Wk,
                                                       const float* __restrict__ Wv,
                                                       unsigned short* __restrict__ dst)
{
    __shared__ float t[32][33];
    const int tx = threadIdx.x, ty = threadIdx.y;   // (32,8)
    int bx = blockIdx.x;
    const float* src; int C, cb, dco;
    if (bx < 32)      { src = Wq; C = 1024; cb = bx;      dco = 0; }
    else if (bx < 40) { src = Wk; C = 256;  cb = bx - 32; dco = 1024; }
    else              { src = Wv; C = 256;  cb = bx - 40; dco = 1280; }
    const int c = cb * 32 + tx;
    const int r0 = blockIdx.y * 32;
#pragma unroll
    for (int i = 0; i < 4; ++i)
        t[ty + i * 8][tx] = src[(size_t)(r0 + ty + i * 8) * C + c];
    __syncthreads();
    const int cc = cb * 32 + ty;
#pragma unroll
    for (int i = 0; i < 4; ++i)
        dst[(size_t)(dco + cc + i * 8) * 2048 + r0 + tx] = f2b(t[tx][ty + i * 8]);
}

__global__ __launch_bounds__(256) void transp_conv(const float* __restrict__ src, int R, int C,
                                                   unsigned short* __restrict__ dst, int pitch)
{
    __shared__ float t[32][33];
    const int tx = threadIdx.x, ty = threadIdx.y;
    const int c = blockIdx.x * 32 + tx;
    const int r0 = blockIdx.y * 32;
#pragma unroll
    for (int i = 0; i < 4; ++i)
        t[ty + i * 8][tx] = src[(size_t)(r0 + ty + i * 8) * C + c];
    __syncthreads();
    const int cc = blockIdx.x * 32 + ty;
#pragma unroll
    for (int i = 0; i < 4; ++i)
        dst[(size_t)(cc + i * 8) * pitch + r0 + tx] = f2b(t[tx][ty + i * 8]);
}

// ---------------------------------------------------------------------------
// bf16 MFMA GEMM, B^T input: C[M][N] = A[M][K] @ Bt[N][K]^T
// BM=128, BN=64, BK=64; 256 threads (4 waves, 2x2); double-buffered
// global_load_lds staging.
// DMA source lanes re-mapped (row=lane&15, col=(lane>>4)*8) so every fragment
// ds_read_b128 lands at base + lane*16B -> lane-linear, bank-conflict-free.
// ---------------------------------------------------------------------------
template <int MODE>
__global__ __launch_bounds__(256, 3) void gemm_bt_mfma(
    const unsigned short* __restrict__ A,
    const unsigned short* __restrict__ Bt,
    int M, int N, int K,
    float* __restrict__ Cf,
    unsigned short* __restrict__ qh,
    unsigned short* __restrict__ kh,
    unsigned short* __restrict__ vtt)
{
    __shared__ __align__(16) unsigned short As[2][2 * 128 * 32];
    __shared__ __align__(16) unsigned short Bs[2][2 * 64 * 32];

    const int tid = threadIdx.x;
    const int w = tid >> 6, lane = tid & 63, l15 = lane & 15, quad = lane >> 4;
    const int wm = w & 1, wn = w >> 1;
    const int m0 = blockIdx.y * 128, n0 = blockIdx.x * 64;

    f32x4 acc[4][2];
    const f32x4 zero4 = {0.f, 0.f, 0.f, 0.f};
#pragma unroll
    for (int i = 0; i < 4; ++i)
#pragma unroll
        for (int j = 0; j < 2; ++j) acc[i][j] = zero4;

    // DMA lane geometry matched to fragment reads: row = lane&15, col = (lane>>4)*8
    const unsigned short* AgL = A  + (size_t)(m0 + w * 32 + l15) * K + quad * 8;
    const unsigned short* BgL = Bt + (size_t)(n0 + w * 16 + l15) * K + quad * 8;

#pragma unroll
    for (int t = 0; t < 4; ++t) {
        const int sub = t >> 1, half = t & 1;
        gload16(AgL + (size_t)(half * 16) * K + sub * 32,
                &As[0][sub * 4096 + (w * 2 + half) * 512]);
    }
#pragma unroll
    for (int kk = 0; kk < 2; ++kk)
        gload16(BgL + kk * 32, &Bs[0][kk * 2048 + w * 512]);
    __syncthreads();

    int cb = 0;
    for (int k0 = 0; k0 < K; k0 += 64) {
        if (k0 + 64 < K) {
            const int nb = cb ^ 1;
#pragma unroll
            for (int t = 0; t < 4; ++t) {
                const int sub = t >> 1, half = t & 1;
                gload16(AgL + (size_t)(half * 16) * K + (k0 + 64) + sub * 32,
                        &As[nb][sub * 4096 + (w * 2 + half) * 512]);
            }
#pragma unroll
            for (int kk = 0; kk < 2; ++kk)
                gload16(BgL + (k0 + 64) + kk * 32, &Bs[nb][kk * 2048 + w * 512]);
        }

        bf16x8 af[4][2], bf[2][2];
#pragma unroll
        for (int kk = 0; kk < 2; ++kk) {
#pragma unroll
            for (int mt = 0; mt < 4; ++mt)
                af[mt][kk] = *(const bf16x8*)&As[cb][kk * 4096 + (wm * 4 + mt) * 512 + lane * 8];
#pragma unroll
            for (int nt = 0; nt < 2; ++nt)
                bf[nt][kk] = *(const bf16x8*)&Bs[cb][kk * 2048 + (wn * 2 + nt) * 512 + lane * 8];
        }
#pragma unroll
        for (int kk = 0; kk < 2; ++kk)
#pragma unroll
            for (int mt = 0; mt < 4; ++mt)
#pragma unroll
                for (int nt = 0; nt < 2; ++nt)
                    acc[mt][nt] = MFMA_BF16(af[mt][kk], bf[nt][kk], acc[mt][nt]);

        __syncthreads();
        cb ^= 1;
    }

    if (MODE == 0) {
#pragma unroll
        for (int mt = 0; mt < 4; ++mt)
#pragma unroll
            for (int nt = 0; nt < 2; ++nt) {
                const int gn = n0 + wn * 32 + nt * 16 + l15;
#pragma unroll
                for (int r = 0; r < 4; ++r) {
                    const int gm = m0 + wm * 64 + mt * 16 + quad * 4 + r;
                    Cf[(size_t)gm * N + gn] = acc[mt][nt][r];
                }
            }
    } else {
        if (n0 < 1024) {            // Q: tanh -> qh[m][n], pitch 1024
#pragma unroll
            for (int mt = 0; mt < 4; ++mt)
#pragma unroll
                for (int nt = 0; nt < 2; ++nt) {
                    const int gn = n0 + wn * 32 + nt * 16 + l15;
#pragma unroll
                    for (int r = 0; r < 4; ++r) {
                        const int gm = m0 + wm * 64 + mt * 16 + quad * 4 + r;
                        qh[(size_t)gm * 1024 + gn] = f2b(tanhf(acc[mt][nt][r]));
                    }
                }
        } else if (n0 < 1280) {     // K: tanh -> kh[m][n-1024], pitch 256
#pragma unroll
            for (int mt = 0; mt < 4; ++mt)
#pragma unroll
                for (int nt = 0; nt < 2; ++nt) {
                    const int gn = n0 + wn * 32 + nt * 16 + l15 - 1024;
#pragma unroll
                    for (int r = 0; r < 4; ++r) {
                        const int gm = m0 + wm * 64 + mt * 16 + quad * 4 + r;
                        kh[(size_t)gm * 256 + gn] = f2b(tanhf(acc[mt][nt][r]));
                    }
                }
        } else {                    // V: sigmoid -> vtt[(b*4+g)*64+v][s]
#pragma unroll
            for (int mt = 0; mt < 4; ++mt)
#pragma unroll
                for (int nt = 0; nt < 2; ++nt) {
                    const int gn = n0 + wn * 32 + nt * 16 + l15 - 1280;
                    const int g = gn >> 6, vv = gn & 63;
                    const int s0 = m0 + wm * 64 + mt * 16 + quad * 4;
                    const int b = s0 >> 11, sl = s0 & 2047;
                    ushort4 pk;
                    unsigned short* pp = (unsigned short*)&pk;
#pragma unroll
                    for (int r = 0; r < 4; ++r) {
                        float sv = 1.0f / (1.0f + __expf(-acc[mt][nt][r]));
                        pp[r] = f2b(sv);
                    }
                    *(ushort4*)&vtt[((size_t)(b * 4 + g) * 64 + vv) * 2048 + sl] = pk;
                }
        }
    }
}

// ---------------------------------------------------------------------------
// MFMA flash attention.
// One q-tile per block (grid 32x16x2 = 1024 blocks, heavy tiles first) ->
// 3 blocks/CU; lane-linear K/V LDS (DMA source lanes pre-permuted so fragment
// ds_read_b128 is base + lane*16B, conflict-free); cvt_pk P-packing.
// Ps is uint-typed end-to-end (stores u32x2, loads u32x4 + bit_cast) so the
// compiler sees the write->read dependence (TBAA!) and cannot hoist the reads.
// One barrier/tile. Fixed-max softmax (|s|<1).
// ---------------------------------------------------------------------------
__global__ __launch_bounds__(256, 3) void rosa_attn_mfma(
    const unsigned short* __restrict__ qh,
    const unsigned short* __restrict__ kh,
    const unsigned short* __restrict__ vtt,
    const int* __restrict__ amask,
    const float* __restrict__ emb0,
    const float* __restrict__ emb1,
    unsigned short* __restrict__ ob)
{
    __shared__ __align__(16) unsigned short Ks[2][2][2048];  // [buf][kk][group*512 + lane*8]
    __shared__ __align__(16) unsigned short Vs[2][2][2048];
    __shared__ __align__(16) unsigned int   Ps[4][16][36];   // [wave][q][j/2] (uint-typed!)
    __shared__ int Mski[2][64];

    const int qt = 31 - blockIdx.x;               // heavy blocks dispatch first
    const int h = blockIdx.y, b = blockIdx.z, g = h >> 2;
    const int tid = threadIdx.x;
    const int w = tid >> 6, lane = tid & 63, l15 = lane & 15, quad = lane >> 4;

    // DMA lane geometry matched to fragment reads: row = lane&15, col = (lane>>4)*8
    const unsigned short* kst = kh + (size_t)b * 2048 * 256 + g * 64
                               + (size_t)(w * 16 + l15) * 256 + quad * 8;    // + k0*256 + kk*32
    const unsigned short* vst = vtt + ((size_t)(b * 4 + g) * 64 + w * 16 + l15) * 2048
                               + quad * 8;                                   // + k0 + kk*32
    const int* mbase = amask + b * 2048;

    const f32x4 zero4 = {0.f, 0.f, 0.f, 0.f};
    const float cexp = 0.0225421100f;             // log2(e)/64

#define STAGE_TILE(k0s, buf)                                               \
    {                                                                      \
        gload16(kst + (size_t)(k0s) * 256,      &Ks[buf][0][w * 512]);     \
        gload16(kst + (size_t)(k0s) * 256 + 32, &Ks[buf][1][w * 512]);     \
        gload16(vst + (k0s),                    &Vs[buf][0][w * 512]);     \
        gload16(vst + (k0s) + 32,               &Vs[buf][1][w * 512]);     \
        if (w == 0) gload4(mbase + (k0s) + lane, &Mski[buf][0]);           \
    }

    const int q0 = qt * 64;
    const int nkt = qt + 1;
    const int qg = q0 + w * 16 + l15;

    // Q B-fragment (n = q = l15, k = d), per wave, from global (L2-hot)
    const unsigned short* qrow = qh + ((size_t)(b * 2048 + qg) * 16 + h) * 64;
    const bf16x8 qf0 = *(const bf16x8*)(qrow + quad * 8);
    const bf16x8 qf1 = *(const bf16x8*)(qrow + 32 + quad * 8);

    f32x4 oacc[4];
#pragma unroll
    for (int t = 0; t < 4; ++t) oacc[t] = zero4;
    float psum = 0.0f;

    STAGE_TILE(0, 0)
    __syncthreads();               // vmcnt(0) drain: tile 0 visible

    int cb = 0;
    for (int kt = 0; kt < nkt; ++kt) {
        if (kt + 1 < nkt) STAGE_TILE((kt + 1) * 64, cb ^ 1)

        const bool diag = (kt == qt);
        const int ntlim = diag ? (w + 1) : 4;

        // S^T = K.Q^T per 16x16 sub-tile; fixed-max softmax; pack P^T
#pragma unroll
        for (int nt = 0; nt < 4; ++nt) {
            u32x2 pk2;
            if (nt < ntlim) {
                bf16x8 kf0 = *(const bf16x8*)&Ks[cb][0][nt * 512 + lane * 8];
                bf16x8 kf1 = *(const bf16x8*)&Ks[cb][1][nt * 512 + lane * 8];
                f32x4 sc = MFMA_BF16(kf0, qf0, zero4);
                sc = MFMA_BF16(kf1, qf1, sc);
                const int4 m4 = *(const int4*)&Mski[cb][nt * 16 + quad * 4];
                const int* mm = (const int*)&m4;
                const bool dnw = diag && (nt == w);
                float p[4];
#pragma unroll
                for (int r = 0; r < 4; ++r) {
                    float pv = __builtin_exp2f(sc[r] * cexp);
                    bool valid = (mm[r] != 0);
                    if (dnw) valid = valid && ((quad * 4 + r) <= l15);
                    pv = valid ? pv : 0.0f;
                    psum += pv;
                    p[r] = pv;
                }
                pk2[0] = cvtpk(p[0], p[1]);
                pk2[1] = cvtpk(p[2], p[3]);
            } else {
                pk2[0] = 0u; pk2[1] = 0u;
            }
            *(u32x2*)&Ps[w][l15][nt * 8 + quad * 2] = pk2;   // P^T packed along j
        }

        // O += P.V (uint-typed Ps load keeps the write->read dependence visible;
        // in-wave DS ordering covers the hazard at HW level)
        const bf16x8 pf0 = __builtin_bit_cast(bf16x8, *(const u32x4*)&Ps[w][l15][quad * 4]);
        const bf16x8 pf1 = __builtin_bit_cast(bf16x8, *(const u32x4*)&Ps[w][l15][16 + quad * 4]);
#pragma unroll
        for (int nt = 0; nt < 4; ++nt) {
            bf16x8 vf0 = *(const bf16x8*)&Vs[cb][0][nt * 512 + lane * 8];
            bf16x8 vf1 = *(const bf16x8*)&Vs[cb][1][nt * 512 + lane * 8];
            oacc[nt] = MFMA_BF16(pf0, vf0, oacc[nt]);
            oacc[nt] = MFMA_BF16(pf1, vf1, oacc[nt]);
        }

        if (kt + 1 < nkt) {
            __syncthreads();       // drains next tile's DMA + all waves' cb reads
            cb ^= 1;
        }
    }

    // l reduction: sum partials across the 4 quads holding the same q
    float l = psum;
    l += __shfl_xor(l, 16);
    l += __shfl_xor(l, 32);
    float lq[4];
#pragma unroll
    for (int r = 0; r < 4; ++r) lq[r] = __shfl(l, quad * 4 + r);

    // epilogue: oacc row = q_local = quad*4+r, col = v = nt*16+l15
#pragma unroll
    for (int nt = 0; nt < 4; ++nt) {
        const float e0 = emb0[h * 64 + nt * 16 + l15];
        const float e1 = emb1[h * 64 + nt * 16 + l15];
#pragma unroll
        for (int r = 0; r < 4; ++r) {
            const float ctx = oacc[nt][r] / lq[r];
            const float val = e0 + ctx * (e1 - e0);
            const size_t s_idx = (size_t)(b * 2048 + q0 + w * 16 + quad * 4 + r);
            ob[(s_idx * 16 + h) * 64 + nt * 16 + l15] = f2b(val);
        }
    }
#undef STAGE_TILE
}

// ---------------------------------------------------------------------------
extern "C" void kernel_launch(void* const* d_in, const int* in_sizes, int n_in,
                              void* d_out, int out_size, void* d_ws, size_t ws_size,
                              hipStream_t stream)
{
    const float* x    = (const float*)d_in[0];
    const int*   amask= (const int*)d_in[1];
    const float* Wq   = (const float*)d_in[2];
    const float* Wk   = (const float*)d_in[3];
    const float* Wv   = (const float*)d_in[4];
    const float* Wo   = (const float*)d_in[5];
    const float* emb0 = (const float*)d_in[6];
    const float* emb1 = (const float*)d_in[7];
    float* out = (float*)d_out;

    char* base = (char*)d_ws;
    unsigned short* xh    = (unsigned short*)(base);                      // 16 MB
    unsigned short* ob    = xh;                                           // aliases xh
    unsigned short* Wqkvt = (unsigned short*)(base + (16u << 20));        // 6 MB
    unsigned short* Wot   = (unsigned short*)(base + (22u << 20));        // 4 MB
    unsigned short* qh    = (unsigned short*)(base + (26u << 20));        // 8 MB
    unsigned short* kh    = (unsigned short*)(base + (34u << 20));        // 2 MB
    unsigned short* vtt   = (unsigned short*)(base + (36u << 20));        // 2 MB

    conv_bf16<<<2048, 256, 0, stream>>>(x, xh, 4096 * 2048);
    transp_conv_qkv<<<dim3(48, 64), dim3(32, 8), 0, stream>>>(Wq, Wk, Wv, Wqkvt);
    transp_conv<<<dim3(64, 32), dim3(32, 8), 0, stream>>>(Wo, 1024, 2048, Wot, 1024);

    gemm_bt_mfma<1><<<dim3(24, 32), 256, 0, stream>>>(xh, Wqkvt, 4096, 1536, 2048,
                                                      nullptr, qh, kh, vtt);
    rosa_attn_mfma<<<dim3(32, 16, 2), 256, 0, stream>>>(qh, kh, vtt, amask, emb0, emb1, ob);
    gemm_bt_mfma<0><<<dim3(32, 32), 256, 0, stream>>>(ob, Wot, 4096, 2048, 1024,
                                                      out, nullptr, nullptr, nullptr);
}

// Round 3
// 301.711 us; speedup vs baseline: 1.0689x; 1.0689x over previous
//
#include <hip/hip_runtime.h>
#include <math.h>

typedef short bf16x8 __attribute__((ext_vector_type(8)));
typedef float f32x4 __attribute__((ext_vector_type(4)));
typedef unsigned int u32x2 __attribute__((ext_vector_type(2)));
typedef unsigned int u32x4 __attribute__((ext_vector_type(4)));

#define MFMA_BF16(A,B,C) __builtin_amdgcn_mfma_f32_16x16x32_bf16(A,B,C,0,0,0)

__device__ __forceinline__ unsigned short f2b(float x) {
    union { float f; unsigned int u; } v; v.f = x;
    unsigned int r = v.u + 0x7FFFu + ((v.u >> 16) & 1u);
    return (unsigned short)(r >> 16);
}

// packed f32x2 -> bf16x2 (RNE), single instruction
__device__ __forceinline__ unsigned int cvtpk(float lo, float hi) {
    unsigned int r;
    asm("v_cvt_pk_bf16_f32 %0, %1, %2" : "=v"(r) : "v"(lo), "v"(hi));
    return r;
}

// async global->LDS DMA, 16B per lane; LDS dest = wave-uniform base + lane*16
__device__ __forceinline__ void gload16(const unsigned short* g, unsigned short* l) {
    __builtin_amdgcn_global_load_lds(
        (const __attribute__((address_space(1))) unsigned int*)(g),
        (__attribute__((address_space(3))) unsigned int*)(l),
        16, 0, 0);
}
// 4B per lane variant; LDS dest = base + lane*4
__device__ __forceinline__ void gload4(const int* g, int* l) {
    __builtin_amdgcn_global_load_lds(
        (const __attribute__((address_space(1))) unsigned int*)(g),
        (__attribute__((address_space(3))) unsigned int*)(l),
        4, 0, 0);
}

// ---------------------------------------------------------------------------
// fp32 -> bf16 convert (flat)
// ---------------------------------------------------------------------------
__global__ __launch_bounds__(256) void conv_bf16(const float* __restrict__ s,
                                                 unsigned short* __restrict__ d, int n)
{
    int i = blockIdx.x * blockDim.x + threadIdx.x;
    int stride = gridDim.x * blockDim.x;
    for (int idx = i * 4; idx < n; idx += stride * 4) {
        float4 v = *(const float4*)(s + idx);
        ushort4 o;
        o.x = f2b(v.x); o.y = f2b(v.y); o.z = f2b(v.z); o.w = f2b(v.w);
        *(ushort4*)(d + idx) = o;
    }
}

// ---------------------------------------------------------------------------
// Fused weight transpose+convert: Wq|Wk|Wv (fp32, [2048][C]) -> bf16 [C][2048]
// ---------------------------------------------------------------------------
__global__ __launch_bounds__(256) void transp_conv_qkv(const float* __restrict__ Wq,
                                                       const float* __restrict__ Wk,
                                                       const float* __restrict__ Wv,
                                                       unsigned short* __restrict__ dst)
{
    __shared__ float t[32][33];
    const int tx = threadIdx.x, ty = threadIdx.y;   // (32,8)
    int bx = blockIdx.x;
    const float* src; int C, cb, dco;
    if (bx < 32)      { src = Wq; C = 1024; cb = bx;      dco = 0; }
    else if (bx < 40) { src = Wk; C = 256;  cb = bx - 32; dco = 1024; }
    else              { src = Wv; C = 256;  cb = bx - 40; dco = 1280; }
    const int c = cb * 32 + tx;
    const int r0 = blockIdx.y * 32;
#pragma unroll
    for (int i = 0; i < 4; ++i)
        t[ty + i * 8][tx] = src[(size_t)(r0 + ty + i * 8) * C + c];
    __syncthreads();
    const int cc = cb * 32 + ty;
#pragma unroll
    for (int i = 0; i < 4; ++i)
        dst[(size_t)(dco + cc + i * 8) * 2048 + r0 + tx] = f2b(t[tx][ty + i * 8]);
}

__global__ __launch_bounds__(256) void transp_conv(const float* __restrict__ src, int R, int C,
                                                   unsigned short* __restrict__ dst, int pitch)
{
    __shared__ float t[32][33];
    const int tx = threadIdx.x, ty = threadIdx.y;
    const int c = blockIdx.x * 32 + tx;
    const int r0 = blockIdx.y * 32;
#pragma unroll
    for (int i = 0; i < 4; ++i)
        t[ty + i * 8][tx] = src[(size_t)(r0 + ty + i * 8) * C + c];
    __syncthreads();
    const int cc = blockIdx.x * 32 + ty;
#pragma unroll
    for (int i = 0; i < 4; ++i)
        dst[(size_t)(cc + i * 8) * pitch + r0 + tx] = f2b(t[tx][ty + i * 8]);
}

// ---------------------------------------------------------------------------
// bf16 MFMA GEMM, B^T input: C[M][N] = A[M][K] @ Bt[N][K]^T
// BM=128, BN=64, BK=64; 256 threads (4 waves, 2x2); double-buffered
// global_load_lds staging.
// DMA source lanes re-mapped (row=lane&15, col=(lane>>4)*8) so every fragment
// ds_read_b128 lands at base + lane*16B -> lane-linear, bank-conflict-free.
// ---------------------------------------------------------------------------
template <int MODE>
__global__ __launch_bounds__(256, 3) void gemm_bt_mfma(
    const unsigned short* __restrict__ A,
    const unsigned short* __restrict__ Bt,
    int M, int N, int K,
    float* __restrict__ Cf,
    unsigned short* __restrict__ qh,
    unsigned short* __restrict__ kh,
    unsigned short* __restrict__ vtt)
{
    __shared__ __align__(16) unsigned short As[2][2 * 128 * 32];
    __shared__ __align__(16) unsigned short Bs[2][2 * 64 * 32];

    const int tid = threadIdx.x;
    const int w = tid >> 6, lane = tid & 63, l15 = lane & 15, quad = lane >> 4;
    const int wm = w & 1, wn = w >> 1;
    const int m0 = blockIdx.y * 128, n0 = blockIdx.x * 64;

    f32x4 acc[4][2];
    const f32x4 zero4 = {0.f, 0.f, 0.f, 0.f};
#pragma unroll
    for (int i = 0; i < 4; ++i)
#pragma unroll
        for (int j = 0; j < 2; ++j) acc[i][j] = zero4;

    // DMA lane geometry matched to fragment reads: row = lane&15, col = (lane>>4)*8
    const unsigned short* AgL = A  + (size_t)(m0 + w * 32 + l15) * K + quad * 8;
    const unsigned short* BgL = Bt + (size_t)(n0 + w * 16 + l15) * K + quad * 8;

#pragma unroll
    for (int t = 0; t < 4; ++t) {
        const int sub = t >> 1, half = t & 1;
        gload16(AgL + (size_t)(half * 16) * K + sub * 32,
                &As[0][sub * 4096 + (w * 2 + half) * 512]);
    }
#pragma unroll
    for (int kk = 0; kk < 2; ++kk)
        gload16(BgL + kk * 32, &Bs[0][kk * 2048 + w * 512]);
    __syncthreads();

    int cb = 0;
    for (int k0 = 0; k0 < K; k0 += 64) {
        if (k0 + 64 < K) {
            const int nb = cb ^ 1;
#pragma unroll
            for (int t = 0; t < 4; ++t) {
                const int sub = t >> 1, half = t & 1;
                gload16(AgL + (size_t)(half * 16) * K + (k0 + 64) + sub * 32,
                        &As[nb][sub * 4096 + (w * 2 + half) * 512]);
            }
#pragma unroll
            for (int kk = 0; kk < 2; ++kk)
                gload16(BgL + (k0 + 64) + kk * 32, &Bs[nb][kk * 2048 + w * 512]);
        }

        bf16x8 af[4][2], bf[2][2];
#pragma unroll
        for (int kk = 0; kk < 2; ++kk) {
#pragma unroll
            for (int mt = 0; mt < 4; ++mt)
                af[mt][kk] = *(const bf16x8*)&As[cb][kk * 4096 + (wm * 4 + mt) * 512 + lane * 8];
#pragma unroll
            for (int nt = 0; nt < 2; ++nt)
                bf[nt][kk] = *(const bf16x8*)&Bs[cb][kk * 2048 + (wn * 2 + nt) * 512 + lane * 8];
        }
#pragma unroll
        for (int kk = 0; kk < 2; ++kk)
#pragma unroll
            for (int mt = 0; mt < 4; ++mt)
#pragma unroll
                for (int nt = 0; nt < 2; ++nt)
                    acc[mt][nt] = MFMA_BF16(af[mt][kk], bf[nt][kk], acc[mt][nt]);

        __syncthreads();
        cb ^= 1;
    }

    if (MODE == 0) {
#pragma unroll
        for (int mt = 0; mt < 4; ++mt)
#pragma unroll
            for (int nt = 0; nt < 2; ++nt) {
                const int gn = n0 + wn * 32 + nt * 16 + l15;
#pragma unroll
                for (int r = 0; r < 4; ++r) {
                    const int gm = m0 + wm * 64 + mt * 16 + quad * 4 + r;
                    Cf[(size_t)gm * N + gn] = acc[mt][nt][r];
                }
            }
    } else {
        if (n0 < 1024) {            // Q: tanh -> qh[m][n], pitch 1024
#pragma unroll
            for (int mt = 0; mt < 4; ++mt)
#pragma unroll
                for (int nt = 0; nt < 2; ++nt) {
                    const int gn = n0 + wn * 32 + nt * 16 + l15;
#pragma unroll
                    for (int r = 0; r < 4; ++r) {
                        const int gm = m0 + wm * 64 + mt * 16 + quad * 4 + r;
                        qh[(size_t)gm * 1024 + gn] = f2b(tanhf(acc[mt][nt][r]));
                    }
                }
        } else if (n0 < 1280) {     // K: tanh -> kh[m][n-1024], pitch 256
#pragma unroll
            for (int mt = 0; mt < 4; ++mt)
#pragma unroll
                for (int nt = 0; nt < 2; ++nt) {
                    const int gn = n0 + wn * 32 + nt * 16 + l15 - 1024;
#pragma unroll
                    for (int r = 0; r < 4; ++r) {
                        const int gm = m0 + wm * 64 + mt * 16 + quad * 4 + r;
                        kh[(size_t)gm * 256 + gn] = f2b(tanhf(acc[mt][nt][r]));
                    }
                }
        } else {                    // V: sigmoid -> vtt[(b*4+g)*64+v][s]
#pragma unroll
            for (int mt = 0; mt < 4; ++mt)
#pragma unroll
                for (int nt = 0; nt < 2; ++nt) {
                    const int gn = n0 + wn * 32 + nt * 16 + l15 - 1280;
                    const int g = gn >> 6, vv = gn & 63;
                    const int s0 = m0 + wm * 64 + mt * 16 + quad * 4;
                    const int b = s0 >> 11, sl = s0 & 2047;
                    ushort4 pk;
                    unsigned short* pp = (unsigned short*)&pk;
#pragma unroll
                    for (int r = 0; r < 4; ++r) {
                        float sv = 1.0f / (1.0f + __expf(-acc[mt][nt][r]));
                        pp[r] = f2b(sv);
                    }
                    *(ushort4*)&vtt[((size_t)(b * 4 + g) * 64 + vv) * 2048 + sl] = pk;
                }
        }
    }
}

// ---------------------------------------------------------------------------
// MFMA flash attention.
// Grid (24,16,2) = 768 blocks = exactly 3 blocks/CU (LDS 42.5KB -> 3 fit),
// ALL co-resident from t=0 (no dispatch queue, no tail).  Work balance:
//   x=0..7   -> singleton qt=31-x          (work 32-x)
//   x=8..15  -> singleton qt=x+8           (work x+9)
//   x=16..23 -> pair (x-16, 31-x)          (work 17)
// Round-robin CU assignment {c, c+256, c+512} -> orbit {a,a+8,a+16} ->
// per-CU work = (32-a)+(17+a)+17 = 66 for every a: exact balance.
// Lane-linear K/V LDS (conflict-free ds_read_b128); cvt_pk P-packing;
// Ps uint-typed end-to-end (TBAA dependence); s_setprio around MFMA clusters
// (3 independent blocks/CU at different phases = the regime where it pays).
// One barrier/tile. Fixed-max softmax (|s|<1).
// ---------------------------------------------------------------------------
__global__ __launch_bounds__(256, 3) void rosa_attn_mfma(
    const unsigned short* __restrict__ qh,
    const unsigned short* __restrict__ kh,
    const unsigned short* __restrict__ vtt,
    const int* __restrict__ amask,
    const float* __restrict__ emb0,
    const float* __restrict__ emb1,
    unsigned short* __restrict__ ob)
{
    __shared__ __align__(16) unsigned short Ks[2][2][2048];  // [buf][kk][group*512 + lane*8]
    __shared__ __align__(16) unsigned short Vs[2][2][2048];
    __shared__ __align__(16) unsigned int   Ps[4][16][36];   // [wave][q][j/2] (uint-typed!)
    __shared__ int Mski[2][64];

    const int X = blockIdx.x;                     // 0..23
    int qa, qb = 0, nq;
    if (X < 8)       { qa = 31 - X; nq = 1; }
    else if (X < 16) { qa = X + 8;  nq = 1; }
    else             { qa = X - 16; qb = 31 - X; nq = 2; }

    const int h = blockIdx.y, b = blockIdx.z, g = h >> 2;
    const int tid = threadIdx.x;
    const int w = tid >> 6, lane = tid & 63, l15 = lane & 15, quad = lane >> 4;

    // DMA lane geometry matched to fragment reads: row = lane&15, col = (lane>>4)*8
    const unsigned short* kst = kh + (size_t)b * 2048 * 256 + g * 64
                               + (size_t)(w * 16 + l15) * 256 + quad * 8;    // + k0*256 + kk*32
    const unsigned short* vst = vtt + ((size_t)(b * 4 + g) * 64 + w * 16 + l15) * 2048
                               + quad * 8;                                   // + k0 + kk*32
    const int* mbase = amask + b * 2048;

    const f32x4 zero4 = {0.f, 0.f, 0.f, 0.f};
    const float cexp = 0.0225421100f;             // log2(e)/64

#define STAGE_TILE(k0s, buf)                                               \
    {                                                                      \
        gload16(kst + (size_t)(k0s) * 256,      &Ks[buf][0][w * 512]);     \
        gload16(kst + (size_t)(k0s) * 256 + 32, &Ks[buf][1][w * 512]);     \
        gload16(vst + (k0s),                    &Vs[buf][0][w * 512]);     \
        gload16(vst + (k0s) + 32,               &Vs[buf][1][w * 512]);     \
        if (w == 0) gload4(mbase + (k0s) + lane, &Mski[buf][0]);           \
    }

    for (int hi = 0; hi < nq; ++hi) {
        const int qt = (hi == 0) ? qa : qb;
        const int q0 = qt * 64;
        const int nkt = qt + 1;
        const int qg = q0 + w * 16 + l15;

        // Q B-fragment (n = q = l15, k = d), per wave, from global (L2-hot)
        const unsigned short* qrow = qh + ((size_t)(b * 2048 + qg) * 16 + h) * 64;
        const bf16x8 qf0 = *(const bf16x8*)(qrow + quad * 8);
        const bf16x8 qf1 = *(const bf16x8*)(qrow + 32 + quad * 8);

        f32x4 oacc[4];
#pragma unroll
        for (int t = 0; t < 4; ++t) oacc[t] = zero4;
        float psum = 0.0f;

        __syncthreads();           // protect bufs from previous tile's readers
        STAGE_TILE(0, 0)
        __syncthreads();           // vmcnt(0) drain: tile 0 visible

        int cb = 0;
        for (int kt = 0; kt < nkt; ++kt) {
            if (kt + 1 < nkt) STAGE_TILE((kt + 1) * 64, cb ^ 1)

            const bool diag = (kt == qt);
            const int ntlim = diag ? (w + 1) : 4;

            // S^T = K.Q^T per 16x16 sub-tile; fixed-max softmax; pack P^T
#pragma unroll
            for (int nt = 0; nt < 4; ++nt) {
                u32x2 pk2;
                if (nt < ntlim) {
                    bf16x8 kf0 = *(const bf16x8*)&Ks[cb][0][nt * 512 + lane * 8];
                    bf16x8 kf1 = *(const bf16x8*)&Ks[cb][1][nt * 512 + lane * 8];
                    __builtin_amdgcn_s_setprio(1);
                    f32x4 sc = MFMA_BF16(kf0, qf0, zero4);
                    sc = MFMA_BF16(kf1, qf1, sc);
                    __builtin_amdgcn_s_setprio(0);
                    const int4 m4 = *(const int4*)&Mski[cb][nt * 16 + quad * 4];
                    const int* mm = (const int*)&m4;
                    const bool dnw = diag && (nt == w);
                    float p[4];
#pragma unroll
                    for (int r = 0; r < 4; ++r) {
                        float pv = __builtin_exp2f(sc[r] * cexp);
                        bool valid = (mm[r] != 0);
                        if (dnw) valid = valid && ((quad * 4 + r) <= l15);
                        pv = valid ? pv : 0.0f;
                        psum += pv;
                        p[r] = pv;
                    }
                    pk2[0] = cvtpk(p[0], p[1]);
                    pk2[1] = cvtpk(p[2], p[3]);
                } else {
                    pk2[0] = 0u; pk2[1] = 0u;
                }
                *(u32x2*)&Ps[w][l15][nt * 8 + quad * 2] = pk2;   // P^T packed along j
            }

            // O += P.V (uint-typed Ps load keeps the write->read dependence
            // visible; in-wave DS ordering covers the hazard at HW level)
            const bf16x8 pf0 = __builtin_bit_cast(bf16x8, *(const u32x4*)&Ps[w][l15][quad * 4]);
            const bf16x8 pf1 = __builtin_bit_cast(bf16x8, *(const u32x4*)&Ps[w][l15][16 + quad * 4]);
            __builtin_amdgcn_s_setprio(1);
#pragma unroll
            for (int nt = 0; nt < 4; ++nt) {
                bf16x8 vf0 = *(const bf16x8*)&Vs[cb][0][nt * 512 + lane * 8];
                bf16x8 vf1 = *(const bf16x8*)&Vs[cb][1][nt * 512 + lane * 8];
                oacc[nt] = MFMA_BF16(pf0, vf0, oacc[nt]);
                oacc[nt] = MFMA_BF16(pf1, vf1, oacc[nt]);
            }
            __builtin_amdgcn_s_setprio(0);

            if (kt + 1 < nkt) {
                __syncthreads();   // drains next tile's DMA + all waves' cb reads
                cb ^= 1;
            }
        }

        // l reduction: sum partials across the 4 quads holding the same q
        float l = psum;
        l += __shfl_xor(l, 16);
        l += __shfl_xor(l, 32);
        float lq[4];
#pragma unroll
        for (int r = 0; r < 4; ++r) lq[r] = __shfl(l, quad * 4 + r);

        // epilogue: oacc row = q_local = quad*4+r, col = v = nt*16+l15
#pragma unroll
        for (int nt = 0; nt < 4; ++nt) {
            const float e0 = emb0[h * 64 + nt * 16 + l15];
            const float e1 = emb1[h * 64 + nt * 16 + l15];
#pragma unroll
            for (int r = 0; r < 4; ++r) {
                const float ctx = oacc[nt][r] / lq[r];
                const float val = e0 + ctx * (e1 - e0);
                const size_t s_idx = (size_t)(b * 2048 + q0 + w * 16 + quad * 4 + r);
                ob[(s_idx * 16 + h) * 64 + nt * 16 + l15] = f2b(val);
            }
        }
    }
#undef STAGE_TILE
}

// ---------------------------------------------------------------------------
extern "C" void kernel_launch(void* const* d_in, const int* in_sizes, int n_in,
                              void* d_out, int out_size, void* d_ws, size_t ws_size,
                              hipStream_t stream)
{
    const float* x    = (const float*)d_in[0];
    const int*   amask= (const int*)d_in[1];
    const float* Wq   = (const float*)d_in[2];
    const float* Wk   = (const float*)d_in[3];
    const float* Wv   = (const float*)d_in[4];
    const float* Wo   = (const float*)d_in[5];
    const float* emb0 = (const float*)d_in[6];
    const float* emb1 = (const float*)d_in[7];
    float* out = (float*)d_out;

    char* base = (char*)d_ws;
    unsigned short* xh    = (unsigned short*)(base);                      // 16 MB
    unsigned short* ob    = xh;                                           // aliases xh
    unsigned short* Wqkvt = (unsigned short*)(base + (16u << 20));        // 6 MB
    unsigned short* Wot   = (unsigned short*)(base + (22u << 20));        // 4 MB
    unsigned short* qh    = (unsigned short*)(base + (26u << 20));        // 8 MB
    unsigned short* kh    = (unsigned short*)(base + (34u << 20));        // 2 MB
    unsigned short* vtt   = (unsigned short*)(base + (36u << 20));        // 2 MB

    conv_bf16<<<2048, 256, 0, stream>>>(x, xh, 4096 * 2048);
    transp_conv_qkv<<<dim3(48, 64), dim3(32, 8), 0, stream>>>(Wq, Wk, Wv, Wqkvt);
    transp_conv<<<dim3(64, 32), dim3(32, 8), 0, stream>>>(Wo, 1024, 2048, Wot, 1024);

    gemm_bt_mfma<1><<<dim3(24, 32), 256, 0, stream>>>(xh, Wqkvt, 4096, 1536, 2048,
                                                      nullptr, qh, kh, vtt);
    rosa_attn_mfma<<<dim3(24, 16, 2), 256, 0, stream>>>(qh, kh, vtt, amask, emb0, emb1, ob);
    gemm_bt_mfma<0><<<dim3(32, 32), 256, 0, stream>>>(ob, Wot, 4096, 2048, 1024,
                                                      out, nullptr, nullptr, nullptr);
}

// Round 4
// 300.616 us; speedup vs baseline: 1.0728x; 1.0036x over previous
//
#include <hip/hip_runtime.h>
#include <math.h>

typedef short bf16x8 __attribute__((ext_vector_type(8)));
typedef float f32x4 __attribute__((ext_vector_type(4)));
typedef unsigned int u32x2 __attribute__((ext_vector_type(2)));
typedef unsigned int u32x4 __attribute__((ext_vector_type(4)));

#define MFMA_BF16(A,B,C) __builtin_amdgcn_mfma_f32_16x16x32_bf16(A,B,C,0,0,0)

// counted vmcnt wait: loads newer than the N most recent stay in flight
#define VMCNT(N) asm volatile("s_waitcnt vmcnt(" #N ")" ::: "memory")
// raw barrier (no vmcnt drain!) with compiler memory fences on both sides
#define RBAR() do { asm volatile("" ::: "memory"); __builtin_amdgcn_s_barrier(); \
                    asm volatile("" ::: "memory"); } while (0)

__device__ __forceinline__ unsigned short f2b(float x) {
    union { float f; unsigned int u; } v; v.f = x;
    unsigned int r = v.u + 0x7FFFu + ((v.u >> 16) & 1u);
    return (unsigned short)(r >> 16);
}

// packed f32x2 -> bf16x2 (RNE), single instruction
__device__ __forceinline__ unsigned int cvtpk(float lo, float hi) {
    unsigned int r;
    asm("v_cvt_pk_bf16_f32 %0, %1, %2" : "=v"(r) : "v"(lo), "v"(hi));
    return r;
}

// async global->LDS DMA, 16B per lane; LDS dest = wave-uniform base + lane*16
__device__ __forceinline__ void gload16(const unsigned short* g, unsigned short* l) {
    __builtin_amdgcn_global_load_lds(
        (const __attribute__((address_space(1))) unsigned int*)(g),
        (__attribute__((address_space(3))) unsigned int*)(l),
        16, 0, 0);
}
// 4B per lane variant; LDS dest = base + lane*4
__device__ __forceinline__ void gload4(const int* g, int* l) {
    __builtin_amdgcn_global_load_lds(
        (const __attribute__((address_space(1))) unsigned int*)(g),
        (__attribute__((address_space(3))) unsigned int*)(l),
        4, 0, 0);
}

// ---------------------------------------------------------------------------
// fp32 -> bf16 convert (flat)
// ---------------------------------------------------------------------------
__global__ __launch_bounds__(256) void conv_bf16(const float* __restrict__ s,
                                                 unsigned short* __restrict__ d, int n)
{
    int i = blockIdx.x * blockDim.x + threadIdx.x;
    int stride = gridDim.x * blockDim.x;
    for (int idx = i * 4; idx < n; idx += stride * 4) {
        float4 v = *(const float4*)(s + idx);
        ushort4 o;
        o.x = f2b(v.x); o.y = f2b(v.y); o.z = f2b(v.z); o.w = f2b(v.w);
        *(ushort4*)(d + idx) = o;
    }
}

// ---------------------------------------------------------------------------
// Fused weight transpose+convert: Wq|Wk|Wv (fp32, [2048][C]) -> bf16 [C][2048]
// ---------------------------------------------------------------------------
__global__ __launch_bounds__(256) void transp_conv_qkv(const float* __restrict__ Wq,
                                                       const float* __restrict__ Wk,
                                                       const float* __restrict__ Wv,
                                                       unsigned short* __restrict__ dst)
{
    __shared__ float t[32][33];
    const int tx = threadIdx.x, ty = threadIdx.y;   // (32,8)
    int bx = blockIdx.x;
    const float* src; int C, cb, dco;
    if (bx < 32)      { src = Wq; C = 1024; cb = bx;      dco = 0; }
    else if (bx < 40) { src = Wk; C = 256;  cb = bx - 32; dco = 1024; }
    else              { src = Wv; C = 256;  cb = bx - 40; dco = 1280; }
    const int c = cb * 32 + tx;
    const int r0 = blockIdx.y * 32;
#pragma unroll
    for (int i = 0; i < 4; ++i)
        t[ty + i * 8][tx] = src[(size_t)(r0 + ty + i * 8) * C + c];
    __syncthreads();
    const int cc = cb * 32 + ty;
#pragma unroll
    for (int i = 0; i < 4; ++i)
        dst[(size_t)(dco + cc + i * 8) * 2048 + r0 + tx] = f2b(t[tx][ty + i * 8]);
}

__global__ __launch_bounds__(256) void transp_conv(const float* __restrict__ src, int R, int C,
                                                   unsigned short* __restrict__ dst, int pitch)
{
    __shared__ float t[32][33];
    const int tx = threadIdx.x, ty = threadIdx.y;
    const int c = blockIdx.x * 32 + tx;
    const int r0 = blockIdx.y * 32;
#pragma unroll
    for (int i = 0; i < 4; ++i)
        t[ty + i * 8][tx] = src[(size_t)(r0 + ty + i * 8) * C + c];
    __syncthreads();
    const int cc = blockIdx.x * 32 + ty;
#pragma unroll
    for (int i = 0; i < 4; ++i)
        dst[(size_t)(cc + i * 8) * pitch + r0 + tx] = f2b(t[tx][ty + i * 8]);
}

// ---------------------------------------------------------------------------
// bf16 MFMA GEMM, B^T input: C[M][N] = A[M][K] @ Bt[N][K]^T
// BM=128, BN=64, BK=64; 256 threads (4 waves, 2x2); double-buffered
// global_load_lds staging, lane-linear LDS (0 bank conflicts).
// This round: counted-vmcnt pipeline (T4). No __syncthreads in the K-loop:
// raw s_barrier + "s_waitcnt vmcnt(6)" keeps the 6 just-issued next-tile
// DMA loads in flight across the barrier (the vmcnt(0) drain was the
// ~2100-cyc K-step stall: MfmaUtil 11%).
// ---------------------------------------------------------------------------
__device__ __forceinline__ void stage_g(const unsigned short* AgL, const unsigned short* BgL,
                                        int K, int k0s,
                                        unsigned short* Asb, unsigned short* Bsb, int w)
{
#pragma unroll
    for (int t = 0; t < 4; ++t) {
        const int sub = t >> 1, half = t & 1;
        gload16(AgL + (size_t)(half * 16) * K + k0s + sub * 32,
                Asb + sub * 4096 + (w * 2 + half) * 512);
    }
#pragma unroll
    for (int kk = 0; kk < 2; ++kk)
        gload16(BgL + k0s + kk * 32, Bsb + kk * 2048 + w * 512);
}

template <int MODE>
__global__ __launch_bounds__(256, 3) void gemm_bt_mfma(
    const unsigned short* __restrict__ A,
    const unsigned short* __restrict__ Bt,
    int M, int N, int K,
    float* __restrict__ Cf,
    unsigned short* __restrict__ qh,
    unsigned short* __restrict__ kh,
    unsigned short* __restrict__ vtt)
{
    __shared__ __align__(16) unsigned short As[2][2 * 128 * 32];
    __shared__ __align__(16) unsigned short Bs[2][2 * 64 * 32];

    const int tid = threadIdx.x;
    const int w = tid >> 6, lane = tid & 63, l15 = lane & 15, quad = lane >> 4;
    const int wm = w & 1, wn = w >> 1;
    const int m0 = blockIdx.y * 128, n0 = blockIdx.x * 64;

    f32x4 acc[4][2];
    const f32x4 zero4 = {0.f, 0.f, 0.f, 0.f};
#pragma unroll
    for (int i = 0; i < 4; ++i)
#pragma unroll
        for (int j = 0; j < 2; ++j) acc[i][j] = zero4;

    // DMA lane geometry matched to fragment reads: row = lane&15, col = (lane>>4)*8
    const unsigned short* AgL = A  + (size_t)(m0 + w * 32 + l15) * K + quad * 8;
    const unsigned short* BgL = Bt + (size_t)(n0 + w * 16 + l15) * K + quad * 8;

    const int NT = K >> 6;
    stage_g(AgL, BgL, K, 0, &As[0][0], &Bs[0][0], w);   // prologue: tile 0, no drain

    int cb = 0;
    for (int t = 0; t < NT; ++t) {
        if (t + 1 < NT) {
            stage_g(AgL, BgL, K, (t + 1) * 64, &As[cb ^ 1][0], &Bs[cb ^ 1][0], w);
            VMCNT(6);              // wait tile t (oldest 6); tile t+1 stays in flight
        } else {
            VMCNT(0);
        }
        RBAR();                    // everyone's tile-t DMA landed

        bf16x8 af[4][2], bf[2][2];
#pragma unroll
        for (int kk = 0; kk < 2; ++kk) {
#pragma unroll
            for (int mt = 0; mt < 4; ++mt)
                af[mt][kk] = *(const bf16x8*)&As[cb][kk * 4096 + (wm * 4 + mt) * 512 + lane * 8];
#pragma unroll
            for (int nt = 0; nt < 2; ++nt)
                bf[nt][kk] = *(const bf16x8*)&Bs[cb][kk * 2048 + (wn * 2 + nt) * 512 + lane * 8];
        }
#pragma unroll
        for (int kk = 0; kk < 2; ++kk)
#pragma unroll
            for (int mt = 0; mt < 4; ++mt)
#pragma unroll
                for (int nt = 0; nt < 2; ++nt)
                    acc[mt][nt] = MFMA_BF16(af[mt][kk], bf[nt][kk], acc[mt][nt]);

        if (t + 1 < NT) RBAR();    // readers done before next iter overwrites cb
        cb ^= 1;
    }

    if (MODE == 0) {
#pragma unroll
        for (int mt = 0; mt < 4; ++mt)
#pragma unroll
            for (int nt = 0; nt < 2; ++nt) {
                const int gn = n0 + wn * 32 + nt * 16 + l15;
#pragma unroll
                for (int r = 0; r < 4; ++r) {
                    const int gm = m0 + wm * 64 + mt * 16 + quad * 4 + r;
                    Cf[(size_t)gm * N + gn] = acc[mt][nt][r];
                }
            }
    } else {
        if (n0 < 1024) {            // Q: tanh -> qh[m][n], pitch 1024
#pragma unroll
            for (int mt = 0; mt < 4; ++mt)
#pragma unroll
                for (int nt = 0; nt < 2; ++nt) {
                    const int gn = n0 + wn * 32 + nt * 16 + l15;
#pragma unroll
                    for (int r = 0; r < 4; ++r) {
                        const int gm = m0 + wm * 64 + mt * 16 + quad * 4 + r;
                        qh[(size_t)gm * 1024 + gn] = f2b(tanhf(acc[mt][nt][r]));
                    }
                }
        } else if (n0 < 1280) {     // K: tanh -> kh[m][n-1024], pitch 256
#pragma unroll
            for (int mt = 0; mt < 4; ++mt)
#pragma unroll
                for (int nt = 0; nt < 2; ++nt) {
                    const int gn = n0 + wn * 32 + nt * 16 + l15 - 1024;
#pragma unroll
                    for (int r = 0; r < 4; ++r) {
                        const int gm = m0 + wm * 64 + mt * 16 + quad * 4 + r;
                        kh[(size_t)gm * 256 + gn] = f2b(tanhf(acc[mt][nt][r]));
                    }
                }
        } else {                    // V: sigmoid -> vtt[(b*4+g)*64+v][s]
#pragma unroll
            for (int mt = 0; mt < 4; ++mt)
#pragma unroll
                for (int nt = 0; nt < 2; ++nt) {
                    const int gn = n0 + wn * 32 + nt * 16 + l15 - 1280;
                    const int g = gn >> 6, vv = gn & 63;
                    const int s0 = m0 + wm * 64 + mt * 16 + quad * 4;
                    const int b = s0 >> 11, sl = s0 & 2047;
                    ushort4 pk;
                    unsigned short* pp = (unsigned short*)&pk;
#pragma unroll
                    for (int r = 0; r < 4; ++r) {
                        float sv = 1.0f / (1.0f + __expf(-acc[mt][nt][r]));
                        pp[r] = f2b(sv);
                    }
                    *(ushort4*)&vtt[((size_t)(b * 4 + g) * 64 + vv) * 2048 + sl] = pk;
                }
        }
    }
}

// ---------------------------------------------------------------------------
// MFMA flash attention.
// Grid (24,16,2) = 768 blocks = exactly 3 blocks/CU, co-resident, per-CU
// work balanced (orbit sum = 66 for every CU under round-robin).
// This round: counted-vmcnt pipeline (T4) in the k-tile loop — raw s_barrier
// + vmcnt(4|5) keeps the next tile's DMA in flight across the barrier
// (wave 0 stages 5 ops incl. mask, waves 1-3 stage 4).
// Lane-linear K/V LDS (0 conflicts); cvt_pk P-packing; uint-typed Ps (TBAA);
// s_setprio around MFMA clusters. Fixed-max softmax (|s|<1).
// ---------------------------------------------------------------------------
__global__ __launch_bounds__(256, 3) void rosa_attn_mfma(
    const unsigned short* __restrict__ qh,
    const unsigned short* __restrict__ kh,
    const unsigned short* __restrict__ vtt,
    const int* __restrict__ amask,
    const float* __restrict__ emb0,
    const float* __restrict__ emb1,
    unsigned short* __restrict__ ob)
{
    __shared__ __align__(16) unsigned short Ks[2][2][2048];  // [buf][kk][group*512 + lane*8]
    __shared__ __align__(16) unsigned short Vs[2][2][2048];
    __shared__ __align__(16) unsigned int   Ps[4][16][36];   // [wave][q][j/2] (uint-typed!)
    __shared__ int Mski[2][64];

    const int X = blockIdx.x;                     // 0..23
    int qa, qb = 0, nq;
    if (X < 8)       { qa = 31 - X; nq = 1; }
    else if (X < 16) { qa = X + 8;  nq = 1; }
    else             { qa = X - 16; qb = 31 - X; nq = 2; }

    const int h = blockIdx.y, b = blockIdx.z, g = h >> 2;
    const int tid = threadIdx.x;
    const int w = tid >> 6, lane = tid & 63, l15 = lane & 15, quad = lane >> 4;

    // DMA lane geometry matched to fragment reads: row = lane&15, col = (lane>>4)*8
    const unsigned short* kst = kh + (size_t)b * 2048 * 256 + g * 64
                               + (size_t)(w * 16 + l15) * 256 + quad * 8;    // + k0*256 + kk*32
    const unsigned short* vst = vtt + ((size_t)(b * 4 + g) * 64 + w * 16 + l15) * 2048
                               + quad * 8;                                   // + k0 + kk*32
    const int* mbase = amask + b * 2048;

    const f32x4 zero4 = {0.f, 0.f, 0.f, 0.f};
    const float cexp = 0.0225421100f;             // log2(e)/64

#define STAGE_TILE(k0s, buf)                                               \
    {                                                                      \
        gload16(kst + (size_t)(k0s) * 256,      &Ks[buf][0][w * 512]);     \
        gload16(kst + (size_t)(k0s) * 256 + 32, &Ks[buf][1][w * 512]);     \
        gload16(vst + (k0s),                    &Vs[buf][0][w * 512]);     \
        gload16(vst + (k0s) + 32,               &Vs[buf][1][w * 512]);     \
        if (w == 0) gload4(mbase + (k0s) + lane, &Mski[buf][0]);           \
    }

    for (int hi = 0; hi < nq; ++hi) {
        const int qt = (hi == 0) ? qa : qb;
        const int q0 = qt * 64;
        const int nkt = qt + 1;
        const int qg = q0 + w * 16 + l15;

        // Q B-fragment (n = q = l15, k = d), per wave, from global (L2-hot)
        const unsigned short* qrow = qh + ((size_t)(b * 2048 + qg) * 16 + h) * 64;
        const bf16x8 qf0 = *(const bf16x8*)(qrow + quad * 8);
        const bf16x8 qf1 = *(const bf16x8*)(qrow + 32 + quad * 8);

        f32x4 oacc[4];
#pragma unroll
        for (int t = 0; t < 4; ++t) oacc[t] = zero4;
        float psum = 0.0f;

        RBAR();                    // protect bufs from previous tile's readers
        STAGE_TILE(0, 0)           // prologue: tile 0, no drain

        int cb = 0;
        for (int kt = 0; kt < nkt; ++kt) {
            if (kt + 1 < nkt) {
                STAGE_TILE((kt + 1) * 64, cb ^ 1)
                if (w == 0) { VMCNT(5); } else { VMCNT(4); }   // wait tile kt only
            } else {
                VMCNT(0);
            }
            RBAR();                // everyone's tile-kt DMA landed

            const bool diag = (kt == qt);
            const int ntlim = diag ? (w + 1) : 4;

            // S^T = K.Q^T per 16x16 sub-tile; fixed-max softmax; pack P^T
#pragma unroll
            for (int nt = 0; nt < 4; ++nt) {
                u32x2 pk2;
                if (nt < ntlim) {
                    bf16x8 kf0 = *(const bf16x8*)&Ks[cb][0][nt * 512 + lane * 8];
                    bf16x8 kf1 = *(const bf16x8*)&Ks[cb][1][nt * 512 + lane * 8];
                    __builtin_amdgcn_s_setprio(1);
                    f32x4 sc = MFMA_BF16(kf0, qf0, zero4);
                    sc = MFMA_BF16(kf1, qf1, sc);
                    __builtin_amdgcn_s_setprio(0);
                    const int4 m4 = *(const int4*)&Mski[cb][nt * 16 + quad * 4];
                    const int* mm = (const int*)&m4;
                    const bool dnw = diag && (nt == w);
                    float p[4];
#pragma unroll
                    for (int r = 0; r < 4; ++r) {
                        float pv = __builtin_exp2f(sc[r] * cexp);
                        bool valid = (mm[r] != 0);
                        if (dnw) valid = valid && ((quad * 4 + r) <= l15);
                        pv = valid ? pv : 0.0f;
                        psum += pv;
                        p[r] = pv;
                    }
                    pk2[0] = cvtpk(p[0], p[1]);
                    pk2[1] = cvtpk(p[2], p[3]);
                } else {
                    pk2[0] = 0u; pk2[1] = 0u;
                }
                *(u32x2*)&Ps[w][l15][nt * 8 + quad * 2] = pk2;   // P^T packed along j
            }

            // O += P.V (uint-typed Ps load keeps the write->read dependence
            // visible; in-wave DS ordering covers the hazard at HW level)
            const bf16x8 pf0 = __builtin_bit_cast(bf16x8, *(const u32x4*)&Ps[w][l15][quad * 4]);
            const bf16x8 pf1 = __builtin_bit_cast(bf16x8, *(const u32x4*)&Ps[w][l15][16 + quad * 4]);
            __builtin_amdgcn_s_setprio(1);
#pragma unroll
            for (int nt = 0; nt < 4; ++nt) {
                bf16x8 vf0 = *(const bf16x8*)&Vs[cb][0][nt * 512 + lane * 8];
                bf16x8 vf1 = *(const bf16x8*)&Vs[cb][1][nt * 512 + lane * 8];
                oacc[nt] = MFMA_BF16(pf0, vf0, oacc[nt]);
                oacc[nt] = MFMA_BF16(pf1, vf1, oacc[nt]);
            }
            __builtin_amdgcn_s_setprio(0);

            if (kt + 1 < nkt) {
                RBAR();            // readers done before next iter overwrites cb
                cb ^= 1;
            }
        }

        // l reduction: sum partials across the 4 quads holding the same q
        float l = psum;
        l += __shfl_xor(l, 16);
        l += __shfl_xor(l, 32);
        float lq[4];
#pragma unroll
        for (int r = 0; r < 4; ++r) lq[r] = __shfl(l, quad * 4 + r);

        // epilogue: oacc row = q_local = quad*4+r, col = v = nt*16+l15
#pragma unroll
        for (int nt = 0; nt < 4; ++nt) {
            const float e0 = emb0[h * 64 + nt * 16 + l15];
            const float e1 = emb1[h * 64 + nt * 16 + l15];
#pragma unroll
            for (int r = 0; r < 4; ++r) {
                const float ctx = oacc[nt][r] / lq[r];
                const float val = e0 + ctx * (e1 - e0);
                const size_t s_idx = (size_t)(b * 2048 + q0 + w * 16 + quad * 4 + r);
                ob[(s_idx * 16 + h) * 64 + nt * 16 + l15] = f2b(val);
            }
        }
    }
#undef STAGE_TILE
}

// ---------------------------------------------------------------------------
extern "C" void kernel_launch(void* const* d_in, const int* in_sizes, int n_in,
                              void* d_out, int out_size, void* d_ws, size_t ws_size,
                              hipStream_t stream)
{
    const float* x    = (const float*)d_in[0];
    const int*   amask= (const int*)d_in[1];
    const float* Wq   = (const float*)d_in[2];
    const float* Wk   = (const float*)d_in[3];
    const float* Wv   = (const float*)d_in[4];
    const float* Wo   = (const float*)d_in[5];
    const float* emb0 = (const float*)d_in[6];
    const float* emb1 = (const float*)d_in[7];
    float* out = (float*)d_out;

    char* base = (char*)d_ws;
    unsigned short* xh    = (unsigned short*)(base);                      // 16 MB
    unsigned short* ob    = xh;                                           // aliases xh
    unsigned short* Wqkvt = (unsigned short*)(base + (16u << 20));        // 6 MB
    unsigned short* Wot   = (unsigned short*)(base + (22u << 20));        // 4 MB
    unsigned short* qh    = (unsigned short*)(base + (26u << 20));        // 8 MB
    unsigned short* kh    = (unsigned short*)(base + (34u << 20));        // 2 MB
    unsigned short* vtt   = (unsigned short*)(base + (36u << 20));        // 2 MB

    conv_bf16<<<2048, 256, 0, stream>>>(x, xh, 4096 * 2048);
    transp_conv_qkv<<<dim3(48, 64), dim3(32, 8), 0, stream>>>(Wq, Wk, Wv, Wqkvt);
    transp_conv<<<dim3(64, 32), dim3(32, 8), 0, stream>>>(Wo, 1024, 2048, Wot, 1024);

    gemm_bt_mfma<1><<<dim3(24, 32), 256, 0, stream>>>(xh, Wqkvt, 4096, 1536, 2048,
                                                      nullptr, qh, kh, vtt);
    rosa_attn_mfma<<<dim3(24, 16, 2), 256, 0, stream>>>(qh, kh, vtt, amask, emb0, emb1, ob);
    gemm_bt_mfma<0><<<dim3(32, 32), 256, 0, stream>>>(ob, Wot, 4096, 2048, 1024,
                                                      out, nullptr, nullptr, nullptr);
}

// Round 5
// 235.344 us; speedup vs baseline: 1.3704x; 1.2773x over previous
//
#include <hip/hip_runtime.h>
#include <math.h>

typedef short bf16x8 __attribute__((ext_vector_type(8)));
typedef float f32x4 __attribute__((ext_vector_type(4)));
typedef unsigned int u32x2 __attribute__((ext_vector_type(2)));
typedef unsigned int u32x4 __attribute__((ext_vector_type(4)));

#define MFMA_BF16(A,B,C) __builtin_amdgcn_mfma_f32_16x16x32_bf16(A,B,C,0,0,0)

// counted vmcnt wait: loads newer than the N most recent stay in flight
#define VMCNT(N) asm volatile("s_waitcnt vmcnt(" #N ")" ::: "memory")
// raw barrier (no vmcnt drain!) with compiler memory fences on both sides
#define RBAR() do { asm volatile("" ::: "memory"); __builtin_amdgcn_s_barrier(); \
                    asm volatile("" ::: "memory"); } while (0)

// ---------------------------------------------------------------------------
// Two-sided LDS swizzle (per 64-slot / 1KB block):
//   storage: slot s holds (row = s>>2, colgrp = (s&3) ^ ((s>>3)&3))
//     -> DMA source: each 4-lane group fetches one full 64B row-line
//        (4 line-requests per quarter-wave, TA-coalescing friendly)
//   read: lane l needs (row = l&15, colgrp = l>>4)
//     -> slot s(l) = ((l&15)<<2) | ((l>>4) ^ ((l>>1)&3))
//        s%8 distinct within every 8-lane phase -> 0 LDS bank conflicts
// ---------------------------------------------------------------------------

__device__ __forceinline__ unsigned short f2b(float x) {
    union { float f; unsigned int u; } v; v.f = x;
    unsigned int r = v.u + 0x7FFFu + ((v.u >> 16) & 1u);
    return (unsigned short)(r >> 16);
}

// packed f32x2 -> bf16x2 (RNE), single instruction
__device__ __forceinline__ unsigned int cvtpk(float lo, float hi) {
    unsigned int r;
    asm("v_cvt_pk_bf16_f32 %0, %1, %2" : "=v"(r) : "v"(lo), "v"(hi));
    return r;
}

// async global->LDS DMA, 16B per lane; LDS dest = wave-uniform base + lane*16
__device__ __forceinline__ void gload16(const unsigned short* g, unsigned short* l) {
    __builtin_amdgcn_global_load_lds(
        (const __attribute__((address_space(1))) unsigned int*)(g),
        (__attribute__((address_space(3))) unsigned int*)(l),
        16, 0, 0);
}
// 4B per lane variant; LDS dest = base + lane*4
__device__ __forceinline__ void gload4(const int* g, int* l) {
    __builtin_amdgcn_global_load_lds(
        (const __attribute__((address_space(1))) unsigned int*)(g),
        (__attribute__((address_space(3))) unsigned int*)(l),
        4, 0, 0);
}

// ---------------------------------------------------------------------------
// fp32 -> bf16 convert (flat)
// ---------------------------------------------------------------------------
__global__ __launch_bounds__(256) void conv_bf16(const float* __restrict__ s,
                                                 unsigned short* __restrict__ d, int n)
{
    int i = blockIdx.x * blockDim.x + threadIdx.x;
    int stride = gridDim.x * blockDim.x;
    for (int idx = i * 4; idx < n; idx += stride * 4) {
        float4 v = *(const float4*)(s + idx);
        ushort4 o;
        o.x = f2b(v.x); o.y = f2b(v.y); o.z = f2b(v.z); o.w = f2b(v.w);
        *(ushort4*)(d + idx) = o;
    }
}

// ---------------------------------------------------------------------------
// Fused weight transpose+convert: Wq|Wk|Wv (fp32, [2048][C]) -> bf16 [C][2048]
// ---------------------------------------------------------------------------
__global__ __launch_bounds__(256) void transp_conv_qkv(const float* __restrict__ Wq,
                                                       const float* __restrict__ Wk,
                                                       const float* __restrict__ Wv,
                                                       unsigned short* __restrict__ dst)
{
    __shared__ float t[32][33];
    const int tx = threadIdx.x, ty = threadIdx.y;   // (32,8)
    int bx = blockIdx.x;
    const float* src; int C, cb, dco;
    if (bx < 32)      { src = Wq; C = 1024; cb = bx;      dco = 0; }
    else if (bx < 40) { src = Wk; C = 256;  cb = bx - 32; dco = 1024; }
    else              { src = Wv; C = 256;  cb = bx - 40; dco = 1280; }
    const int c = cb * 32 + tx;
    const int r0 = blockIdx.y * 32;
#pragma unroll
    for (int i = 0; i < 4; ++i)
        t[ty + i * 8][tx] = src[(size_t)(r0 + ty + i * 8) * C + c];
    __syncthreads();
    const int cc = cb * 32 + ty;
#pragma unroll
    for (int i = 0; i < 4; ++i)
        dst[(size_t)(dco + cc + i * 8) * 2048 + r0 + tx] = f2b(t[tx][ty + i * 8]);
}

__global__ __launch_bounds__(256) void transp_conv(const float* __restrict__ src, int R, int C,
                                                   unsigned short* __restrict__ dst, int pitch)
{
    __shared__ float t[32][33];
    const int tx = threadIdx.x, ty = threadIdx.y;
    const int c = blockIdx.x * 32 + tx;
    const int r0 = blockIdx.y * 32;
#pragma unroll
    for (int i = 0; i < 4; ++i)
        t[ty + i * 8][tx] = src[(size_t)(r0 + ty + i * 8) * C + c];
    __syncthreads();
    const int cc = blockIdx.x * 32 + ty;
#pragma unroll
    for (int i = 0; i < 4; ++i)
        dst[(size_t)(cc + i * 8) * pitch + r0 + tx] = f2b(t[tx][ty + i * 8]);
}

// ---------------------------------------------------------------------------
// bf16 MFMA GEMM, B^T input: C[M][N] = A[M][K] @ Bt[N][K]^T
// BM=128, BN=64, BK=64; 256 threads (4 waves, 2x2); double-buffered
// global_load_lds staging; two-sided swizzle (coalesced source AND
// conflict-free fragment reads); counted-vmcnt pipeline.
// ---------------------------------------------------------------------------
__device__ __forceinline__ void stage_g(const unsigned short* AgL, const unsigned short* BgL,
                                        int K, int k0s,
                                        unsigned short* Asb, unsigned short* Bsb, int w)
{
#pragma unroll
    for (int t = 0; t < 4; ++t) {
        const int sub = t >> 1, half = t & 1;
        gload16(AgL + (size_t)(half * 16) * K + k0s + sub * 32,
                Asb + sub * 4096 + (w * 2 + half) * 512);
    }
#pragma unroll
    for (int kk = 0; kk < 2; ++kk)
        gload16(BgL + k0s + kk * 32, Bsb + kk * 2048 + w * 512);
}

template <int MODE>
__global__ __launch_bounds__(256, 3) void gemm_bt_mfma(
    const unsigned short* __restrict__ A,
    const unsigned short* __restrict__ Bt,
    int M, int N, int K,
    float* __restrict__ Cf,
    unsigned short* __restrict__ qh,
    unsigned short* __restrict__ kh,
    unsigned short* __restrict__ vtt)
{
    __shared__ __align__(16) unsigned short As[2][2 * 128 * 32];
    __shared__ __align__(16) unsigned short Bs[2][2 * 64 * 32];

    const int tid = threadIdx.x;
    const int w = tid >> 6, lane = tid & 63, l15 = lane & 15, quad = lane >> 4;
    const int wm = w & 1, wn = w >> 1;
    const int m0 = blockIdx.y * 128, n0 = blockIdx.x * 64;

    // two-sided swizzle lane constants
    const int dsrow = lane >> 2;                              // DMA source row in 16-row block
    const int dscol = ((lane & 3) ^ ((lane >> 3) & 3)) * 8;   // DMA source col-group (elems)
    const int sl8   = (((lane & 15) << 2) | ((lane >> 4) ^ ((lane >> 1) & 3))) * 8; // read slot

    f32x4 acc[4][2];
    const f32x4 zero4 = {0.f, 0.f, 0.f, 0.f};
#pragma unroll
    for (int i = 0; i < 4; ++i)
#pragma unroll
        for (int j = 0; j < 2; ++j) acc[i][j] = zero4;

    const unsigned short* AgL = A  + (size_t)(m0 + w * 32 + dsrow) * K + dscol;
    const unsigned short* BgL = Bt + (size_t)(n0 + w * 16 + dsrow) * K + dscol;

    const int NT = K >> 6;
    stage_g(AgL, BgL, K, 0, &As[0][0], &Bs[0][0], w);   // prologue: tile 0, no drain

    int cb = 0;
    for (int t = 0; t < NT; ++t) {
        if (t + 1 < NT) {
            stage_g(AgL, BgL, K, (t + 1) * 64, &As[cb ^ 1][0], &Bs[cb ^ 1][0], w);
            VMCNT(6);              // wait tile t (oldest 6); tile t+1 stays in flight
        } else {
            VMCNT(0);
        }
        RBAR();                    // everyone's tile-t DMA landed

        bf16x8 af[4][2], bf[2][2];
#pragma unroll
        for (int kk = 0; kk < 2; ++kk) {
#pragma unroll
            for (int mt = 0; mt < 4; ++mt)
                af[mt][kk] = *(const bf16x8*)&As[cb][kk * 4096 + (wm * 4 + mt) * 512 + sl8];
#pragma unroll
            for (int nt = 0; nt < 2; ++nt)
                bf[nt][kk] = *(const bf16x8*)&Bs[cb][kk * 2048 + (wn * 2 + nt) * 512 + sl8];
        }
#pragma unroll
        for (int kk = 0; kk < 2; ++kk)
#pragma unroll
            for (int mt = 0; mt < 4; ++mt)
#pragma unroll
                for (int nt = 0; nt < 2; ++nt)
                    acc[mt][nt] = MFMA_BF16(af[mt][kk], bf[nt][kk], acc[mt][nt]);

        if (t + 1 < NT) RBAR();    // readers done before next iter overwrites cb
        cb ^= 1;
    }

    if (MODE == 0) {
#pragma unroll
        for (int mt = 0; mt < 4; ++mt)
#pragma unroll
            for (int nt = 0; nt < 2; ++nt) {
                const int gn = n0 + wn * 32 + nt * 16 + l15;
#pragma unroll
                for (int r = 0; r < 4; ++r) {
                    const int gm = m0 + wm * 64 + mt * 16 + quad * 4 + r;
                    Cf[(size_t)gm * N + gn] = acc[mt][nt][r];
                }
            }
    } else {
        if (n0 < 1024) {            // Q: tanh -> qh[m][n], pitch 1024
#pragma unroll
            for (int mt = 0; mt < 4; ++mt)
#pragma unroll
                for (int nt = 0; nt < 2; ++nt) {
                    const int gn = n0 + wn * 32 + nt * 16 + l15;
#pragma unroll
                    for (int r = 0; r < 4; ++r) {
                        const int gm = m0 + wm * 64 + mt * 16 + quad * 4 + r;
                        qh[(size_t)gm * 1024 + gn] = f2b(tanhf(acc[mt][nt][r]));
                    }
                }
        } else if (n0 < 1280) {     // K: tanh -> kh[m][n-1024], pitch 256
#pragma unroll
            for (int mt = 0; mt < 4; ++mt)
#pragma unroll
                for (int nt = 0; nt < 2; ++nt) {
                    const int gn = n0 + wn * 32 + nt * 16 + l15 - 1024;
#pragma unroll
                    for (int r = 0; r < 4; ++r) {
                        const int gm = m0 + wm * 64 + mt * 16 + quad * 4 + r;
                        kh[(size_t)gm * 256 + gn] = f2b(tanhf(acc[mt][nt][r]));
                    }
                }
        } else {                    // V: sigmoid -> vtt[(b*4+g)*64+v][s]
#pragma unroll
            for (int mt = 0; mt < 4; ++mt)
#pragma unroll
                for (int nt = 0; nt < 2; ++nt) {
                    const int gn = n0 + wn * 32 + nt * 16 + l15 - 1280;
                    const int g = gn >> 6, vv = gn & 63;
                    const int s0 = m0 + wm * 64 + mt * 16 + quad * 4;
                    const int b = s0 >> 11, sl = s0 & 2047;
                    ushort4 pk;
                    unsigned short* pp = (unsigned short*)&pk;
#pragma unroll
                    for (int r = 0; r < 4; ++r) {
                        float sv = 1.0f / (1.0f + __expf(-acc[mt][nt][r]));
                        pp[r] = f2b(sv);
                    }
                    *(ushort4*)&vtt[((size_t)(b * 4 + g) * 64 + vv) * 2048 + sl] = pk;
                }
        }
    }
}

// ---------------------------------------------------------------------------
// MFMA flash attention.
// Grid (24,16,2) = 768 blocks = exactly 3 blocks/CU, co-resident, per-CU
// work balanced (orbit sum = 66 for every CU under round-robin).
// Two-sided swizzled K/V staging (coalesced source + conflict-free reads);
// counted-vmcnt pipeline; cvt_pk P-packing; uint-typed Ps (TBAA);
// s_setprio around MFMA clusters. Fixed-max softmax (|s|<1).
// ---------------------------------------------------------------------------
__global__ __launch_bounds__(256, 3) void rosa_attn_mfma(
    const unsigned short* __restrict__ qh,
    const unsigned short* __restrict__ kh,
    const unsigned short* __restrict__ vtt,
    const int* __restrict__ amask,
    const float* __restrict__ emb0,
    const float* __restrict__ emb1,
    unsigned short* __restrict__ ob)
{
    __shared__ __align__(16) unsigned short Ks[2][2][2048];  // [buf][kk][blk*512 + slot*8]
    __shared__ __align__(16) unsigned short Vs[2][2][2048];
    __shared__ __align__(16) unsigned int   Ps[4][16][36];   // [wave][q][j/2] (uint-typed!)
    __shared__ int Mski[2][64];

    const int X = blockIdx.x;                     // 0..23
    int qa, qb = 0, nq;
    if (X < 8)       { qa = 31 - X; nq = 1; }
    else if (X < 16) { qa = X + 8;  nq = 1; }
    else             { qa = X - 16; qb = 31 - X; nq = 2; }

    const int h = blockIdx.y, b = blockIdx.z, g = h >> 2;
    const int tid = threadIdx.x;
    const int w = tid >> 6, lane = tid & 63, l15 = lane & 15, quad = lane >> 4;

    // two-sided swizzle lane constants
    const int dsrow = lane >> 2;
    const int dscol = ((lane & 3) ^ ((lane >> 3) & 3)) * 8;
    const int sl8   = (((lane & 15) << 2) | ((lane >> 4) ^ ((lane >> 1) & 3))) * 8;

    const unsigned short* kst = kh + (size_t)b * 2048 * 256 + g * 64
                               + (size_t)(w * 16 + dsrow) * 256 + dscol;     // + k0*256 + kk*32
    const unsigned short* vst = vtt + ((size_t)(b * 4 + g) * 64 + w * 16 + dsrow) * 2048
                               + dscol;                                      // + k0 + kk*32
    const int* mbase = amask + b * 2048;

    const f32x4 zero4 = {0.f, 0.f, 0.f, 0.f};
    const float cexp = 0.0225421100f;             // log2(e)/64

#define STAGE_TILE(k0s, buf)                                               \
    {                                                                      \
        gload16(kst + (size_t)(k0s) * 256,      &Ks[buf][0][w * 512]);     \
        gload16(kst + (size_t)(k0s) * 256 + 32, &Ks[buf][1][w * 512]);     \
        gload16(vst + (k0s),                    &Vs[buf][0][w * 512]);     \
        gload16(vst + (k0s) + 32,               &Vs[buf][1][w * 512]);     \
        if (w == 0) gload4(mbase + (k0s) + lane, &Mski[buf][0]);           \
    }

    for (int hi = 0; hi < nq; ++hi) {
        const int qt = (hi == 0) ? qa : qb;
        const int q0 = qt * 64;
        const int nkt = qt + 1;
        const int qg = q0 + w * 16 + l15;

        // Q B-fragment (n = q = l15, k = d), per wave, from global (L2-hot)
        const unsigned short* qrow = qh + ((size_t)(b * 2048 + qg) * 16 + h) * 64;
        const bf16x8 qf0 = *(const bf16x8*)(qrow + quad * 8);
        const bf16x8 qf1 = *(const bf16x8*)(qrow + 32 + quad * 8);

        f32x4 oacc[4];
#pragma unroll
        for (int t = 0; t < 4; ++t) oacc[t] = zero4;
        float psum = 0.0f;

        RBAR();                    // protect bufs from previous tile's readers
        STAGE_TILE(0, 0)           // prologue: tile 0, no drain

        int cb = 0;
        for (int kt = 0; kt < nkt; ++kt) {
            if (kt + 1 < nkt) {
                STAGE_TILE((kt + 1) * 64, cb ^ 1)
                if (w == 0) { VMCNT(5); } else { VMCNT(4); }   // wait tile kt only
            } else {
                VMCNT(0);
            }
            RBAR();                // everyone's tile-kt DMA landed

            const bool diag = (kt == qt);
            const int ntlim = diag ? (w + 1) : 4;

            // S^T = K.Q^T per 16x16 sub-tile; fixed-max softmax; pack P^T
#pragma unroll
            for (int nt = 0; nt < 4; ++nt) {
                u32x2 pk2;
                if (nt < ntlim) {
                    bf16x8 kf0 = *(const bf16x8*)&Ks[cb][0][nt * 512 + sl8];
                    bf16x8 kf1 = *(const bf16x8*)&Ks[cb][1][nt * 512 + sl8];
                    __builtin_amdgcn_s_setprio(1);
                    f32x4 sc = MFMA_BF16(kf0, qf0, zero4);
                    sc = MFMA_BF16(kf1, qf1, sc);
                    __builtin_amdgcn_s_setprio(0);
                    const int4 m4 = *(const int4*)&Mski[cb][nt * 16 + quad * 4];
                    const int* mm = (const int*)&m4;
                    const bool dnw = diag && (nt == w);
                    float p[4];
#pragma unroll
                    for (int r = 0; r < 4; ++r) {
                        float pv = __builtin_exp2f(sc[r] * cexp);
                        bool valid = (mm[r] != 0);
                        if (dnw) valid = valid && ((quad * 4 + r) <= l15);
                        pv = valid ? pv : 0.0f;
                        psum += pv;
                        p[r] = pv;
                    }
                    pk2[0] = cvtpk(p[0], p[1]);
                    pk2[1] = cvtpk(p[2], p[3]);
                } else {
                    pk2[0] = 0u; pk2[1] = 0u;
                }
                *(u32x2*)&Ps[w][l15][nt * 8 + quad * 2] = pk2;   // P^T packed along j
            }

            // O += P.V (uint-typed Ps load keeps the write->read dependence
            // visible; in-wave DS ordering covers the hazard at HW level)
            const bf16x8 pf0 = __builtin_bit_cast(bf16x8, *(const u32x4*)&Ps[w][l15][quad * 4]);
            const bf16x8 pf1 = __builtin_bit_cast(bf16x8, *(const u32x4*)&Ps[w][l15][16 + quad * 4]);
            __builtin_amdgcn_s_setprio(1);
#pragma unroll
            for (int nt = 0; nt < 4; ++nt) {
                bf16x8 vf0 = *(const bf16x8*)&Vs[cb][0][nt * 512 + sl8];
                bf16x8 vf1 = *(const bf16x8*)&Vs[cb][1][nt * 512 + sl8];
                oacc[nt] = MFMA_BF16(pf0, vf0, oacc[nt]);
                oacc[nt] = MFMA_BF16(pf1, vf1, oacc[nt]);
            }
            __builtin_amdgcn_s_setprio(0);

            if (kt + 1 < nkt) {
                RBAR();            // readers done before next iter overwrites cb
                cb ^= 1;
            }
        }

        // l reduction: sum partials across the 4 quads holding the same q
        float l = psum;
        l += __shfl_xor(l, 16);
        l += __shfl_xor(l, 32);
        float lq[4];
#pragma unroll
        for (int r = 0; r < 4; ++r) lq[r] = __shfl(l, quad * 4 + r);

        // epilogue: oacc row = q_local = quad*4+r, col = v = nt*16+l15
#pragma unroll
        for (int nt = 0; nt < 4; ++nt) {
            const float e0 = emb0[h * 64 + nt * 16 + l15];
            const float e1 = emb1[h * 64 + nt * 16 + l15];
#pragma unroll
            for (int r = 0; r < 4; ++r) {
                const float ctx = oacc[nt][r] / lq[r];
                const float val = e0 + ctx * (e1 - e0);
                const size_t s_idx = (size_t)(b * 2048 + q0 + w * 16 + quad * 4 + r);
                ob[(s_idx * 16 + h) * 64 + nt * 16 + l15] = f2b(val);
            }
        }
    }
#undef STAGE_TILE
}

// ---------------------------------------------------------------------------
extern "C" void kernel_launch(void* const* d_in, const int* in_sizes, int n_in,
                              void* d_out, int out_size, void* d_ws, size_t ws_size,
                              hipStream_t stream)
{
    const float* x    = (const float*)d_in[0];
    const int*   amask= (const int*)d_in[1];
    const float* Wq   = (const float*)d_in[2];
    const float* Wk   = (const float*)d_in[3];
    const float* Wv   = (const float*)d_in[4];
    const float* Wo   = (const float*)d_in[5];
    const float* emb0 = (const float*)d_in[6];
    const float* emb1 = (const float*)d_in[7];
    float* out = (float*)d_out;

    char* base = (char*)d_ws;
    unsigned short* xh    = (unsigned short*)(base);                      // 16 MB
    unsigned short* ob    = xh;                                           // aliases xh
    unsigned short* Wqkvt = (unsigned short*)(base + (16u << 20));        // 6 MB
    unsigned short* Wot   = (unsigned short*)(base + (22u << 20));        // 4 MB
    unsigned short* qh    = (unsigned short*)(base + (26u << 20));        // 8 MB
    unsigned short* kh    = (unsigned short*)(base + (34u << 20));        // 2 MB
    unsigned short* vtt   = (unsigned short*)(base + (36u << 20));        // 2 MB

    conv_bf16<<<2048, 256, 0, stream>>>(x, xh, 4096 * 2048);
    transp_conv_qkv<<<dim3(48, 64), dim3(32, 8), 0, stream>>>(Wq, Wk, Wv, Wqkvt);
    transp_conv<<<dim3(64, 32), dim3(32, 8), 0, stream>>>(Wo, 1024, 2048, Wot, 1024);

    gemm_bt_mfma<1><<<dim3(24, 32), 256, 0, stream>>>(xh, Wqkvt, 4096, 1536, 2048,
                                                      nullptr, qh, kh, vtt);
    rosa_attn_mfma<<<dim3(24, 16, 2), 256, 0, stream>>>(qh, kh, vtt, amask, emb0, emb1, ob);
    gemm_bt_mfma<0><<<dim3(32, 32), 256, 0, stream>>>(ob, Wot, 4096, 2048, 1024,
                                                      out, nullptr, nullptr, nullptr);
}

// Round 6
// 229.842 us; speedup vs baseline: 1.4032x; 1.0239x over previous
//
#include <hip/hip_runtime.h>
#include <math.h>

typedef short bf16x8 __attribute__((ext_vector_type(8)));
typedef float f32x4 __attribute__((ext_vector_type(4)));
typedef unsigned int u32x2 __attribute__((ext_vector_type(2)));
typedef unsigned int u32x4 __attribute__((ext_vector_type(4)));

#define MFMA_BF16(A,B,C) __builtin_amdgcn_mfma_f32_16x16x32_bf16(A,B,C,0,0,0)

// counted vmcnt wait: loads newer than the N most recent stay in flight
#define VMCNT(N) asm volatile("s_waitcnt vmcnt(" #N ")" ::: "memory")
#define LGKM0()  asm volatile("s_waitcnt lgkmcnt(0)" ::: "memory")
// raw barrier (no vmcnt drain!) with compiler memory fences on both sides
#define RBAR() do { asm volatile("" ::: "memory"); __builtin_amdgcn_s_barrier(); \
                    asm volatile("" ::: "memory"); } while (0)

__device__ __forceinline__ unsigned short f2b(float x) {
    union { float f; unsigned int u; } v; v.f = x;
    unsigned int r = v.u + 0x7FFFu + ((v.u >> 16) & 1u);
    return (unsigned short)(r >> 16);
}

// packed f32x2 -> bf16x2 (RNE), single instruction
__device__ __forceinline__ unsigned int cvtpk(float lo, float hi) {
    unsigned int r;
    asm("v_cvt_pk_bf16_f32 %0, %1, %2" : "=v"(r) : "v"(lo), "v"(hi));
    return r;
}

// async global->LDS DMA, 16B per lane; LDS dest = wave-uniform base + lane*16
__device__ __forceinline__ void gload16(const unsigned short* g, unsigned short* l) {
    __builtin_amdgcn_global_load_lds(
        (const __attribute__((address_space(1))) unsigned int*)(g),
        (__attribute__((address_space(3))) unsigned int*)(l),
        16, 0, 0);
}

// ---------------------------------------------------------------------------
// fp32 -> bf16 convert (flat)
// ---------------------------------------------------------------------------
__global__ __launch_bounds__(256) void conv_bf16(const float* __restrict__ s,
                                                 unsigned short* __restrict__ d, int n)
{
    int i = blockIdx.x * blockDim.x + threadIdx.x;
    int stride = gridDim.x * blockDim.x;
    for (int idx = i * 4; idx < n; idx += stride * 4) {
        float4 v = *(const float4*)(s + idx);
        ushort4 o;
        o.x = f2b(v.x); o.y = f2b(v.y); o.z = f2b(v.z); o.w = f2b(v.w);
        *(ushort4*)(d + idx) = o;
    }
}

// ---------------------------------------------------------------------------
// Fused weight transpose+convert: Wq|Wk|Wv (fp32, [2048][C]) -> bf16 [C][2048]
// ---------------------------------------------------------------------------
__global__ __launch_bounds__(256) void transp_conv_qkv(const float* __restrict__ Wq,
                                                       const float* __restrict__ Wk,
                                                       const float* __restrict__ Wv,
                                                       unsigned short* __restrict__ dst)
{
    __shared__ float t[32][33];
    const int tx = threadIdx.x, ty = threadIdx.y;   // (32,8)
    int bx = blockIdx.x;
    const float* src; int C, cb, dco;
    if (bx < 32)      { src = Wq; C = 1024; cb = bx;      dco = 0; }
    else if (bx < 40) { src = Wk; C = 256;  cb = bx - 32; dco = 1024; }
    else              { src = Wv; C = 256;  cb = bx - 40; dco = 1280; }
    const int c = cb * 32 + tx;
    const int r0 = blockIdx.y * 32;
#pragma unroll
    for (int i = 0; i < 4; ++i)
        t[ty + i * 8][tx] = src[(size_t)(r0 + ty + i * 8) * C + c];
    __syncthreads();
    const int cc = cb * 32 + ty;
#pragma unroll
    for (int i = 0; i < 4; ++i)
        dst[(size_t)(dco + cc + i * 8) * 2048 + r0 + tx] = f2b(t[tx][ty + i * 8]);
}

__global__ __launch_bounds__(256) void transp_conv(const float* __restrict__ src, int R, int C,
                                                   unsigned short* __restrict__ dst, int pitch)
{
    __shared__ float t[32][33];
    const int tx = threadIdx.x, ty = threadIdx.y;
    const int c = blockIdx.x * 32 + tx;
    const int r0 = blockIdx.y * 32;
#pragma unroll
    for (int i = 0; i < 4; ++i)
        t[ty + i * 8][tx] = src[(size_t)(r0 + ty + i * 8) * C + c];
    __syncthreads();
    const int cc = blockIdx.x * 32 + ty;
#pragma unroll
    for (int i = 0; i < 4; ++i)
        dst[(size_t)(cc + i * 8) * pitch + r0 + tx] = f2b(t[tx][ty + i * 8]);
}

// ---------------------------------------------------------------------------
// bf16 MFMA GEMM, B^T input (unchanged from R5 — proven: 0 conflicts,
// coalesced DMA source via two-sided swizzle, counted-vmcnt pipeline).
// ---------------------------------------------------------------------------
__device__ __forceinline__ void stage_g(const unsigned short* AgL, const unsigned short* BgL,
                                        int K, int k0s,
                                        unsigned short* Asb, unsigned short* Bsb, int w)
{
#pragma unroll
    for (int t = 0; t < 4; ++t) {
        const int sub = t >> 1, half = t & 1;
        gload16(AgL + (size_t)(half * 16) * K + k0s + sub * 32,
                Asb + sub * 4096 + (w * 2 + half) * 512);
    }
#pragma unroll
    for (int kk = 0; kk < 2; ++kk)
        gload16(BgL + k0s + kk * 32, Bsb + kk * 2048 + w * 512);
}

template <int MODE>
__global__ __launch_bounds__(256, 3) void gemm_bt_mfma(
    const unsigned short* __restrict__ A,
    const unsigned short* __restrict__ Bt,
    int M, int N, int K,
    float* __restrict__ Cf,
    unsigned short* __restrict__ qh,
    unsigned short* __restrict__ kh,
    unsigned short* __restrict__ vtt)
{
    __shared__ __align__(16) unsigned short As[2][2 * 128 * 32];
    __shared__ __align__(16) unsigned short Bs[2][2 * 64 * 32];

    const int tid = threadIdx.x;
    const int w = tid >> 6, lane = tid & 63, l15 = lane & 15, quad = lane >> 4;
    const int wm = w & 1, wn = w >> 1;
    const int m0 = blockIdx.y * 128, n0 = blockIdx.x * 64;

    // two-sided swizzle lane constants
    const int dsrow = lane >> 2;                              // DMA source row in 16-row block
    const int dscol = ((lane & 3) ^ ((lane >> 3) & 3)) * 8;   // DMA source col-group (elems)
    const int sl8   = (((lane & 15) << 2) | ((lane >> 4) ^ ((lane >> 1) & 3))) * 8; // read slot

    f32x4 acc[4][2];
    const f32x4 zero4 = {0.f, 0.f, 0.f, 0.f};
#pragma unroll
    for (int i = 0; i < 4; ++i)
#pragma unroll
        for (int j = 0; j < 2; ++j) acc[i][j] = zero4;

    const unsigned short* AgL = A  + (size_t)(m0 + w * 32 + dsrow) * K + dscol;
    const unsigned short* BgL = Bt + (size_t)(n0 + w * 16 + dsrow) * K + dscol;

    const int NT = K >> 6;
    stage_g(AgL, BgL, K, 0, &As[0][0], &Bs[0][0], w);   // prologue: tile 0, no drain

    int cb = 0;
    for (int t = 0; t < NT; ++t) {
        if (t + 1 < NT) {
            stage_g(AgL, BgL, K, (t + 1) * 64, &As[cb ^ 1][0], &Bs[cb ^ 1][0], w);
            VMCNT(6);              // wait tile t (oldest 6); tile t+1 stays in flight
        } else {
            VMCNT(0);
        }
        RBAR();                    // everyone's tile-t DMA landed

        bf16x8 af[4][2], bf[2][2];
#pragma unroll
        for (int kk = 0; kk < 2; ++kk) {
#pragma unroll
            for (int mt = 0; mt < 4; ++mt)
                af[mt][kk] = *(const bf16x8*)&As[cb][kk * 4096 + (wm * 4 + mt) * 512 + sl8];
#pragma unroll
            for (int nt = 0; nt < 2; ++nt)
                bf[nt][kk] = *(const bf16x8*)&Bs[cb][kk * 2048 + (wn * 2 + nt) * 512 + sl8];
        }
#pragma unroll
        for (int kk = 0; kk < 2; ++kk)
#pragma unroll
            for (int mt = 0; mt < 4; ++mt)
#pragma unroll
                for (int nt = 0; nt < 2; ++nt)
                    acc[mt][nt] = MFMA_BF16(af[mt][kk], bf[nt][kk], acc[mt][nt]);

        if (t + 1 < NT) RBAR();    // readers done before next iter overwrites cb
        cb ^= 1;
    }

    if (MODE == 0) {
#pragma unroll
        for (int mt = 0; mt < 4; ++mt)
#pragma unroll
            for (int nt = 0; nt < 2; ++nt) {
                const int gn = n0 + wn * 32 + nt * 16 + l15;
#pragma unroll
                for (int r = 0; r < 4; ++r) {
                    const int gm = m0 + wm * 64 + mt * 16 + quad * 4 + r;
                    Cf[(size_t)gm * N + gn] = acc[mt][nt][r];
                }
            }
    } else {
        if (n0 < 1024) {            // Q: tanh -> qh[m][n], pitch 1024
#pragma unroll
            for (int mt = 0; mt < 4; ++mt)
#pragma unroll
                for (int nt = 0; nt < 2; ++nt) {
                    const int gn = n0 + wn * 32 + nt * 16 + l15;
#pragma unroll
                    for (int r = 0; r < 4; ++r) {
                        const int gm = m0 + wm * 64 + mt * 16 + quad * 4 + r;
                        qh[(size_t)gm * 1024 + gn] = f2b(tanhf(acc[mt][nt][r]));
                    }
                }
        } else if (n0 < 1280) {     // K: tanh -> kh[m][n-1024], pitch 256
#pragma unroll
            for (int mt = 0; mt < 4; ++mt)
#pragma unroll
                for (int nt = 0; nt < 2; ++nt) {
                    const int gn = n0 + wn * 32 + nt * 16 + l15 - 1024;
#pragma unroll
                    for (int r = 0; r < 4; ++r) {
                        const int gm = m0 + wm * 64 + mt * 16 + quad * 4 + r;
                        kh[(size_t)gm * 256 + gn] = f2b(tanhf(acc[mt][nt][r]));
                    }
                }
        } else {                    // V: sigmoid -> vtt[(b*4+g)*64+v][s]
#pragma unroll
            for (int mt = 0; mt < 4; ++mt)
#pragma unroll
                for (int nt = 0; nt < 2; ++nt) {
                    const int gn = n0 + wn * 32 + nt * 16 + l15 - 1280;
                    const int g = gn >> 6, vv = gn & 63;
                    const int s0 = m0 + wm * 64 + mt * 16 + quad * 4;
                    const int b = s0 >> 11, sl = s0 & 2047;
                    ushort4 pk;
                    unsigned short* pp = (unsigned short*)&pk;
#pragma unroll
                    for (int r = 0; r < 4; ++r) {
                        float sv = 1.0f / (1.0f + __expf(-acc[mt][nt][r]));
                        pp[r] = f2b(sv);
                    }
                    *(ushort4*)&vtt[((size_t)(b * 4 + g) * 64 + vv) * 2048 + sl] = pk;
                }
        }
    }
}

// ---------------------------------------------------------------------------
// MFMA flash attention.
// R6: (1) mask hoisted to a per-block 32-bit chunk-full bitmap -> inner loop
//     is bare exp2 (+ lane-constant causal multiplier on the diag sub-tile);
//     slow path (padded masks) loads int4 mask in-phase, correct but rare.
// (2) LDS = 40960 B exactly (Ks 16K + Vs 16K + Ps[4][16][32] 8K, XOR-swizzled
//     rows, Mski eliminated) -> 4 blocks/CU.
// (3) grid (32,16,2) = 1024 blocks; qt = class_a[(m + (hb>>3)) & 3] with
//     class_a = {a,15-a,16+a,31-a}: round-robin co-residents (X fixed, hb+8k)
//     get 4 distinct classes -> per-CU work = 66 exactly.
// Two-sided swizzled K/V staging; counted vmcnt; cvt_pk; setprio.
// ---------------------------------------------------------------------------
__global__ __launch_bounds__(256, 4) void rosa_attn_mfma(
    const unsigned short* __restrict__ qh,
    const unsigned short* __restrict__ kh,
    const unsigned short* __restrict__ vtt,
    const int* __restrict__ amask,
    const float* __restrict__ emb0,
    const float* __restrict__ emb1,
    unsigned short* __restrict__ ob)
{
    __shared__ __align__(16) unsigned short Ks[2][2][2048];  // 16 KB
    __shared__ __align__(16) unsigned short Vs[2][2][2048];  // 16 KB
    __shared__ __align__(16) unsigned int   Ps[4][16][32];   // 8 KB (uint-typed)

    const int a = blockIdx.x & 7, m = blockIdx.x >> 3;
    const int h = blockIdx.y, b = blockIdx.z, g = h >> 2;
    const int hb = h + 16 * b;
    const int sel = (m + (hb >> 3)) & 3;
    const int qt = (sel == 0) ? a : (sel == 1) ? 15 - a : (sel == 2) ? 16 + a : 31 - a;

    const int tid = threadIdx.x;
    const int w = tid >> 6, lane = tid & 63, l15 = lane & 15, quad = lane >> 4;

    // two-sided swizzle lane constants (same as GEMM)
    const int dsrow = lane >> 2;
    const int dscol = ((lane & 3) ^ ((lane >> 3) & 3)) * 8;
    const int sl8   = (((lane & 15) << 2) | ((lane >> 4) ^ ((lane >> 1) & 3))) * 8;
    const int pxor  = (l15 & 7) << 2;              // Ps row word-swizzle

    const unsigned short* kst = kh + (size_t)b * 2048 * 256 + g * 64
                               + (size_t)(w * 16 + dsrow) * 256 + dscol;
    const unsigned short* vst = vtt + ((size_t)(b * 4 + g) * 64 + w * 16 + dsrow) * 2048
                               + dscol;
    const int* mbase = amask + b * 2048;

    const f32x4 zero4 = {0.f, 0.f, 0.f, 0.f};
    const float cexp = 0.0225421100f;              // log2(e)/64

    // lane-constant causal multiplier for the diagonal 16x16 sub-tile
    float cm[4];
#pragma unroll
    for (int r = 0; r < 4; ++r) cm[r] = (quad * 4 + r <= l15) ? 1.0f : 0.0f;

    // ---- per-block mask chunk-full bitmap (32 bits, chunk c = k [64c,64c+64))
    const int4 mv0 = *(const int4*)(mbase + tid * 8);
    const int4 mv1 = *(const int4*)(mbase + tid * 8 + 4);

    const int q0 = qt * 64;
    const int nkt = qt + 1;

    // Q B-fragment (n = q = l15, k = d), per wave, from global (L2-hot)
    const unsigned short* qrow = qh + ((size_t)(b * 2048 + q0 + w * 16 + l15) * 16 + h) * 64;
    const bf16x8 qf0 = *(const bf16x8*)(qrow + quad * 8);
    const bf16x8 qf1 = *(const bf16x8*)(qrow + 32 + quad * 8);

#define STAGE_TILE(k0s, buf)                                               \
    {                                                                      \
        gload16(kst + (size_t)(k0s) * 256,      &Ks[buf][0][w * 512]);     \
        gload16(kst + (size_t)(k0s) * 256 + 32, &Ks[buf][1][w * 512]);     \
        gload16(vst + (k0s),                    &Vs[buf][0][w * 512]);     \
        gload16(vst + (k0s) + 32,               &Vs[buf][1][w * 512]);     \
    }

    STAGE_TILE(0, 0)               // prologue: tile 0 DMA in flight

    // finish the bitmap (compiler waits mv loads; stage stays in flight)
    const bool f8 = mv0.x && mv0.y && mv0.z && mv0.w && mv1.x && mv1.y && mv1.z && mv1.w;
    const unsigned long long bal = __ballot(f8);
    const bool bytefull = ((bal >> ((lane & 7) * 8)) & 0xFFull) == 0xFFull;
    const unsigned long long bal2 = __ballot(bytefull && (lane < 8));
    if (lane == 0) Ps[0][0][w] = (unsigned int)(bal2 & 0xFFull);
    RBAR();
    const unsigned int mflags = Ps[0][0][0] | (Ps[0][0][1] << 8)
                              | (Ps[0][0][2] << 16) | (Ps[0][0][3] << 24);
    LGKM0();                       // flag reads processed before Ps is reused
    RBAR();

    f32x4 oacc[4];
#pragma unroll
    for (int t = 0; t < 4; ++t) oacc[t] = zero4;
    float psum = 0.0f;

    int cb = 0;
    for (int kt = 0; kt < nkt; ++kt) {
        if (kt + 1 < nkt) {
            STAGE_TILE((kt + 1) * 64, cb ^ 1)
            VMCNT(4);              // tile kt landed; tile kt+1 stays in flight
        } else {
            VMCNT(0);
        }
        RBAR();                    // everyone's tile-kt DMA landed

        const int k0 = kt * 64;
        const bool diag = (kt == qt);
        const bool full = (mflags >> kt) & 1u;
        const int ntlim = diag ? (w + 1) : 4;

        // S^T = K.Q^T per 16x16 sub-tile; fixed-max softmax; pack P^T
#pragma unroll
        for (int nt = 0; nt < 4; ++nt) {
            u32x2 pk2;
            if (nt < ntlim) {
                bf16x8 kf0 = *(const bf16x8*)&Ks[cb][0][nt * 512 + sl8];
                bf16x8 kf1 = *(const bf16x8*)&Ks[cb][1][nt * 512 + sl8];
                __builtin_amdgcn_s_setprio(1);
                f32x4 sc = MFMA_BF16(kf0, qf0, zero4);
                sc = MFMA_BF16(kf1, qf1, sc);
                __builtin_amdgcn_s_setprio(0);
                const bool dnw = diag && (nt == w);
                float p[4];
                if (full) {
                    if (dnw) {
#pragma unroll
                        for (int r = 0; r < 4; ++r)
                            p[r] = __builtin_exp2f(sc[r] * cexp) * cm[r];
                    } else {
#pragma unroll
                        for (int r = 0; r < 4; ++r)
                            p[r] = __builtin_exp2f(sc[r] * cexp);
                    }
                } else {           // padded-mask slow path (absent in this input)
                    const int4 m4 = *(const int4*)(mbase + k0 + nt * 16 + quad * 4);
                    const int* mm = (const int*)&m4;
#pragma unroll
                    for (int r = 0; r < 4; ++r) {
                        float pv = __builtin_exp2f(sc[r] * cexp);
                        if (dnw) pv *= cm[r];
                        p[r] = (mm[r] != 0) ? pv : 0.0f;
                    }
                }
                psum += (p[0] + p[1]) + (p[2] + p[3]);
                pk2[0] = cvtpk(p[0], p[1]);
                pk2[1] = cvtpk(p[2], p[3]);
            } else {
                pk2[0] = 0u; pk2[1] = 0u;
            }
            *(u32x2*)&Ps[w][l15][(nt * 8 + quad * 2) ^ pxor] = pk2;   // P^T, swizzled
        }

        // O += P.V (uint-typed Ps keeps the dependence visible; in-wave DS order)
        const bf16x8 pf0 = __builtin_bit_cast(bf16x8, *(const u32x4*)&Ps[w][l15][(quad * 4) ^ pxor]);
        const bf16x8 pf1 = __builtin_bit_cast(bf16x8, *(const u32x4*)&Ps[w][l15][(16 + quad * 4) ^ pxor]);
        __builtin_amdgcn_s_setprio(1);
#pragma unroll
        for (int nt = 0; nt < 4; ++nt) {
            bf16x8 vf0 = *(const bf16x8*)&Vs[cb][0][nt * 512 + sl8];
            bf16x8 vf1 = *(const bf16x8*)&Vs[cb][1][nt * 512 + sl8];
            oacc[nt] = MFMA_BF16(pf0, vf0, oacc[nt]);
            oacc[nt] = MFMA_BF16(pf1, vf1, oacc[nt]);
        }
        __builtin_amdgcn_s_setprio(0);

        if (kt + 1 < nkt) {
            RBAR();                // readers done before next iter overwrites cb
            cb ^= 1;
        }
    }

    // l reduction: sum partials across the 4 quads holding the same q
    float l = psum;
    l += __shfl_xor(l, 16);
    l += __shfl_xor(l, 32);
    float lq[4];
#pragma unroll
    for (int r = 0; r < 4; ++r) lq[r] = __shfl(l, quad * 4 + r);

    // epilogue: oacc row = q_local = quad*4+r, col = v = nt*16+l15
#pragma unroll
    for (int nt = 0; nt < 4; ++nt) {
        const float e0 = emb0[h * 64 + nt * 16 + l15];
        const float e1 = emb1[h * 64 + nt * 16 + l15];
#pragma unroll
        for (int r = 0; r < 4; ++r) {
            const float ctx = oacc[nt][r] / lq[r];
            const float val = e0 + ctx * (e1 - e0);
            const size_t s_idx = (size_t)(b * 2048 + q0 + w * 16 + quad * 4 + r);
            ob[(s_idx * 16 + h) * 64 + nt * 16 + l15] = f2b(val);
        }
    }
#undef STAGE_TILE
}

// ---------------------------------------------------------------------------
extern "C" void kernel_launch(void* const* d_in, const int* in_sizes, int n_in,
                              void* d_out, int out_size, void* d_ws, size_t ws_size,
                              hipStream_t stream)
{
    const float* x    = (const float*)d_in[0];
    const int*   amask= (const int*)d_in[1];
    const float* Wq   = (const float*)d_in[2];
    const float* Wk   = (const float*)d_in[3];
    const float* Wv   = (const float*)d_in[4];
    const float* Wo   = (const float*)d_in[5];
    const float* emb0 = (const float*)d_in[6];
    const float* emb1 = (const float*)d_in[7];
    float* out = (float*)d_out;

    char* base = (char*)d_ws;
    unsigned short* xh    = (unsigned short*)(base);                      // 16 MB
    unsigned short* ob    = xh;                                           // aliases xh
    unsigned short* Wqkvt = (unsigned short*)(base + (16u << 20));        // 6 MB
    unsigned short* Wot   = (unsigned short*)(base + (22u << 20));        // 4 MB
    unsigned short* qh    = (unsigned short*)(base + (26u << 20));        // 8 MB
    unsigned short* kh    = (unsigned short*)(base + (34u << 20));        // 2 MB
    unsigned short* vtt   = (unsigned short*)(base + (36u << 20));        // 2 MB

    conv_bf16<<<2048, 256, 0, stream>>>(x, xh, 4096 * 2048);
    transp_conv_qkv<<<dim3(48, 64), dim3(32, 8), 0, stream>>>(Wq, Wk, Wv, Wqkvt);
    transp_conv<<<dim3(64, 32), dim3(32, 8), 0, stream>>>(Wo, 1024, 2048, Wot, 1024);

    gemm_bt_mfma<1><<<dim3(24, 32), 256, 0, stream>>>(xh, Wqkvt, 4096, 1536, 2048,
                                                      nullptr, qh, kh, vtt);
    rosa_attn_mfma<<<dim3(32, 16, 2), 256, 0, stream>>>(qh, kh, vtt, amask, emb0, emb1, ob);
    gemm_bt_mfma<0><<<dim3(32, 32), 256, 0, stream>>>(ob, Wot, 4096, 2048, 1024,
                                                      out, nullptr, nullptr, nullptr);
}

// Round 7
// 223.644 us; speedup vs baseline: 1.4421x; 1.0277x over previous
//
#include <hip/hip_runtime.h>
#include <math.h>

typedef short bf16x8 __attribute__((ext_vector_type(8)));
typedef float f32x4 __attribute__((ext_vector_type(4)));
typedef float f32x16 __attribute__((ext_vector_type(16)));
typedef unsigned int u32x2 __attribute__((ext_vector_type(2)));
typedef unsigned int u32x4 __attribute__((ext_vector_type(4)));

#define MFMA_BF16(A,B,C) __builtin_amdgcn_mfma_f32_16x16x32_bf16(A,B,C,0,0,0)
#define MFMA32(A,B,C)    __builtin_amdgcn_mfma_f32_32x32x16_bf16(A,B,C,0,0,0)

// counted vmcnt wait: loads newer than the N most recent stay in flight
#define VMCNT(N) asm volatile("s_waitcnt vmcnt(" #N ")" ::: "memory")
// raw barrier (no vmcnt drain!) with compiler memory fences on both sides
#define RBAR() do { asm volatile("" ::: "memory"); __builtin_amdgcn_s_barrier(); \
                    asm volatile("" ::: "memory"); } while (0)
// in-place half-swap: a = [a_lo | b_lo], b = [a_hi | b_hi]
#define PERMSWAP(a, b) asm volatile("v_permlane32_swap_b32 %0, %1" : "+v"(a), "+v"(b))

__device__ __forceinline__ unsigned short f2b(float x) {
    union { float f; unsigned int u; } v; v.f = x;
    unsigned int r = v.u + 0x7FFFu + ((v.u >> 16) & 1u);
    return (unsigned short)(r >> 16);
}

// packed f32x2 -> bf16x2 (RNE), single instruction
__device__ __forceinline__ unsigned int cvtpk(float lo, float hi) {
    unsigned int r;
    asm("v_cvt_pk_bf16_f32 %0, %1, %2" : "=v"(r) : "v"(lo), "v"(hi));
    return r;
}

// async global->LDS DMA, 16B per lane; LDS dest = wave-uniform base + lane*16
__device__ __forceinline__ void gload16(const unsigned short* g, unsigned short* l) {
    __builtin_amdgcn_global_load_lds(
        (const __attribute__((address_space(1))) unsigned int*)(g),
        (__attribute__((address_space(3))) unsigned int*)(l),
        16, 0, 0);
}

// ---------------------------------------------------------------------------
// fp32 -> bf16 convert (flat)
// ---------------------------------------------------------------------------
__global__ __launch_bounds__(256) void conv_bf16(const float* __restrict__ s,
                                                 unsigned short* __restrict__ d, int n)
{
    int i = blockIdx.x * blockDim.x + threadIdx.x;
    int stride = gridDim.x * blockDim.x;
    for (int idx = i * 4; idx < n; idx += stride * 4) {
        float4 v = *(const float4*)(s + idx);
        ushort4 o;
        o.x = f2b(v.x); o.y = f2b(v.y); o.z = f2b(v.z); o.w = f2b(v.w);
        *(ushort4*)(d + idx) = o;
    }
}

// ---------------------------------------------------------------------------
// Fused weight transpose+convert: Wq|Wk|Wv (fp32, [2048][C]) -> bf16 [C][2048]
// ---------------------------------------------------------------------------
__global__ __launch_bounds__(256) void transp_conv_qkv(const float* __restrict__ Wq,
                                                       const float* __restrict__ Wk,
                                                       const float* __restrict__ Wv,
                                                       unsigned short* __restrict__ dst)
{
    __shared__ float t[32][33];
    const int tx = threadIdx.x, ty = threadIdx.y;   // (32,8)
    int bx = blockIdx.x;
    const float* src; int C, cb, dco;
    if (bx < 32)      { src = Wq; C = 1024; cb = bx;      dco = 0; }
    else if (bx < 40) { src = Wk; C = 256;  cb = bx - 32; dco = 1024; }
    else              { src = Wv; C = 256;  cb = bx - 40; dco = 1280; }
    const int c = cb * 32 + tx;
    const int r0 = blockIdx.y * 32;
#pragma unroll
    for (int i = 0; i < 4; ++i)
        t[ty + i * 8][tx] = src[(size_t)(r0 + ty + i * 8) * C + c];
    __syncthreads();
    const int cc = cb * 32 + ty;
#pragma unroll
    for (int i = 0; i < 4; ++i)
        dst[(size_t)(dco + cc + i * 8) * 2048 + r0 + tx] = f2b(t[tx][ty + i * 8]);
}

__global__ __launch_bounds__(256) void transp_conv(const float* __restrict__ src, int R, int C,
                                                   unsigned short* __restrict__ dst, int pitch)
{
    __shared__ float t[32][33];
    const int tx = threadIdx.x, ty = threadIdx.y;
    const int c = blockIdx.x * 32 + tx;
    const int r0 = blockIdx.y * 32;
#pragma unroll
    for (int i = 0; i < 4; ++i)
        t[ty + i * 8][tx] = src[(size_t)(r0 + ty + i * 8) * C + c];
    __syncthreads();
    const int cc = blockIdx.x * 32 + ty;
#pragma unroll
    for (int i = 0; i < 4; ++i)
        dst[(size_t)(cc + i * 8) * pitch + r0 + tx] = f2b(t[tx][ty + i * 8]);
}

// ---------------------------------------------------------------------------
// bf16 MFMA GEMM, B^T input (structure unchanged from R5/R6 — proven:
// 0 conflicts, coalesced DMA source via two-sided swizzle, counted vmcnt).
// Only change: Q epilogue folds cexp = log2(e)/64 into qh (Q feeds only the
// attention QK^T; one cexp factor total).
// ---------------------------------------------------------------------------
__device__ __forceinline__ void stage_g(const unsigned short* AgL, const unsigned short* BgL,
                                        int K, int k0s,
                                        unsigned short* Asb, unsigned short* Bsb, int w)
{
#pragma unroll
    for (int t = 0; t < 4; ++t) {
        const int sub = t >> 1, half = t & 1;
        gload16(AgL + (size_t)(half * 16) * K + k0s + sub * 32,
                Asb + sub * 4096 + (w * 2 + half) * 512);
    }
#pragma unroll
    for (int kk = 0; kk < 2; ++kk)
        gload16(BgL + k0s + kk * 32, Bsb + kk * 2048 + w * 512);
}

template <int MODE>
__global__ __launch_bounds__(256, 3) void gemm_bt_mfma(
    const unsigned short* __restrict__ A,
    const unsigned short* __restrict__ Bt,
    int M, int N, int K,
    float* __restrict__ Cf,
    unsigned short* __restrict__ qh,
    unsigned short* __restrict__ kh,
    unsigned short* __restrict__ vtt)
{
    __shared__ __align__(16) unsigned short As[2][2 * 128 * 32];
    __shared__ __align__(16) unsigned short Bs[2][2 * 64 * 32];

    const int tid = threadIdx.x;
    const int w = tid >> 6, lane = tid & 63, l15 = lane & 15, quad = lane >> 4;
    const int wm = w & 1, wn = w >> 1;
    const int m0 = blockIdx.y * 128, n0 = blockIdx.x * 64;

    const int dsrow = lane >> 2;
    const int dscol = ((lane & 3) ^ ((lane >> 3) & 3)) * 8;
    const int sl8   = (((lane & 15) << 2) | ((lane >> 4) ^ ((lane >> 1) & 3))) * 8;

    f32x4 acc[4][2];
    const f32x4 zero4 = {0.f, 0.f, 0.f, 0.f};
#pragma unroll
    for (int i = 0; i < 4; ++i)
#pragma unroll
        for (int j = 0; j < 2; ++j) acc[i][j] = zero4;

    const unsigned short* AgL = A  + (size_t)(m0 + w * 32 + dsrow) * K + dscol;
    const unsigned short* BgL = Bt + (size_t)(n0 + w * 16 + dsrow) * K + dscol;

    const int NT = K >> 6;
    stage_g(AgL, BgL, K, 0, &As[0][0], &Bs[0][0], w);

    int cb = 0;
    for (int t = 0; t < NT; ++t) {
        if (t + 1 < NT) {
            stage_g(AgL, BgL, K, (t + 1) * 64, &As[cb ^ 1][0], &Bs[cb ^ 1][0], w);
            VMCNT(6);
        } else {
            VMCNT(0);
        }
        RBAR();

        bf16x8 af[4][2], bf[2][2];
#pragma unroll
        for (int kk = 0; kk < 2; ++kk) {
#pragma unroll
            for (int mt = 0; mt < 4; ++mt)
                af[mt][kk] = *(const bf16x8*)&As[cb][kk * 4096 + (wm * 4 + mt) * 512 + sl8];
#pragma unroll
            for (int nt = 0; nt < 2; ++nt)
                bf[nt][kk] = *(const bf16x8*)&Bs[cb][kk * 2048 + (wn * 2 + nt) * 512 + sl8];
        }
#pragma unroll
        for (int kk = 0; kk < 2; ++kk)
#pragma unroll
            for (int mt = 0; mt < 4; ++mt)
#pragma unroll
                for (int nt = 0; nt < 2; ++nt)
                    acc[mt][nt] = MFMA_BF16(af[mt][kk], bf[nt][kk], acc[mt][nt]);

        if (t + 1 < NT) RBAR();
        cb ^= 1;
    }

    if (MODE == 0) {
#pragma unroll
        for (int mt = 0; mt < 4; ++mt)
#pragma unroll
            for (int nt = 0; nt < 2; ++nt) {
                const int gn = n0 + wn * 32 + nt * 16 + l15;
#pragma unroll
                for (int r = 0; r < 4; ++r) {
                    const int gm = m0 + wm * 64 + mt * 16 + quad * 4 + r;
                    Cf[(size_t)gm * N + gn] = acc[mt][nt][r];
                }
            }
    } else {
        if (n0 < 1024) {            // Q: tanh * cexp -> qh[m][n], pitch 1024
#pragma unroll
            for (int mt = 0; mt < 4; ++mt)
#pragma unroll
                for (int nt = 0; nt < 2; ++nt) {
                    const int gn = n0 + wn * 32 + nt * 16 + l15;
#pragma unroll
                    for (int r = 0; r < 4; ++r) {
                        const int gm = m0 + wm * 64 + mt * 16 + quad * 4 + r;
                        qh[(size_t)gm * 1024 + gn] = f2b(tanhf(acc[mt][nt][r]) * 0.0225421100f);
                    }
                }
        } else if (n0 < 1280) {     // K: tanh -> kh[m][n-1024], pitch 256
#pragma unroll
            for (int mt = 0; mt < 4; ++mt)
#pragma unroll
                for (int nt = 0; nt < 2; ++nt) {
                    const int gn = n0 + wn * 32 + nt * 16 + l15 - 1024;
#pragma unroll
                    for (int r = 0; r < 4; ++r) {
                        const int gm = m0 + wm * 64 + mt * 16 + quad * 4 + r;
                        kh[(size_t)gm * 256 + gn] = f2b(tanhf(acc[mt][nt][r]));
                    }
                }
        } else {                    // V: sigmoid -> vtt[(b*4+g)*64+v][s]
#pragma unroll
            for (int mt = 0; mt < 4; ++mt)
#pragma unroll
                for (int nt = 0; nt < 2; ++nt) {
                    const int gn = n0 + wn * 32 + nt * 16 + l15 - 1280;
                    const int g = gn >> 6, vv = gn & 63;
                    const int s0 = m0 + wm * 64 + mt * 16 + quad * 4;
                    const int b = s0 >> 11, sl = s0 & 2047;
                    ushort4 pk;
                    unsigned short* pp = (unsigned short*)&pk;
#pragma unroll
                    for (int r = 0; r < 4; ++r) {
                        float sv = 1.0f / (1.0f + __expf(-acc[mt][nt][r]));
                        pp[r] = f2b(sv);
                    }
                    *(ushort4*)&vtt[((size_t)(b * 4 + g) * 64 + vv) * 2048 + sl] = pk;
                }
        }
    }
}

// ---------------------------------------------------------------------------
// MFMA flash attention — 32x32 MFMA restructure.
// Waves = quadrants (kq = w>>1, qq = w&1): wave computes S^T quadrant
// [kq*32.. , qq*32..] via 4x mfma_32x32x16 (K from LDS, Q in registers,
// cexp pre-folded into qh), then P stays IN REGISTERS: cvt_pk pairs +
// 4x v_permlane32_swap redistribute S^T (col=q=lane&31, 16 k's in regs;
// guide-verified C/D layout) into the PV A-operand layout (row=q=lane&31,
// k=(lane>>5)*8+j). PV: O[q][v] partial over the wave's k-range, 4x
// mfma_32x32x16 with V read from LDS. Per wave-tile LDS: 8 b128 reads
// (was 18 + 4 writes). End of q-tile: O partials cross-kq reduced through
// the (now free) Ks area; l via tiny Lred. Epilogue lane<->v: coalesced.
// LDS 33KB -> 4 blocks/CU; R6 grid/balance; two-sided staging swizzle;
// counted vmcnt; R6 mask bitmap.
// ---------------------------------------------------------------------------
__global__ __launch_bounds__(256, 4) void rosa_attn_mfma(
    const unsigned short* __restrict__ qh,
    const unsigned short* __restrict__ kh,
    const unsigned short* __restrict__ vtt,
    const int* __restrict__ amask,
    const float* __restrict__ emb0,
    const float* __restrict__ emb1,
    unsigned short* __restrict__ ob)
{
    __shared__ __align__(16) unsigned short Ks[2][4096];   // [buf][row(k)*64 + d]
    __shared__ __align__(16) unsigned short Vs[2][4096];   // [buf][row(v)*64 + k]
    __shared__ unsigned int Mflg[4];
    __shared__ float Lred[2][2][32];                       // [kq][qq][q_loc]

    const int a = blockIdx.x & 7, m = blockIdx.x >> 3;
    const int h = blockIdx.y, b = blockIdx.z, g = h >> 2;
    const int hb = h + 16 * b;
    const int sel = (m + (hb >> 3)) & 3;
    const int qt = (sel == 0) ? a : (sel == 1) ? 15 - a : (sel == 2) ? 16 + a : 31 - a;

    const int tid = threadIdx.x;
    const int w = tid >> 6, lane = tid & 63;
    const int kq = w >> 1, qq = w & 1;
    const int l31 = lane & 31, H = lane >> 5, x7 = lane & 7;

    // staging source (two-sided XOR swizzle; 8 rows per gload16, full rows
    // fetched with permuted 16B chunks -> line-coalesced)
    const int srow = lane >> 3;
    const int scol = ((lane & 7) ^ srow) * 8;
    const unsigned short* kst0 = kh + ((size_t)(b * 2048) + w * 16 + srow) * 256 + g * 64 + scol;
    const unsigned short* vst0 = vtt + ((size_t)(b * 4 + g) * 64 + w * 16 + srow) * 2048 + scol;
    const int* mbase = amask + b * 2048;

    // fragment read addresses (elem index into Ks/Vs[buf]); row&7 == lane&7
    int kadr[4];
#pragma unroll
    for (int mi = 0; mi < 4; ++mi)
        kadr[mi] = (kq * 32 + l31) * 64 + (((mi * 2 + H) ^ x7) * 8);
    int vadr[2][2];
#pragma unroll
    for (int vh = 0; vh < 2; ++vh)
#pragma unroll
        for (int kc = 0; kc < 2; ++kc)
            vadr[vh][kc] = (vh * 32 + l31) * 64 + (((kq * 4 + kc * 2 + H) ^ x7) * 8);

    // causal bitmask for the kq==qq diagonal quadrant: bit r iff k_loc(r)<=q_loc
    unsigned int cbits = 0;
#pragma unroll
    for (int r = 0; r < 16; ++r) {
        const int kl = (r & 3) + 8 * (r >> 2) + 4 * H;
        if (kl <= l31) cbits |= (1u << r);
    }

    const int q0 = qt * 64, nkt = qt + 1;

#define STAGE_TILE(k0s, buf)                                                   \
    {                                                                          \
        gload16(kst0 + (size_t)(k0s) * 256,        &Ks[buf][(w * 16) * 64]);   \
        gload16(kst0 + (size_t)(k0s) * 256 + 2048, &Ks[buf][(w * 16 + 8) * 64]);\
        gload16(vst0 + (k0s),                      &Vs[buf][(w * 16) * 64]);   \
        gload16(vst0 + (k0s) + 16384,              &Vs[buf][(w * 16 + 8) * 64]);\
    }

    const int4 mv0 = *(const int4*)(mbase + tid * 8);
    const int4 mv1 = *(const int4*)(mbase + tid * 8 + 4);

    STAGE_TILE(0, 0)

    // Q fragments (B operand: col=q=lane&31, k=d=(lane>>5)*8+j, 4 d-chunks)
    const unsigned short* qp = qh + ((size_t)(b * 2048 + q0 + qq * 32 + l31) * 16 + h) * 64 + H * 8;
    const bf16x8 qf0 = *(const bf16x8*)(qp);
    const bf16x8 qf1 = *(const bf16x8*)(qp + 16);
    const bf16x8 qf2 = *(const bf16x8*)(qp + 32);
    const bf16x8 qf3 = *(const bf16x8*)(qp + 48);

    // mask chunk-full bitmap (R6 scheme)
    const bool f8 = mv0.x && mv0.y && mv0.z && mv0.w && mv1.x && mv1.y && mv1.z && mv1.w;
    const unsigned long long bal = __ballot(f8);
    const bool bytefull = ((bal >> ((lane & 7) * 8)) & 0xFFull) == 0xFFull;
    const unsigned long long bal2 = __ballot(bytefull && (lane < 8));
    if (lane == 0) Mflg[w] = (unsigned int)(bal2 & 0xFFull);
    RBAR();
    const unsigned int mflags = Mflg[0] | (Mflg[1] << 8) | (Mflg[2] << 16) | (Mflg[3] << 24);

    const f32x16 z16 = {0.f,0.f,0.f,0.f, 0.f,0.f,0.f,0.f, 0.f,0.f,0.f,0.f, 0.f,0.f,0.f,0.f};
    f32x16 oacc0 = z16, oacc1 = z16;
    float psum = 0.0f;
    const bool skipdiag = (kq > qq);

    int cb = 0;
    for (int kt = 0; kt < nkt; ++kt) {
        if (kt + 1 < nkt) {
            STAGE_TILE((kt + 1) * 64, cb ^ 1)
            VMCNT(4);              // tile kt landed; tile kt+1 stays in flight
        } else {
            VMCNT(0);
        }
        RBAR();

        const bool diag = (kt == qt);
        if (!(diag && skipdiag)) {
            // ---- QK^T quadrant: sc[reg] = S^T[k_loc][q], col=q=lane&31
            const bf16x8 kf0 = *(const bf16x8*)&Ks[cb][kadr[0]];
            const bf16x8 kf1 = *(const bf16x8*)&Ks[cb][kadr[1]];
            const bf16x8 kf2 = *(const bf16x8*)&Ks[cb][kadr[2]];
            const bf16x8 kf3 = *(const bf16x8*)&Ks[cb][kadr[3]];
            __builtin_amdgcn_s_setprio(1);
            f32x16 sc = MFMA32(kf0, qf0, z16);
            sc = MFMA32(kf1, qf1, sc);
            sc = MFMA32(kf2, qf2, sc);
            sc = MFMA32(kf3, qf3, sc);
            __builtin_amdgcn_s_setprio(0);

            // ---- softmax numerators (cexp pre-folded into qh)
            float p[16];
#pragma unroll
            for (int r = 0; r < 16; ++r) p[r] = __builtin_exp2f(sc[r]);
            if (diag && kq == qq) {
#pragma unroll
                for (int r = 0; r < 16; ++r)
                    if (!((cbits >> r) & 1u)) p[r] = 0.0f;
            }
            if (!((mflags >> kt) & 1u)) {      // padded-mask slow path
#pragma unroll
                for (int r = 0; r < 16; ++r) {
                    const int kgl = kt * 64 + kq * 32 + (r & 3) + 8 * (r >> 2) + 4 * H;
                    if (mbase[kgl] == 0) p[r] = 0.0f;
                }
            }
            psum += (((p[0]+p[1])+(p[2]+p[3])) + ((p[4]+p[5])+(p[6]+p[7])))
                  + (((p[8]+p[9])+(p[10]+p[11])) + ((p[12]+p[13])+(p[14]+p[15])));

            // ---- P -> PV A-operand, entirely in registers
            unsigned int W0 = cvtpk(p[0],  p[1]),  W1 = cvtpk(p[2],  p[3]);
            unsigned int W2 = cvtpk(p[4],  p[5]),  W3 = cvtpk(p[6],  p[7]);
            unsigned int W4 = cvtpk(p[8],  p[9]),  W5 = cvtpk(p[10], p[11]);
            unsigned int W6 = cvtpk(p[12], p[13]), W7 = cvtpk(p[14], p[15]);
            PERMSWAP(W0, W2);  PERMSWAP(W1, W3);   // kc=0 frag words
            PERMSWAP(W4, W6);  PERMSWAP(W5, W7);   // kc=1 frag words
            u32x4 paw0; paw0[0] = W0; paw0[1] = W1; paw0[2] = W2; paw0[3] = W3;
            u32x4 paw1; paw1[0] = W4; paw1[1] = W5; paw1[2] = W6; paw1[3] = W7;
            const bf16x8 pa0 = __builtin_bit_cast(bf16x8, paw0);
            const bf16x8 pa1 = __builtin_bit_cast(bf16x8, paw1);

            // ---- PV: O[q][v] partial for this wave's k-range
            const bf16x8 vb00 = *(const bf16x8*)&Vs[cb][vadr[0][0]];
            const bf16x8 vb01 = *(const bf16x8*)&Vs[cb][vadr[0][1]];
            const bf16x8 vb10 = *(const bf16x8*)&Vs[cb][vadr[1][0]];
            const bf16x8 vb11 = *(const bf16x8*)&Vs[cb][vadr[1][1]];
            __builtin_amdgcn_s_setprio(1);
            oacc0 = MFMA32(pa0, vb00, oacc0);
            oacc0 = MFMA32(pa1, vb01, oacc0);
            oacc1 = MFMA32(pa0, vb10, oacc1);
            oacc1 = MFMA32(pa1, vb11, oacc1);
            __builtin_amdgcn_s_setprio(0);
        }

        if (kt + 1 < nkt) { RBAR(); cb ^= 1; }
    }

    // ---- l: combine lane halves (lanes l, l^32 hold same q, disjoint k)
    psum += __shfl_xor(psum, 32);

    RBAR();                         // all Ks/Vs reads done -> reuse Ks as Ored

    if (H == 0) Lred[kq][qq][l31] = psum;

    // O partial exchange: wave keeps vh=kq, ships vh=1-kq to slot (qq, 1-kq)
    float* Ored = (float*)&Ks[0][0];
    const int slw = qq * 2 + (1 - kq);
    if (kq == 0) {
#pragma unroll
        for (int c = 0; c < 4; ++c) {
            float4 t = {oacc1[c*4+0], oacc1[c*4+1], oacc1[c*4+2], oacc1[c*4+3]};
            *(float4*)&Ored[slw * 1024 + lane * 16 + ((c ^ (lane & 3)) * 4)] = t;
        }
    } else {
#pragma unroll
        for (int c = 0; c < 4; ++c) {
            float4 t = {oacc0[c*4+0], oacc0[c*4+1], oacc0[c*4+2], oacc0[c*4+3]};
            *(float4*)&Ored[slw * 1024 + lane * 16 + ((c ^ (lane & 3)) * 4)] = t;
        }
    }
    RBAR();

    const int slr = qq * 2 + kq;
    f32x16 osum = (kq == 0) ? oacc0 : oacc1;
#pragma unroll
    for (int c = 0; c < 4; ++c) {
        float4 t = *(const float4*)&Ored[slr * 1024 + lane * 16 + ((c ^ (lane & 3)) * 4)];
        osum[c*4+0] += t.x; osum[c*4+1] += t.y; osum[c*4+2] += t.z; osum[c*4+3] += t.w;
    }

    float rl[16];
#pragma unroll
    for (int r = 0; r < 16; ++r) {
        const int ql = (r & 3) + 8 * (r >> 2) + 4 * H;
        rl[r] = __builtin_amdgcn_rcpf(Lred[0][qq][ql] + Lred[1][qq][ql]);
    }

    // epilogue: lane holds v = kq*32 + l31 (fixed), q per reg -> coalesced
    const int vg = kq * 32 + l31;
    const float e0 = emb0[h * 64 + vg];
    const float ed = emb1[h * 64 + vg] - e0;
    unsigned short* obp = ob + ((size_t)(b * 2048 + q0 + qq * 32) * 16 + h) * 64 + vg;
#pragma unroll
    for (int r = 0; r < 16; ++r) {
        const int ql = (r & 3) + 8 * (r >> 2) + 4 * H;
        const float val = e0 + (osum[r] * rl[r]) * ed;
        obp[(size_t)ql * 1024] = f2b(val);
    }
#undef STAGE_TILE
}

// ---------------------------------------------------------------------------
extern "C" void kernel_launch(void* const* d_in, const int* in_sizes, int n_in,
                              void* d_out, int out_size, void* d_ws, size_t ws_size,
                              hipStream_t stream)
{
    const float* x    = (const float*)d_in[0];
    const int*   amask= (const int*)d_in[1];
    const float* Wq   = (const float*)d_in[2];
    const float* Wk   = (const float*)d_in[3];
    const float* Wv   = (const float*)d_in[4];
    const float* Wo   = (const float*)d_in[5];
    const float* emb0 = (const float*)d_in[6];
    const float* emb1 = (const float*)d_in[7];
    float* out = (float*)d_out;

    char* base = (char*)d_ws;
    unsigned short* xh    = (unsigned short*)(base);                      // 16 MB
    unsigned short* ob    = xh;                                           // aliases xh
    unsigned short* Wqkvt = (unsigned short*)(base + (16u << 20));        // 6 MB
    unsigned short* Wot   = (unsigned short*)(base + (22u << 20));        // 4 MB
    unsigned short* qh    = (unsigned short*)(base + (26u << 20));        // 8 MB
    unsigned short* kh    = (unsigned short*)(base + (34u << 20));        // 2 MB
    unsigned short* vtt   = (unsigned short*)(base + (36u << 20));        // 2 MB

    conv_bf16<<<2048, 256, 0, stream>>>(x, xh, 4096 * 2048);
    transp_conv_qkv<<<dim3(48, 64), dim3(32, 8), 0, stream>>>(Wq, Wk, Wv, Wqkvt);
    transp_conv<<<dim3(64, 32), dim3(32, 8), 0, stream>>>(Wo, 1024, 2048, Wot, 1024);

    gemm_bt_mfma<1><<<dim3(24, 32), 256, 0, stream>>>(xh, Wqkvt, 4096, 1536, 2048,
                                                      nullptr, qh, kh, vtt);
    rosa_attn_mfma<<<dim3(32, 16, 2), 256, 0, stream>>>(qh, kh, vtt, amask, emb0, emb1, ob);
    gemm_bt_mfma<0><<<dim3(32, 32), 256, 0, stream>>>(ob, Wot, 4096, 2048, 1024,
                                                      out, nullptr, nullptr, nullptr);
}

// Round 8
// 223.329 us; speedup vs baseline: 1.4441x; 1.0014x over previous
//
#include <hip/hip_runtime.h>
#include <math.h>

typedef short bf16x8 __attribute__((ext_vector_type(8)));
typedef float f32x4 __attribute__((ext_vector_type(4)));
typedef float f32x16 __attribute__((ext_vector_type(16)));
typedef unsigned int u32x2 __attribute__((ext_vector_type(2)));
typedef unsigned int u32x4 __attribute__((ext_vector_type(4)));

#define MFMA_BF16(A,B,C) __builtin_amdgcn_mfma_f32_16x16x32_bf16(A,B,C,0,0,0)
#define MFMA32(A,B,C)    __builtin_amdgcn_mfma_f32_32x32x16_bf16(A,B,C,0,0,0)

// counted vmcnt wait: loads newer than the N most recent stay in flight
#define VMCNT(N) asm volatile("s_waitcnt vmcnt(" #N ")" ::: "memory")
// raw barrier (no vmcnt drain!) with compiler memory fences on both sides
#define RBAR() do { asm volatile("" ::: "memory"); __builtin_amdgcn_s_barrier(); \
                    asm volatile("" ::: "memory"); } while (0)
// in-place half-swap: a = [a_lo | b_lo], b = [a_hi | b_hi]
#define PERMSWAP(a, b) asm volatile("v_permlane32_swap_b32 %0, %1" : "+v"(a), "+v"(b))

__device__ __forceinline__ unsigned short f2b(float x) {
    union { float f; unsigned int u; } v; v.f = x;
    unsigned int r = v.u + 0x7FFFu + ((v.u >> 16) & 1u);
    return (unsigned short)(r >> 16);
}

// packed f32x2 -> bf16x2 (RNE), single instruction
__device__ __forceinline__ unsigned int cvtpk(float lo, float hi) {
    unsigned int r;
    asm("v_cvt_pk_bf16_f32 %0, %1, %2" : "=v"(r) : "v"(lo), "v"(hi));
    return r;
}

// async global->LDS DMA, 16B per lane; LDS dest = wave-uniform base + lane*16
__device__ __forceinline__ void gload16(const unsigned short* g, unsigned short* l) {
    __builtin_amdgcn_global_load_lds(
        (const __attribute__((address_space(1))) unsigned int*)(g),
        (__attribute__((address_space(3))) unsigned int*)(l),
        16, 0, 0);
}

// ---------------------------------------------------------------------------
// fp32 -> bf16 convert (flat)
// ---------------------------------------------------------------------------
__global__ __launch_bounds__(256) void conv_bf16(const float* __restrict__ s,
                                                 unsigned short* __restrict__ d, int n)
{
    int i = blockIdx.x * blockDim.x + threadIdx.x;
    int stride = gridDim.x * blockDim.x;
    for (int idx = i * 4; idx < n; idx += stride * 4) {
        float4 v = *(const float4*)(s + idx);
        ushort4 o;
        o.x = f2b(v.x); o.y = f2b(v.y); o.z = f2b(v.z); o.w = f2b(v.w);
        *(ushort4*)(d + idx) = o;
    }
}

// ---------------------------------------------------------------------------
// Fused weight transpose+convert: Wq|Wk|Wv (fp32, [2048][C]) -> bf16 [C][2048]
// ---------------------------------------------------------------------------
__global__ __launch_bounds__(256) void transp_conv_qkv(const float* __restrict__ Wq,
                                                       const float* __restrict__ Wk,
                                                       const float* __restrict__ Wv,
                                                       unsigned short* __restrict__ dst)
{
    __shared__ float t[32][33];
    const int tx = threadIdx.x, ty = threadIdx.y;   // (32,8)
    int bx = blockIdx.x;
    const float* src; int C, cb, dco;
    if (bx < 32)      { src = Wq; C = 1024; cb = bx;      dco = 0; }
    else if (bx < 40) { src = Wk; C = 256;  cb = bx - 32; dco = 1024; }
    else              { src = Wv; C = 256;  cb = bx - 40; dco = 1280; }
    const int c = cb * 32 + tx;
    const int r0 = blockIdx.y * 32;
#pragma unroll
    for (int i = 0; i < 4; ++i)
        t[ty + i * 8][tx] = src[(size_t)(r0 + ty + i * 8) * C + c];
    __syncthreads();
    const int cc = cb * 32 + ty;
#pragma unroll
    for (int i = 0; i < 4; ++i)
        dst[(size_t)(dco + cc + i * 8) * 2048 + r0 + tx] = f2b(t[tx][ty + i * 8]);
}

__global__ __launch_bounds__(256) void transp_conv(const float* __restrict__ src, int R, int C,
                                                   unsigned short* __restrict__ dst, int pitch)
{
    __shared__ float t[32][33];
    const int tx = threadIdx.x, ty = threadIdx.y;
    const int c = blockIdx.x * 32 + tx;
    const int r0 = blockIdx.y * 32;
#pragma unroll
    for (int i = 0; i < 4; ++i)
        t[ty + i * 8][tx] = src[(size_t)(r0 + ty + i * 8) * C + c];
    __syncthreads();
    const int cc = blockIdx.x * 32 + ty;
#pragma unroll
    for (int i = 0; i < 4; ++i)
        dst[(size_t)(cc + i * 8) * pitch + r0 + tx] = f2b(t[tx][ty + i * 8]);
}

// ---------------------------------------------------------------------------
// bf16 MFMA GEMM, B^T input: C[M][N] = A[M][K] @ Bt[N][K]^T
// R8: 128x128 tile (was 128x64), BK=64; 4 waves at 2x2, each wave 64x64 out.
// Per wave K-step: 32 MFMA vs 16 LDS b128 reads + 8 staging DMAs (reads/MFMA
// 0.75 -> 0.5, B-panel reuse x2 — the m97-class config).  LDS 64KB double-
// buffered -> 2 blocks/CU.  Two-sided swizzle staging (R5-proven) on both
// A and B; counted vmcnt(8).
// ---------------------------------------------------------------------------
__device__ __forceinline__ void stage_g(const unsigned short* AgL, const unsigned short* BgL,
                                        int K, int k0s,
                                        unsigned short* Asb, unsigned short* Bsb, int w)
{
#pragma unroll
    for (int t = 0; t < 4; ++t) {
        const int sub = t >> 1, half = t & 1;
        gload16(AgL + (size_t)(half * 16) * K + k0s + sub * 32,
                Asb + sub * 4096 + (w * 2 + half) * 512);
        gload16(BgL + (size_t)(half * 16) * K + k0s + sub * 32,
                Bsb + sub * 4096 + (w * 2 + half) * 512);
    }
}

template <int MODE>
__global__ __launch_bounds__(256, 2) void gemm_bt_mfma(
    const unsigned short* __restrict__ A,
    const unsigned short* __restrict__ Bt,
    int M, int N, int K,
    float* __restrict__ Cf,
    unsigned short* __restrict__ qh,
    unsigned short* __restrict__ kh,
    unsigned short* __restrict__ vtt)
{
    __shared__ __align__(16) unsigned short As[2][8192];   // [buf][kk*4096 + grp*512 + slot*8]
    __shared__ __align__(16) unsigned short Bs[2][8192];

    const int tid = threadIdx.x;
    const int w = tid >> 6, lane = tid & 63, l15 = lane & 15, quad = lane >> 4;
    const int wm = w & 1, wn = w >> 1;
    const int m0 = blockIdx.y * 128, n0 = blockIdx.x * 128;

    // two-sided swizzle lane constants (R5-proven)
    const int dsrow = lane >> 2;                              // DMA source row in 16-row block
    const int dscol = ((lane & 3) ^ ((lane >> 3) & 3)) * 8;   // DMA source col-group (elems)
    const int sl8   = (((lane & 15) << 2) | ((lane >> 4) ^ ((lane >> 1) & 3))) * 8; // read slot

    f32x4 acc[4][4];
    const f32x4 zero4 = {0.f, 0.f, 0.f, 0.f};
#pragma unroll
    for (int i = 0; i < 4; ++i)
#pragma unroll
        for (int j = 0; j < 4; ++j) acc[i][j] = zero4;

    const unsigned short* AgL = A  + (size_t)(m0 + w * 32 + dsrow) * K + dscol;
    const unsigned short* BgL = Bt + (size_t)(n0 + w * 32 + dsrow) * K + dscol;

    const int NT = K >> 6;
    stage_g(AgL, BgL, K, 0, &As[0][0], &Bs[0][0], w);   // prologue: tile 0, no drain

    int cb = 0;
    for (int t = 0; t < NT; ++t) {
        if (t + 1 < NT) {
            stage_g(AgL, BgL, K, (t + 1) * 64, &As[cb ^ 1][0], &Bs[cb ^ 1][0], w);
            VMCNT(8);              // wait tile t (oldest 8); tile t+1 stays in flight
        } else {
            VMCNT(0);
        }
        RBAR();                    // everyone's tile-t DMA landed

#pragma unroll
        for (int kk = 0; kk < 2; ++kk) {
            bf16x8 af[4], bf[4];
#pragma unroll
            for (int mt = 0; mt < 4; ++mt)
                af[mt] = *(const bf16x8*)&As[cb][kk * 4096 + (wm * 4 + mt) * 512 + sl8];
#pragma unroll
            for (int nt = 0; nt < 4; ++nt)
                bf[nt] = *(const bf16x8*)&Bs[cb][kk * 4096 + (wn * 4 + nt) * 512 + sl8];
#pragma unroll
            for (int mt = 0; mt < 4; ++mt)
#pragma unroll
                for (int nt = 0; nt < 4; ++nt)
                    acc[mt][nt] = MFMA_BF16(af[mt], bf[nt], acc[mt][nt]);
        }

        if (t + 1 < NT) RBAR();    // readers done before next iter overwrites cb
        cb ^= 1;
    }

    if (MODE == 0) {
#pragma unroll
        for (int mt = 0; mt < 4; ++mt)
#pragma unroll
            for (int nt = 0; nt < 4; ++nt) {
                const int gn = n0 + wn * 64 + nt * 16 + l15;
#pragma unroll
                for (int r = 0; r < 4; ++r) {
                    const int gm = m0 + wm * 64 + mt * 16 + quad * 4 + r;
                    Cf[(size_t)gm * N + gn] = acc[mt][nt][r];
                }
            }
    } else {
        if (n0 < 1024) {            // Q: tanh * cexp -> qh[m][n], pitch 1024
#pragma unroll
            for (int mt = 0; mt < 4; ++mt)
#pragma unroll
                for (int nt = 0; nt < 4; ++nt) {
                    const int gn = n0 + wn * 64 + nt * 16 + l15;
#pragma unroll
                    for (int r = 0; r < 4; ++r) {
                        const int gm = m0 + wm * 64 + mt * 16 + quad * 4 + r;
                        qh[(size_t)gm * 1024 + gn] = f2b(tanhf(acc[mt][nt][r]) * 0.0225421100f);
                    }
                }
        } else if (n0 < 1280) {     // K: tanh -> kh[m][n-1024], pitch 256
#pragma unroll
            for (int mt = 0; mt < 4; ++mt)
#pragma unroll
                for (int nt = 0; nt < 4; ++nt) {
                    const int gn = n0 + wn * 64 + nt * 16 + l15 - 1024;
#pragma unroll
                    for (int r = 0; r < 4; ++r) {
                        const int gm = m0 + wm * 64 + mt * 16 + quad * 4 + r;
                        kh[(size_t)gm * 256 + gn] = f2b(tanhf(acc[mt][nt][r]));
                    }
                }
        } else {                    // V: sigmoid -> vtt[(b*4+g)*64+v][s]
#pragma unroll
            for (int mt = 0; mt < 4; ++mt)
#pragma unroll
                for (int nt = 0; nt < 4; ++nt) {
                    const int gn = n0 + wn * 64 + nt * 16 + l15 - 1280;
                    const int g = gn >> 6, vv = gn & 63;
                    const int s0 = m0 + wm * 64 + mt * 16 + quad * 4;
                    const int b = s0 >> 11, sl = s0 & 2047;
                    ushort4 pk;
                    unsigned short* pp = (unsigned short*)&pk;
#pragma unroll
                    for (int r = 0; r < 4; ++r) {
                        float sv = 1.0f / (1.0f + __expf(-acc[mt][nt][r]));
                        pp[r] = f2b(sv);
                    }
                    *(ushort4*)&vtt[((size_t)(b * 4 + g) * 64 + vv) * 2048 + sl] = pk;
                }
        }
    }
}

// ---------------------------------------------------------------------------
// MFMA flash attention — 32x32 MFMA structure (R7-proven).  Only change this
// round: Ored exchange index gains "^ ((lane>>2)&3)" (storage permutation
// only) to break the 4-way bank alias on the f32x4 O-reduction.
// ---------------------------------------------------------------------------
__global__ __launch_bounds__(256, 4) void rosa_attn_mfma(
    const unsigned short* __restrict__ qh,
    const unsigned short* __restrict__ kh,
    const unsigned short* __restrict__ vtt,
    const int* __restrict__ amask,
    const float* __restrict__ emb0,
    const float* __restrict__ emb1,
    unsigned short* __restrict__ ob)
{
    __shared__ __align__(16) unsigned short Ks[2][4096];   // [buf][row(k)*64 + d]
    __shared__ __align__(16) unsigned short Vs[2][4096];   // [buf][row(v)*64 + k]
    __shared__ unsigned int Mflg[4];
    __shared__ float Lred[2][2][32];                       // [kq][qq][q_loc]

    const int a = blockIdx.x & 7, m = blockIdx.x >> 3;
    const int h = blockIdx.y, b = blockIdx.z, g = h >> 2;
    const int hb = h + 16 * b;
    const int sel = (m + (hb >> 3)) & 3;
    const int qt = (sel == 0) ? a : (sel == 1) ? 15 - a : (sel == 2) ? 16 + a : 31 - a;

    const int tid = threadIdx.x;
    const int w = tid >> 6, lane = tid & 63;
    const int kq = w >> 1, qq = w & 1;
    const int l31 = lane & 31, H = lane >> 5, x7 = lane & 7;

    // staging source (two-sided XOR swizzle)
    const int srow = lane >> 3;
    const int scol = ((lane & 7) ^ srow) * 8;
    const unsigned short* kst0 = kh + ((size_t)(b * 2048) + w * 16 + srow) * 256 + g * 64 + scol;
    const unsigned short* vst0 = vtt + ((size_t)(b * 4 + g) * 64 + w * 16 + srow) * 2048 + scol;
    const int* mbase = amask + b * 2048;

    // fragment read addresses (elem index into Ks/Vs[buf]); row&7 == lane&7
    int kadr[4];
#pragma unroll
    for (int mi = 0; mi < 4; ++mi)
        kadr[mi] = (kq * 32 + l31) * 64 + (((mi * 2 + H) ^ x7) * 8);
    int vadr[2][2];
#pragma unroll
    for (int vh = 0; vh < 2; ++vh)
#pragma unroll
        for (int kc = 0; kc < 2; ++kc)
            vadr[vh][kc] = (vh * 32 + l31) * 64 + (((kq * 4 + kc * 2 + H) ^ x7) * 8);

    // causal bitmask for the kq==qq diagonal quadrant: bit r iff k_loc(r)<=q_loc
    unsigned int cbits = 0;
#pragma unroll
    for (int r = 0; r < 16; ++r) {
        const int kl = (r & 3) + 8 * (r >> 2) + 4 * H;
        if (kl <= l31) cbits |= (1u << r);
    }

    const int q0 = qt * 64, nkt = qt + 1;

#define STAGE_TILE(k0s, buf)                                                   \
    {                                                                          \
        gload16(kst0 + (size_t)(k0s) * 256,        &Ks[buf][(w * 16) * 64]);   \
        gload16(kst0 + (size_t)(k0s) * 256 + 2048, &Ks[buf][(w * 16 + 8) * 64]);\
        gload16(vst0 + (k0s),                      &Vs[buf][(w * 16) * 64]);   \
        gload16(vst0 + (k0s) + 16384,              &Vs[buf][(w * 16 + 8) * 64]);\
    }

    const int4 mv0 = *(const int4*)(mbase + tid * 8);
    const int4 mv1 = *(const int4*)(mbase + tid * 8 + 4);

    STAGE_TILE(0, 0)

    // Q fragments (B operand: col=q=lane&31, k=d=(lane>>5)*8+j, 4 d-chunks)
    const unsigned short* qp = qh + ((size_t)(b * 2048 + q0 + qq * 32 + l31) * 16 + h) * 64 + H * 8;
    const bf16x8 qf0 = *(const bf16x8*)(qp);
    const bf16x8 qf1 = *(const bf16x8*)(qp + 16);
    const bf16x8 qf2 = *(const bf16x8*)(qp + 32);
    const bf16x8 qf3 = *(const bf16x8*)(qp + 48);

    // mask chunk-full bitmap (R6 scheme)
    const bool f8 = mv0.x && mv0.y && mv0.z && mv0.w && mv1.x && mv1.y && mv1.z && mv1.w;
    const unsigned long long bal = __ballot(f8);
    const bool bytefull = ((bal >> ((lane & 7) * 8)) & 0xFFull) == 0xFFull;
    const unsigned long long bal2 = __ballot(bytefull && (lane < 8));
    if (lane == 0) Mflg[w] = (unsigned int)(bal2 & 0xFFull);
    RBAR();
    const unsigned int mflags = Mflg[0] | (Mflg[1] << 8) | (Mflg[2] << 16) | (Mflg[3] << 24);

    const f32x16 z16 = {0.f,0.f,0.f,0.f, 0.f,0.f,0.f,0.f, 0.f,0.f,0.f,0.f, 0.f,0.f,0.f,0.f};
    f32x16 oacc0 = z16, oacc1 = z16;
    float psum = 0.0f;
    const bool skipdiag = (kq > qq);

    int cb = 0;
    for (int kt = 0; kt < nkt; ++kt) {
        if (kt + 1 < nkt) {
            STAGE_TILE((kt + 1) * 64, cb ^ 1)
            VMCNT(4);              // tile kt landed; tile kt+1 stays in flight
        } else {
            VMCNT(0);
        }
        RBAR();

        const bool diag = (kt == qt);
        if (!(diag && skipdiag)) {
            // ---- QK^T quadrant: sc[reg] = S^T[k_loc][q], col=q=lane&31
            const bf16x8 kf0 = *(const bf16x8*)&Ks[cb][kadr[0]];
            const bf16x8 kf1 = *(const bf16x8*)&Ks[cb][kadr[1]];
            const bf16x8 kf2 = *(const bf16x8*)&Ks[cb][kadr[2]];
            const bf16x8 kf3 = *(const bf16x8*)&Ks[cb][kadr[3]];
            __builtin_amdgcn_s_setprio(1);
            f32x16 sc = MFMA32(kf0, qf0, z16);
            sc = MFMA32(kf1, qf1, sc);
            sc = MFMA32(kf2, qf2, sc);
            sc = MFMA32(kf3, qf3, sc);
            __builtin_amdgcn_s_setprio(0);

            // ---- softmax numerators (cexp pre-folded into qh)
            float p[16];
#pragma unroll
            for (int r = 0; r < 16; ++r) p[r] = __builtin_exp2f(sc[r]);
            if (diag && kq == qq) {
#pragma unroll
                for (int r = 0; r < 16; ++r)
                    if (!((cbits >> r) & 1u)) p[r] = 0.0f;
            }
            if (!((mflags >> kt) & 1u)) {      // padded-mask slow path
#pragma unroll
                for (int r = 0; r < 16; ++r) {
                    const int kgl = kt * 64 + kq * 32 + (r & 3) + 8 * (r >> 2) + 4 * H;
                    if (mbase[kgl] == 0) p[r] = 0.0f;
                }
            }
            psum += (((p[0]+p[1])+(p[2]+p[3])) + ((p[4]+p[5])+(p[6]+p[7])))
                  + (((p[8]+p[9])+(p[10]+p[11])) + ((p[12]+p[13])+(p[14]+p[15])));

            // ---- P -> PV A-operand, entirely in registers
            unsigned int W0 = cvtpk(p[0],  p[1]),  W1 = cvtpk(p[2],  p[3]);
            unsigned int W2 = cvtpk(p[4],  p[5]),  W3 = cvtpk(p[6],  p[7]);
            unsigned int W4 = cvtpk(p[8],  p[9]),  W5 = cvtpk(p[10], p[11]);
            unsigned int W6 = cvtpk(p[12], p[13]), W7 = cvtpk(p[14], p[15]);
            PERMSWAP(W0, W2);  PERMSWAP(W1, W3);   // kc=0 frag words
            PERMSWAP(W4, W6);  PERMSWAP(W5, W7);   // kc=1 frag words
            u32x4 paw0; paw0[0] = W0; paw0[1] = W1; paw0[2] = W2; paw0[3] = W3;
            u32x4 paw1; paw1[0] = W4; paw1[1] = W5; paw1[2] = W6; paw1[3] = W7;
            const bf16x8 pa0 = __builtin_bit_cast(bf16x8, paw0);
            const bf16x8 pa1 = __builtin_bit_cast(bf16x8, paw1);

            // ---- PV: O[q][v] partial for this wave's k-range
            const bf16x8 vb00 = *(const bf16x8*)&Vs[cb][vadr[0][0]];
            const bf16x8 vb01 = *(const bf16x8*)&Vs[cb][vadr[0][1]];
            const bf16x8 vb10 = *(const bf16x8*)&Vs[cb][vadr[1][0]];
            const bf16x8 vb11 = *(const bf16x8*)&Vs[cb][vadr[1][1]];
            __builtin_amdgcn_s_setprio(1);
            oacc0 = MFMA32(pa0, vb00, oacc0);
            oacc0 = MFMA32(pa1, vb01, oacc0);
            oacc1 = MFMA32(pa0, vb10, oacc1);
            oacc1 = MFMA32(pa1, vb11, oacc1);
            __builtin_amdgcn_s_setprio(0);
        }

        if (kt + 1 < nkt) { RBAR(); cb ^= 1; }
    }

    // ---- l: combine lane halves (lanes l, l^32 hold same q, disjoint k)
    psum += __shfl_xor(psum, 32);

    RBAR();                         // all Ks/Vs reads done -> reuse Ks as Ored

    if (H == 0) Lred[kq][qq][l31] = psum;

    // O partial exchange: wave keeps vh=kq, ships vh=1-kq to slot (qq, 1-kq)
    float* Ored = (float*)&Ks[0][0];
    const int slw = qq * 2 + (1 - kq);
    const int cx = (lane & 3) ^ ((lane >> 2) & 3);   // bank-spread XOR (2-way max)
    if (kq == 0) {
#pragma unroll
        for (int c = 0; c < 4; ++c) {
            float4 t = {oacc1[c*4+0], oacc1[c*4+1], oacc1[c*4+2], oacc1[c*4+3]};
            *(float4*)&Ored[slw * 1024 + lane * 16 + ((c ^ cx) * 4)] = t;
        }
    } else {
#pragma unroll
        for (int c = 0; c < 4; ++c) {
            float4 t = {oacc0[c*4+0], oacc0[c*4+1], oacc0[c*4+2], oacc0[c*4+3]};
            *(float4*)&Ored[slw * 1024 + lane * 16 + ((c ^ cx) * 4)] = t;
        }
    }
    RBAR();

    const int slr = qq * 2 + kq;
    f32x16 osum = (kq == 0) ? oacc0 : oacc1;
#pragma unroll
    for (int c = 0; c < 4; ++c) {
        float4 t = *(const float4*)&Ored[slr * 1024 + lane * 16 + ((c ^ cx) * 4)];
        osum[c*4+0] += t.x; osum[c*4+1] += t.y; osum[c*4+2] += t.z; osum[c*4+3] += t.w;
    }

    float rl[16];
#pragma unroll
    for (int r = 0; r < 16; ++r) {
        const int ql = (r & 3) + 8 * (r >> 2) + 4 * H;
        rl[r] = __builtin_amdgcn_rcpf(Lred[0][qq][ql] + Lred[1][qq][ql]);
    }

    // epilogue: lane holds v = kq*32 + l31 (fixed), q per reg -> coalesced
    const int vg = kq * 32 + l31;
    const float e0 = emb0[h * 64 + vg];
    const float ed = emb1[h * 64 + vg] - e0;
    unsigned short* obp = ob + ((size_t)(b * 2048 + q0 + qq * 32) * 16 + h) * 64 + vg;
#pragma unroll
    for (int r = 0; r < 16; ++r) {
        const int ql = (r & 3) + 8 * (r >> 2) + 4 * H;
        const float val = e0 + (osum[r] * rl[r]) * ed;
        obp[(size_t)ql * 1024] = f2b(val);
    }
#undef STAGE_TILE
}

// ---------------------------------------------------------------------------
extern "C" void kernel_launch(void* const* d_in, const int* in_sizes, int n_in,
                              void* d_out, int out_size, void* d_ws, size_t ws_size,
                              hipStream_t stream)
{
    const float* x    = (const float*)d_in[0];
    const int*   amask= (const int*)d_in[1];
    const float* Wq   = (const float*)d_in[2];
    const float* Wk   = (const float*)d_in[3];
    const float* Wv   = (const float*)d_in[4];
    const float* Wo   = (const float*)d_in[5];
    const float* emb0 = (const float*)d_in[6];
    const float* emb1 = (const float*)d_in[7];
    float* out = (float*)d_out;

    char* base = (char*)d_ws;
    unsigned short* xh    = (unsigned short*)(base);                      // 16 MB
    unsigned short* ob    = xh;                                           // aliases xh
    unsigned short* Wqkvt = (unsigned short*)(base + (16u << 20));        // 6 MB
    unsigned short* Wot   = (unsigned short*)(base + (22u << 20));        // 4 MB
    unsigned short* qh    = (unsigned short*)(base + (26u << 20));        // 8 MB
    unsigned short* kh    = (unsigned short*)(base + (34u << 20));        // 2 MB
    unsigned short* vtt   = (unsigned short*)(base + (36u << 20));        // 2 MB

    conv_bf16<<<2048, 256, 0, stream>>>(x, xh, 4096 * 2048);
    transp_conv_qkv<<<dim3(48, 64), dim3(32, 8), 0, stream>>>(Wq, Wk, Wv, Wqkvt);
    transp_conv<<<dim3(64, 32), dim3(32, 8), 0, stream>>>(Wo, 1024, 2048, Wot, 1024);

    gemm_bt_mfma<1><<<dim3(12, 32), 256, 0, stream>>>(xh, Wqkvt, 4096, 1536, 2048,
                                                      nullptr, qh, kh, vtt);
    rosa_attn_mfma<<<dim3(32, 16, 2), 256, 0, stream>>>(qh, kh, vtt, amask, emb0, emb1, ob);
    gemm_bt_mfma<0><<<dim3(16, 32), 256, 0, stream>>>(ob, Wot, 4096, 2048, 1024,
                                                      out, nullptr, nullptr, nullptr);
}

// Round 9
// 213.931 us; speedup vs baseline: 1.5075x; 1.0439x over previous
//
#include <hip/hip_runtime.h>
#include <math.h>

typedef short bf16x8 __attribute__((ext_vector_type(8)));
typedef float f32x4 __attribute__((ext_vector_type(4)));
typedef float f32x16 __attribute__((ext_vector_type(16)));
typedef unsigned int u32x2 __attribute__((ext_vector_type(2)));
typedef unsigned int u32x4 __attribute__((ext_vector_type(4)));

#define MFMA_BF16(A,B,C) __builtin_amdgcn_mfma_f32_16x16x32_bf16(A,B,C,0,0,0)
#define MFMA32(A,B,C)    __builtin_amdgcn_mfma_f32_32x32x16_bf16(A,B,C,0,0,0)

// counted vmcnt wait: loads newer than the N most recent stay in flight
#define VMCNT(N) asm volatile("s_waitcnt vmcnt(" #N ")" ::: "memory")
// raw barrier (no vmcnt drain!) with compiler memory fences on both sides
#define RBAR() do { asm volatile("" ::: "memory"); __builtin_amdgcn_s_barrier(); \
                    asm volatile("" ::: "memory"); } while (0)
// in-place half-swap: a = [a_lo | b_lo], b = [a_hi | b_hi]
#define PERMSWAP(a, b) asm volatile("v_permlane32_swap_b32 %0, %1" : "+v"(a), "+v"(b))

__device__ __forceinline__ unsigned short f2b(float x) {
    union { float f; unsigned int u; } v; v.f = x;
    unsigned int r = v.u + 0x7FFFu + ((v.u >> 16) & 1u);
    return (unsigned short)(r >> 16);
}

// packed f32x2 -> bf16x2 (RNE), single instruction
__device__ __forceinline__ unsigned int cvtpk(float lo, float hi) {
    unsigned int r;
    asm("v_cvt_pk_bf16_f32 %0, %1, %2" : "=v"(r) : "v"(lo), "v"(hi));
    return r;
}

// async global->LDS DMA, 16B per lane; LDS dest = wave-uniform base + lane*16
__device__ __forceinline__ void gload16(const unsigned short* g, unsigned short* l) {
    __builtin_amdgcn_global_load_lds(
        (const __attribute__((address_space(1))) unsigned int*)(g),
        (__attribute__((address_space(3))) unsigned int*)(l),
        16, 0, 0);
}

// ---------------------------------------------------------------------------
// Fused preprocessing: one dispatch replaces conv_bf16 + transp_conv_qkv +
// transp_conv (removes 2 launch gaps).  Block-range dispatch; bodies verbatim.
//   bid [0,2048):       x fp32 -> bf16 flat
//   bid [2048,5120):    Wq|Wk|Wv transpose+convert -> Wqkvt
//   bid [5120,7168):    Wo transpose+convert -> Wot
// ---------------------------------------------------------------------------
__global__ __launch_bounds__(256) void prep(
    const float* __restrict__ x, unsigned short* __restrict__ xh,
    const float* __restrict__ Wq, const float* __restrict__ Wk,
    const float* __restrict__ Wv, unsigned short* __restrict__ Wqkvt,
    const float* __restrict__ Wo, unsigned short* __restrict__ Wot)
{
    __shared__ float t[32][33];
    const int bid = blockIdx.x, tid = threadIdx.x;

    if (bid < 2048) {                       // ---- conv_bf16(x -> xh), n = 8.39M
        const int n = 4096 * 2048;
        int i = bid * 256 + tid;
        int stride = 2048 * 256;
        for (int idx = i * 4; idx < n; idx += stride * 4) {
            float4 v = *(const float4*)(x + idx);
            ushort4 o;
            o.x = f2b(v.x); o.y = f2b(v.y); o.z = f2b(v.z); o.w = f2b(v.w);
            *(ushort4*)(xh + idx) = o;
        }
        return;
    }

    const int tx = tid & 31, ty = tid >> 5;         // (32,8) remap

    if (bid < 5120) {                       // ---- transp_conv_qkv
        const int idx = bid - 2048;                 // [0, 3072) = 48 x 64
        const int bx = idx % 48, by = idx / 48;
        const float* src; int C, cb, dco;
        if (bx < 32)      { src = Wq; C = 1024; cb = bx;      dco = 0; }
        else if (bx < 40) { src = Wk; C = 256;  cb = bx - 32; dco = 1024; }
        else              { src = Wv; C = 256;  cb = bx - 40; dco = 1280; }
        const int c = cb * 32 + tx;
        const int r0 = by * 32;
#pragma unroll
        for (int i = 0; i < 4; ++i)
            t[ty + i * 8][tx] = src[(size_t)(r0 + ty + i * 8) * C + c];
        __syncthreads();
        const int cc = cb * 32 + ty;
#pragma unroll
        for (int i = 0; i < 4; ++i)
            Wqkvt[(size_t)(dco + cc + i * 8) * 2048 + r0 + tx] = f2b(t[tx][ty + i * 8]);
        return;
    }

    {                                       // ---- transp_conv(Wo -> Wot)
        const int idx = bid - 5120;                 // [0, 2048) = 64 x 32
        const int bx = idx % 64, by = idx / 64;
        const int c = bx * 32 + tx;                 // C = 2048
        const int r0 = by * 32;                     // R = 1024
#pragma unroll
        for (int i = 0; i < 4; ++i)
            t[ty + i * 8][tx] = Wo[(size_t)(r0 + ty + i * 8) * 2048 + c];
        __syncthreads();
        const int cc = bx * 32 + ty;
#pragma unroll
        for (int i = 0; i < 4; ++i)
            Wot[(size_t)(cc + i * 8) * 1024 + r0 + tx] = f2b(t[tx][ty + i * 8]);
    }
}

// ---------------------------------------------------------------------------
// GEMM 1 (QKV projections): R5-proven config restored — 128x64 tile, BK=64,
// 48KB double-buffered LDS -> 3 blocks/CU, grid 768 = 3/CU balanced;
// two-sided swizzle staging (0 conflicts, coalesced source); counted vmcnt(6).
// R9 adds: XCD-chunked block swizzle (768%8==0, bijective) so blocks sharing
// an A-panel land on the same XCD L2.
// ---------------------------------------------------------------------------
__device__ __forceinline__ void stage_qkv(const unsigned short* AgL, const unsigned short* BgL,
                                          int K, int k0s,
                                          unsigned short* Asb, unsigned short* Bsb, int w)
{
#pragma unroll
    for (int t = 0; t < 4; ++t) {
        const int sub = t >> 1, half = t & 1;
        gload16(AgL + (size_t)(half * 16) * K + k0s + sub * 32,
                Asb + sub * 4096 + (w * 2 + half) * 512);
    }
#pragma unroll
    for (int kk = 0; kk < 2; ++kk)
        gload16(BgL + k0s + kk * 32, Bsb + kk * 2048 + w * 512);
}

__global__ __launch_bounds__(256, 3) void gemm_qkv(
    const unsigned short* __restrict__ A,
    const unsigned short* __restrict__ Bt,
    unsigned short* __restrict__ qh,
    unsigned short* __restrict__ kh,
    unsigned short* __restrict__ vtt)
{
    __shared__ __align__(16) unsigned short As[2][2 * 128 * 32];
    __shared__ __align__(16) unsigned short Bs[2][2 * 64 * 32];

    const int K = 2048;
    const int tid = threadIdx.x;
    const int w = tid >> 6, lane = tid & 63, l15 = lane & 15, quad = lane >> 4;
    const int wm = w & 1, wn = w >> 1;

    // XCD-chunked swizzle: 96 consecutive logical tiles (4 A-panel rows) / XCD
    const int orig = blockIdx.x + 24 * blockIdx.y;       // [0, 768)
    const int lb = (orig & 7) * 96 + (orig >> 3);
    const int m0 = (lb / 24) * 128, n0 = (lb % 24) * 64;

    // two-sided swizzle lane constants (R5-proven)
    const int dsrow = lane >> 2;
    const int dscol = ((lane & 3) ^ ((lane >> 3) & 3)) * 8;
    const int sl8   = (((lane & 15) << 2) | ((lane >> 4) ^ ((lane >> 1) & 3))) * 8;

    f32x4 acc[4][2];
    const f32x4 zero4 = {0.f, 0.f, 0.f, 0.f};
#pragma unroll
    for (int i = 0; i < 4; ++i)
#pragma unroll
        for (int j = 0; j < 2; ++j) acc[i][j] = zero4;

    const unsigned short* AgL = A  + (size_t)(m0 + w * 32 + dsrow) * K + dscol;
    const unsigned short* BgL = Bt + (size_t)(n0 + w * 16 + dsrow) * K + dscol;

    const int NT = K >> 6;
    stage_qkv(AgL, BgL, K, 0, &As[0][0], &Bs[0][0], w);

    int cb = 0;
    for (int t = 0; t < NT; ++t) {
        if (t + 1 < NT) {
            stage_qkv(AgL, BgL, K, (t + 1) * 64, &As[cb ^ 1][0], &Bs[cb ^ 1][0], w);
            VMCNT(6);              // wait tile t (oldest 6); tile t+1 stays in flight
        } else {
            VMCNT(0);
        }
        RBAR();

        bf16x8 af[4][2], bf[2][2];
#pragma unroll
        for (int kk = 0; kk < 2; ++kk) {
#pragma unroll
            for (int mt = 0; mt < 4; ++mt)
                af[mt][kk] = *(const bf16x8*)&As[cb][kk * 4096 + (wm * 4 + mt) * 512 + sl8];
#pragma unroll
            for (int nt = 0; nt < 2; ++nt)
                bf[nt][kk] = *(const bf16x8*)&Bs[cb][kk * 2048 + (wn * 2 + nt) * 512 + sl8];
        }
#pragma unroll
        for (int kk = 0; kk < 2; ++kk)
#pragma unroll
            for (int mt = 0; mt < 4; ++mt)
#pragma unroll
                for (int nt = 0; nt < 2; ++nt)
                    acc[mt][nt] = MFMA_BF16(af[mt][kk], bf[nt][kk], acc[mt][nt]);

        if (t + 1 < NT) RBAR();
        cb ^= 1;
    }

    if (n0 < 1024) {            // Q: tanh * cexp -> qh[m][n], pitch 1024
#pragma unroll
        for (int mt = 0; mt < 4; ++mt)
#pragma unroll
            for (int nt = 0; nt < 2; ++nt) {
                const int gn = n0 + wn * 32 + nt * 16 + l15;
#pragma unroll
                for (int r = 0; r < 4; ++r) {
                    const int gm = m0 + wm * 64 + mt * 16 + quad * 4 + r;
                    qh[(size_t)gm * 1024 + gn] = f2b(tanhf(acc[mt][nt][r]) * 0.0225421100f);
                }
            }
    } else if (n0 < 1280) {     // K: tanh -> kh[m][n-1024], pitch 256
#pragma unroll
        for (int mt = 0; mt < 4; ++mt)
#pragma unroll
            for (int nt = 0; nt < 2; ++nt) {
                const int gn = n0 + wn * 32 + nt * 16 + l15 - 1024;
#pragma unroll
                for (int r = 0; r < 4; ++r) {
                    const int gm = m0 + wm * 64 + mt * 16 + quad * 4 + r;
                    kh[(size_t)gm * 256 + gn] = f2b(tanhf(acc[mt][nt][r]));
                }
            }
    } else {                    // V: sigmoid -> vtt[(b*4+g)*64+v][s]
#pragma unroll
        for (int mt = 0; mt < 4; ++mt)
#pragma unroll
            for (int nt = 0; nt < 2; ++nt) {
                const int gn = n0 + wn * 32 + nt * 16 + l15 - 1280;
                const int g = gn >> 6, vv = gn & 63;
                const int s0 = m0 + wm * 64 + mt * 16 + quad * 4;
                const int b = s0 >> 11, sl = s0 & 2047;
                ushort4 pk;
                unsigned short* pp = (unsigned short*)&pk;
#pragma unroll
                for (int r = 0; r < 4; ++r) {
                    float sv = 1.0f / (1.0f + __expf(-acc[mt][nt][r]));
                    pp[r] = f2b(sv);
                }
                *(ushort4*)&vtt[((size_t)(b * 4 + g) * 64 + vv) * 2048 + sl] = pk;
            }
    }
}

// ---------------------------------------------------------------------------
// GEMM 2 (output projection): R8 128x128 tile (grid 512 = 2/CU balanced),
// BK=64, 64KB dbuf, counted vmcnt(8).  R9 adds XCD-chunked swizzle.
// ---------------------------------------------------------------------------
__device__ __forceinline__ void stage_out(const unsigned short* AgL, const unsigned short* BgL,
                                          int K, int k0s,
                                          unsigned short* Asb, unsigned short* Bsb, int w)
{
#pragma unroll
    for (int t = 0; t < 4; ++t) {
        const int sub = t >> 1, half = t & 1;
        gload16(AgL + (size_t)(half * 16) * K + k0s + sub * 32,
                Asb + sub * 4096 + (w * 2 + half) * 512);
        gload16(BgL + (size_t)(half * 16) * K + k0s + sub * 32,
                Bsb + sub * 4096 + (w * 2 + half) * 512);
    }
}

__global__ __launch_bounds__(256, 2) void gemm_out(
    const unsigned short* __restrict__ A,
    const unsigned short* __restrict__ Bt,
    float* __restrict__ Cf)
{
    __shared__ __align__(16) unsigned short As[2][8192];
    __shared__ __align__(16) unsigned short Bs[2][8192];

    const int K = 1024, N = 2048;
    const int tid = threadIdx.x;
    const int w = tid >> 6, lane = tid & 63, l15 = lane & 15, quad = lane >> 4;
    const int wm = w & 1, wn = w >> 1;

    // XCD-chunked swizzle: 64 consecutive logical tiles (4 A-panel rows) / XCD
    const int orig = blockIdx.x + 16 * blockIdx.y;       // [0, 512)
    const int lb = (orig & 7) * 64 + (orig >> 3);
    const int m0 = (lb >> 4) * 128, n0 = (lb & 15) * 128;

    const int dsrow = lane >> 2;
    const int dscol = ((lane & 3) ^ ((lane >> 3) & 3)) * 8;
    const int sl8   = (((lane & 15) << 2) | ((lane >> 4) ^ ((lane >> 1) & 3))) * 8;

    f32x4 acc[4][4];
    const f32x4 zero4 = {0.f, 0.f, 0.f, 0.f};
#pragma unroll
    for (int i = 0; i < 4; ++i)
#pragma unroll
        for (int j = 0; j < 4; ++j) acc[i][j] = zero4;

    const unsigned short* AgL = A  + (size_t)(m0 + w * 32 + dsrow) * K + dscol;
    const unsigned short* BgL = Bt + (size_t)(n0 + w * 32 + dsrow) * K + dscol;

    const int NT = K >> 6;
    stage_out(AgL, BgL, K, 0, &As[0][0], &Bs[0][0], w);

    int cb = 0;
    for (int t = 0; t < NT; ++t) {
        if (t + 1 < NT) {
            stage_out(AgL, BgL, K, (t + 1) * 64, &As[cb ^ 1][0], &Bs[cb ^ 1][0], w);
            VMCNT(8);
        } else {
            VMCNT(0);
        }
        RBAR();

#pragma unroll
        for (int kk = 0; kk < 2; ++kk) {
            bf16x8 af[4], bf[4];
#pragma unroll
            for (int mt = 0; mt < 4; ++mt)
                af[mt] = *(const bf16x8*)&As[cb][kk * 4096 + (wm * 4 + mt) * 512 + sl8];
#pragma unroll
            for (int nt = 0; nt < 4; ++nt)
                bf[nt] = *(const bf16x8*)&Bs[cb][kk * 4096 + (wn * 4 + nt) * 512 + sl8];
#pragma unroll
            for (int mt = 0; mt < 4; ++mt)
#pragma unroll
                for (int nt = 0; nt < 4; ++nt)
                    acc[mt][nt] = MFMA_BF16(af[mt], bf[nt], acc[mt][nt]);
        }

        if (t + 1 < NT) RBAR();
        cb ^= 1;
    }

#pragma unroll
    for (int mt = 0; mt < 4; ++mt)
#pragma unroll
        for (int nt = 0; nt < 4; ++nt) {
            const int gn = n0 + wn * 64 + nt * 16 + l15;
#pragma unroll
            for (int r = 0; r < 4; ++r) {
                const int gm = m0 + wm * 64 + mt * 16 + quad * 4 + r;
                Cf[(size_t)gm * N + gn] = acc[mt][nt][r];
            }
        }
}

// ---------------------------------------------------------------------------
// MFMA flash attention — 32x32 MFMA structure (R7/R8-proven, unchanged).
// ---------------------------------------------------------------------------
__global__ __launch_bounds__(256, 4) void rosa_attn_mfma(
    const unsigned short* __restrict__ qh,
    const unsigned short* __restrict__ kh,
    const unsigned short* __restrict__ vtt,
    const int* __restrict__ amask,
    const float* __restrict__ emb0,
    const float* __restrict__ emb1,
    unsigned short* __restrict__ ob)
{
    __shared__ __align__(16) unsigned short Ks[2][4096];   // [buf][row(k)*64 + d]
    __shared__ __align__(16) unsigned short Vs[2][4096];   // [buf][row(v)*64 + k]
    __shared__ unsigned int Mflg[4];
    __shared__ float Lred[2][2][32];                       // [kq][qq][q_loc]

    const int a = blockIdx.x & 7, m = blockIdx.x >> 3;
    const int h = blockIdx.y, b = blockIdx.z, g = h >> 2;
    const int hb = h + 16 * b;
    const int sel = (m + (hb >> 3)) & 3;
    const int qt = (sel == 0) ? a : (sel == 1) ? 15 - a : (sel == 2) ? 16 + a : 31 - a;

    const int tid = threadIdx.x;
    const int w = tid >> 6, lane = tid & 63;
    const int kq = w >> 1, qq = w & 1;
    const int l31 = lane & 31, H = lane >> 5, x7 = lane & 7;

    // staging source (two-sided XOR swizzle)
    const int srow = lane >> 3;
    const int scol = ((lane & 7) ^ srow) * 8;
    const unsigned short* kst0 = kh + ((size_t)(b * 2048) + w * 16 + srow) * 256 + g * 64 + scol;
    const unsigned short* vst0 = vtt + ((size_t)(b * 4 + g) * 64 + w * 16 + srow) * 2048 + scol;
    const int* mbase = amask + b * 2048;

    // fragment read addresses (elem index into Ks/Vs[buf]); row&7 == lane&7
    int kadr[4];
#pragma unroll
    for (int mi = 0; mi < 4; ++mi)
        kadr[mi] = (kq * 32 + l31) * 64 + (((mi * 2 + H) ^ x7) * 8);
    int vadr[2][2];
#pragma unroll
    for (int vh = 0; vh < 2; ++vh)
#pragma unroll
        for (int kc = 0; kc < 2; ++kc)
            vadr[vh][kc] = (vh * 32 + l31) * 64 + (((kq * 4 + kc * 2 + H) ^ x7) * 8);

    // causal bitmask for the kq==qq diagonal quadrant: bit r iff k_loc(r)<=q_loc
    unsigned int cbits = 0;
#pragma unroll
    for (int r = 0; r < 16; ++r) {
        const int kl = (r & 3) + 8 * (r >> 2) + 4 * H;
        if (kl <= l31) cbits |= (1u << r);
    }

    const int q0 = qt * 64, nkt = qt + 1;

#define STAGE_TILE(k0s, buf)                                                   \
    {                                                                          \
        gload16(kst0 + (size_t)(k0s) * 256,        &Ks[buf][(w * 16) * 64]);   \
        gload16(kst0 + (size_t)(k0s) * 256 + 2048, &Ks[buf][(w * 16 + 8) * 64]);\
        gload16(vst0 + (k0s),                      &Vs[buf][(w * 16) * 64]);   \
        gload16(vst0 + (k0s) + 16384,              &Vs[buf][(w * 16 + 8) * 64]);\
    }

    const int4 mv0 = *(const int4*)(mbase + tid * 8);
    const int4 mv1 = *(const int4*)(mbase + tid * 8 + 4);

    STAGE_TILE(0, 0)

    // Q fragments (B operand: col=q=lane&31, k=d=(lane>>5)*8+j, 4 d-chunks)
    const unsigned short* qp = qh + ((size_t)(b * 2048 + q0 + qq * 32 + l31) * 16 + h) * 64 + H * 8;
    const bf16x8 qf0 = *(const bf16x8*)(qp);
    const bf16x8 qf1 = *(const bf16x8*)(qp + 16);
    const bf16x8 qf2 = *(const bf16x8*)(qp + 32);
    const bf16x8 qf3 = *(const bf16x8*)(qp + 48);

    // mask chunk-full bitmap
    const bool f8 = mv0.x && mv0.y && mv0.z && mv0.w && mv1.x && mv1.y && mv1.z && mv1.w;
    const unsigned long long bal = __ballot(f8);
    const bool bytefull = ((bal >> ((lane & 7) * 8)) & 0xFFull) == 0xFFull;
    const unsigned long long bal2 = __ballot(bytefull && (lane < 8));
    if (lane == 0) Mflg[w] = (unsigned int)(bal2 & 0xFFull);
    RBAR();
    const unsigned int mflags = Mflg[0] | (Mflg[1] << 8) | (Mflg[2] << 16) | (Mflg[3] << 24);

    const f32x16 z16 = {0.f,0.f,0.f,0.f, 0.f,0.f,0.f,0.f, 0.f,0.f,0.f,0.f, 0.f,0.f,0.f,0.f};
    f32x16 oacc0 = z16, oacc1 = z16;
    float psum = 0.0f;
    const bool skipdiag = (kq > qq);

    int cb = 0;
    for (int kt = 0; kt < nkt; ++kt) {
        if (kt + 1 < nkt) {
            STAGE_TILE((kt + 1) * 64, cb ^ 1)
            VMCNT(4);              // tile kt landed; tile kt+1 stays in flight
        } else {
            VMCNT(0);
        }
        RBAR();

        const bool diag = (kt == qt);
        if (!(diag && skipdiag)) {
            // ---- QK^T quadrant: sc[reg] = S^T[k_loc][q], col=q=lane&31
            const bf16x8 kf0 = *(const bf16x8*)&Ks[cb][kadr[0]];
            const bf16x8 kf1 = *(const bf16x8*)&Ks[cb][kadr[1]];
            const bf16x8 kf2 = *(const bf16x8*)&Ks[cb][kadr[2]];
            const bf16x8 kf3 = *(const bf16x8*)&Ks[cb][kadr[3]];
            __builtin_amdgcn_s_setprio(1);
            f32x16 sc = MFMA32(kf0, qf0, z16);
            sc = MFMA32(kf1, qf1, sc);
            sc = MFMA32(kf2, qf2, sc);
            sc = MFMA32(kf3, qf3, sc);
            __builtin_amdgcn_s_setprio(0);

            // ---- softmax numerators (cexp pre-folded into qh)
            float p[16];
#pragma unroll
            for (int r = 0; r < 16; ++r) p[r] = __builtin_exp2f(sc[r]);
            if (diag && kq == qq) {
#pragma unroll
                for (int r = 0; r < 16; ++r)
                    if (!((cbits >> r) & 1u)) p[r] = 0.0f;
            }
            if (!((mflags >> kt) & 1u)) {      // padded-mask slow path
#pragma unroll
                for (int r = 0; r < 16; ++r) {
                    const int kgl = kt * 64 + kq * 32 + (r & 3) + 8 * (r >> 2) + 4 * H;
                    if (mbase[kgl] == 0) p[r] = 0.0f;
                }
            }
            psum += (((p[0]+p[1])+(p[2]+p[3])) + ((p[4]+p[5])+(p[6]+p[7])))
                  + (((p[8]+p[9])+(p[10]+p[11])) + ((p[12]+p[13])+(p[14]+p[15])));

            // ---- P -> PV A-operand, entirely in registers
            unsigned int W0 = cvtpk(p[0],  p[1]),  W1 = cvtpk(p[2],  p[3]);
            unsigned int W2 = cvtpk(p[4],  p[5]),  W3 = cvtpk(p[6],  p[7]);
            unsigned int W4 = cvtpk(p[8],  p[9]),  W5 = cvtpk(p[10], p[11]);
            unsigned int W6 = cvtpk(p[12], p[13]), W7 = cvtpk(p[14], p[15]);
            PERMSWAP(W0, W2);  PERMSWAP(W1, W3);
            PERMSWAP(W4, W6);  PERMSWAP(W5, W7);
            u32x4 paw0; paw0[0] = W0; paw0[1] = W1; paw0[2] = W2; paw0[3] = W3;
            u32x4 paw1; paw1[0] = W4; paw1[1] = W5; paw1[2] = W6; paw1[3] = W7;
            const bf16x8 pa0 = __builtin_bit_cast(bf16x8, paw0);
            const bf16x8 pa1 = __builtin_bit_cast(bf16x8, paw1);

            // ---- PV: O[q][v] partial for this wave's k-range
            const bf16x8 vb00 = *(const bf16x8*)&Vs[cb][vadr[0][0]];
            const bf16x8 vb01 = *(const bf16x8*)&Vs[cb][vadr[0][1]];
            const bf16x8 vb10 = *(const bf16x8*)&Vs[cb][vadr[1][0]];
            const bf16x8 vb11 = *(const bf16x8*)&Vs[cb][vadr[1][1]];
            __builtin_amdgcn_s_setprio(1);
            oacc0 = MFMA32(pa0, vb00, oacc0);
            oacc0 = MFMA32(pa1, vb01, oacc0);
            oacc1 = MFMA32(pa0, vb10, oacc1);
            oacc1 = MFMA32(pa1, vb11, oacc1);
            __builtin_amdgcn_s_setprio(0);
        }

        if (kt + 1 < nkt) { RBAR(); cb ^= 1; }
    }

    // ---- l: combine lane halves (lanes l, l^32 hold same q, disjoint k)
    psum += __shfl_xor(psum, 32);

    RBAR();                         // all Ks/Vs reads done -> reuse Ks as Ored

    if (H == 0) Lred[kq][qq][l31] = psum;

    // O partial exchange: wave keeps vh=kq, ships vh=1-kq to slot (qq, 1-kq)
    float* Ored = (float*)&Ks[0][0];
    const int slw = qq * 2 + (1 - kq);
    const int cx = (lane & 3) ^ ((lane >> 2) & 3);   // bank-spread XOR
    if (kq == 0) {
#pragma unroll
        for (int c = 0; c < 4; ++c) {
            float4 t = {oacc1[c*4+0], oacc1[c*4+1], oacc1[c*4+2], oacc1[c*4+3]};
            *(float4*)&Ored[slw * 1024 + lane * 16 + ((c ^ cx) * 4)] = t;
        }
    } else {
#pragma unroll
        for (int c = 0; c < 4; ++c) {
            float4 t = {oacc0[c*4+0], oacc0[c*4+1], oacc0[c*4+2], oacc0[c*4+3]};
            *(float4*)&Ored[slw * 1024 + lane * 16 + ((c ^ cx) * 4)] = t;
        }
    }
    RBAR();

    const int slr = qq * 2 + kq;
    f32x16 osum = (kq == 0) ? oacc0 : oacc1;
#pragma unroll
    for (int c = 0; c < 4; ++c) {
        float4 t = *(const float4*)&Ored[slr * 1024 + lane * 16 + ((c ^ cx) * 4)];
        osum[c*4+0] += t.x; osum[c*4+1] += t.y; osum[c*4+2] += t.z; osum[c*4+3] += t.w;
    }

    float rl[16];
#pragma unroll
    for (int r = 0; r < 16; ++r) {
        const int ql = (r & 3) + 8 * (r >> 2) + 4 * H;
        rl[r] = __builtin_amdgcn_rcpf(Lred[0][qq][ql] + Lred[1][qq][ql]);
    }

    // epilogue: lane holds v = kq*32 + l31 (fixed), q per reg -> coalesced
    const int vg = kq * 32 + l31;
    const float e0 = emb0[h * 64 + vg];
    const float ed = emb1[h * 64 + vg] - e0;
    unsigned short* obp = ob + ((size_t)(b * 2048 + q0 + qq * 32) * 16 + h) * 64 + vg;
#pragma unroll
    for (int r = 0; r < 16; ++r) {
        const int ql = (r & 3) + 8 * (r >> 2) + 4 * H;
        const float val = e0 + (osum[r] * rl[r]) * ed;
        obp[(size_t)ql * 1024] = f2b(val);
    }
#undef STAGE_TILE
}

// ---------------------------------------------------------------------------
extern "C" void kernel_launch(void* const* d_in, const int* in_sizes, int n_in,
                              void* d_out, int out_size, void* d_ws, size_t ws_size,
                              hipStream_t stream)
{
    const float* x    = (const float*)d_in[0];
    const int*   amask= (const int*)d_in[1];
    const float* Wq   = (const float*)d_in[2];
    const float* Wk   = (const float*)d_in[3];
    const float* Wv   = (const float*)d_in[4];
    const float* Wo   = (const float*)d_in[5];
    const float* emb0 = (const float*)d_in[6];
    const float* emb1 = (const float*)d_in[7];
    float* out = (float*)d_out;

    char* base = (char*)d_ws;
    unsigned short* xh    = (unsigned short*)(base);                      // 16 MB
    unsigned short* ob    = xh;                                           // aliases xh
    unsigned short* Wqkvt = (unsigned short*)(base + (16u << 20));        // 6 MB
    unsigned short* Wot   = (unsigned short*)(base + (22u << 20));        // 4 MB
    unsigned short* qh    = (unsigned short*)(base + (26u << 20));        // 8 MB
    unsigned short* kh    = (unsigned short*)(base + (34u << 20));        // 2 MB
    unsigned short* vtt   = (unsigned short*)(base + (36u << 20));        // 2 MB

    prep<<<7168, 256, 0, stream>>>(x, xh, Wq, Wk, Wv, Wqkvt, Wo, Wot);

    gemm_qkv<<<dim3(24, 32), 256, 0, stream>>>(xh, Wqkvt, qh, kh, vtt);
    rosa_attn_mfma<<<dim3(32, 16, 2), 256, 0, stream>>>(qh, kh, vtt, amask, emb0, emb1, ob);
    gemm_out<<<dim3(16, 32), 256, 0, stream>>>(ob, Wot, out);
}

// Round 10
// 210.644 us; speedup vs baseline: 1.5311x; 1.0156x over previous
//
#include <hip/hip_runtime.h>
#include <math.h>

typedef short bf16x8 __attribute__((ext_vector_type(8)));
typedef float f32x4 __attribute__((ext_vector_type(4)));
typedef float f32x16 __attribute__((ext_vector_type(16)));
typedef unsigned int u32x2 __attribute__((ext_vector_type(2)));
typedef unsigned int u32x4 __attribute__((ext_vector_type(4)));

#define MFMA_BF16(A,B,C) __builtin_amdgcn_mfma_f32_16x16x32_bf16(A,B,C,0,0,0)
#define MFMA32(A,B,C)    __builtin_amdgcn_mfma_f32_32x32x16_bf16(A,B,C,0,0,0)

// counted vmcnt wait: loads newer than the N most recent stay in flight
#define VMCNT(N) asm volatile("s_waitcnt vmcnt(" #N ")" ::: "memory")
// raw barrier (no vmcnt drain!) with compiler memory fences on both sides
#define RBAR() do { asm volatile("" ::: "memory"); __builtin_amdgcn_s_barrier(); \
                    asm volatile("" ::: "memory"); } while (0)
// in-place half-swap: a = [a_lo | b_lo], b = [a_hi | b_hi]
#define PERMSWAP(a, b) asm volatile("v_permlane32_swap_b32 %0, %1" : "+v"(a), "+v"(b))

__device__ __forceinline__ unsigned short f2b(float x) {
    union { float f; unsigned int u; } v; v.f = x;
    unsigned int r = v.u + 0x7FFFu + ((v.u >> 16) & 1u);
    return (unsigned short)(r >> 16);
}

// packed f32x2 -> bf16x2 (RNE), single instruction
__device__ __forceinline__ unsigned int cvtpk(float lo, float hi) {
    unsigned int r;
    asm("v_cvt_pk_bf16_f32 %0, %1, %2" : "=v"(r) : "v"(lo), "v"(hi));
    return r;
}

// async global->LDS DMA, 16B per lane; LDS dest = wave-uniform base + lane*16
__device__ __forceinline__ void gload16(const unsigned short* g, unsigned short* l) {
    __builtin_amdgcn_global_load_lds(
        (const __attribute__((address_space(1))) unsigned int*)(g),
        (__attribute__((address_space(3))) unsigned int*)(l),
        16, 0, 0);
}

// ---------------------------------------------------------------------------
// Fused preprocessing (R9-proven, unchanged): one dispatch for
// x->bf16, Wq|Wk|Wv transpose+convert, Wo transpose+convert.
// ---------------------------------------------------------------------------
__global__ __launch_bounds__(256) void prep(
    const float* __restrict__ x, unsigned short* __restrict__ xh,
    const float* __restrict__ Wq, const float* __restrict__ Wk,
    const float* __restrict__ Wv, unsigned short* __restrict__ Wqkvt,
    const float* __restrict__ Wo, unsigned short* __restrict__ Wot)
{
    __shared__ float t[32][33];
    const int bid = blockIdx.x, tid = threadIdx.x;

    if (bid < 2048) {                       // ---- conv_bf16(x -> xh)
        const int n = 4096 * 2048;
        int i = bid * 256 + tid;
        int stride = 2048 * 256;
        for (int idx = i * 4; idx < n; idx += stride * 4) {
            float4 v = *(const float4*)(x + idx);
            ushort4 o;
            o.x = f2b(v.x); o.y = f2b(v.y); o.z = f2b(v.z); o.w = f2b(v.w);
            *(ushort4*)(xh + idx) = o;
        }
        return;
    }

    const int tx = tid & 31, ty = tid >> 5;

    if (bid < 5120) {                       // ---- transp_conv_qkv
        const int idx = bid - 2048;
        const int bx = idx % 48, by = idx / 48;
        const float* src; int C, cb, dco;
        if (bx < 32)      { src = Wq; C = 1024; cb = bx;      dco = 0; }
        else if (bx < 40) { src = Wk; C = 256;  cb = bx - 32; dco = 1024; }
        else              { src = Wv; C = 256;  cb = bx - 40; dco = 1280; }
        const int c = cb * 32 + tx;
        const int r0 = by * 32;
#pragma unroll
        for (int i = 0; i < 4; ++i)
            t[ty + i * 8][tx] = src[(size_t)(r0 + ty + i * 8) * C + c];
        __syncthreads();
        const int cc = cb * 32 + ty;
#pragma unroll
        for (int i = 0; i < 4; ++i)
            Wqkvt[(size_t)(dco + cc + i * 8) * 2048 + r0 + tx] = f2b(t[tx][ty + i * 8]);
        return;
    }

    {                                       // ---- transp_conv(Wo -> Wot)
        const int idx = bid - 5120;
        const int bx = idx % 64, by = idx / 64;
        const int c = bx * 32 + tx;
        const int r0 = by * 32;
#pragma unroll
        for (int i = 0; i < 4; ++i)
            t[ty + i * 8][tx] = Wo[(size_t)(r0 + ty + i * 8) * 2048 + c];
        __syncthreads();
        const int cc = bx * 32 + ty;
#pragma unroll
        for (int i = 0; i < 4; ++i)
            Wot[(size_t)(cc + i * 8) * 1024 + r0 + tx] = f2b(t[tx][ty + i * 8]);
    }
}

// ---------------------------------------------------------------------------
// GEMM 1 (QKV projections) — R9-proven, unchanged: 128x64, 3 blocks/CU,
// two-sided swizzle, counted vmcnt(6), XCD-chunked block swizzle.
// ---------------------------------------------------------------------------
__device__ __forceinline__ void stage_qkv(const unsigned short* AgL, const unsigned short* BgL,
                                          int K, int k0s,
                                          unsigned short* Asb, unsigned short* Bsb, int w)
{
#pragma unroll
    for (int t = 0; t < 4; ++t) {
        const int sub = t >> 1, half = t & 1;
        gload16(AgL + (size_t)(half * 16) * K + k0s + sub * 32,
                Asb + sub * 4096 + (w * 2 + half) * 512);
    }
#pragma unroll
    for (int kk = 0; kk < 2; ++kk)
        gload16(BgL + k0s + kk * 32, Bsb + kk * 2048 + w * 512);
}

__global__ __launch_bounds__(256, 3) void gemm_qkv(
    const unsigned short* __restrict__ A,
    const unsigned short* __restrict__ Bt,
    unsigned short* __restrict__ qh,
    unsigned short* __restrict__ kh,
    unsigned short* __restrict__ vtt)
{
    __shared__ __align__(16) unsigned short As[2][2 * 128 * 32];
    __shared__ __align__(16) unsigned short Bs[2][2 * 64 * 32];

    const int K = 2048;
    const int tid = threadIdx.x;
    const int w = tid >> 6, lane = tid & 63, l15 = lane & 15, quad = lane >> 4;
    const int wm = w & 1, wn = w >> 1;

    const int orig = blockIdx.x + 24 * blockIdx.y;       // [0, 768)
    const int lb = (orig & 7) * 96 + (orig >> 3);
    const int m0 = (lb / 24) * 128, n0 = (lb % 24) * 64;

    const int dsrow = lane >> 2;
    const int dscol = ((lane & 3) ^ ((lane >> 3) & 3)) * 8;
    const int sl8   = (((lane & 15) << 2) | ((lane >> 4) ^ ((lane >> 1) & 3))) * 8;

    f32x4 acc[4][2];
    const f32x4 zero4 = {0.f, 0.f, 0.f, 0.f};
#pragma unroll
    for (int i = 0; i < 4; ++i)
#pragma unroll
        for (int j = 0; j < 2; ++j) acc[i][j] = zero4;

    const unsigned short* AgL = A  + (size_t)(m0 + w * 32 + dsrow) * K + dscol;
    const unsigned short* BgL = Bt + (size_t)(n0 + w * 16 + dsrow) * K + dscol;

    const int NT = K >> 6;
    stage_qkv(AgL, BgL, K, 0, &As[0][0], &Bs[0][0], w);

    int cb = 0;
    for (int t = 0; t < NT; ++t) {
        if (t + 1 < NT) {
            stage_qkv(AgL, BgL, K, (t + 1) * 64, &As[cb ^ 1][0], &Bs[cb ^ 1][0], w);
            VMCNT(6);
        } else {
            VMCNT(0);
        }
        RBAR();

        bf16x8 af[4][2], bf[2][2];
#pragma unroll
        for (int kk = 0; kk < 2; ++kk) {
#pragma unroll
            for (int mt = 0; mt < 4; ++mt)
                af[mt][kk] = *(const bf16x8*)&As[cb][kk * 4096 + (wm * 4 + mt) * 512 + sl8];
#pragma unroll
            for (int nt = 0; nt < 2; ++nt)
                bf[nt][kk] = *(const bf16x8*)&Bs[cb][kk * 2048 + (wn * 2 + nt) * 512 + sl8];
        }
#pragma unroll
        for (int kk = 0; kk < 2; ++kk)
#pragma unroll
            for (int mt = 0; mt < 4; ++mt)
#pragma unroll
                for (int nt = 0; nt < 2; ++nt)
                    acc[mt][nt] = MFMA_BF16(af[mt][kk], bf[nt][kk], acc[mt][nt]);

        if (t + 1 < NT) RBAR();
        cb ^= 1;
    }

    if (n0 < 1024) {            // Q: tanh * cexp -> qh[m][n], pitch 1024
#pragma unroll
        for (int mt = 0; mt < 4; ++mt)
#pragma unroll
            for (int nt = 0; nt < 2; ++nt) {
                const int gn = n0 + wn * 32 + nt * 16 + l15;
#pragma unroll
                for (int r = 0; r < 4; ++r) {
                    const int gm = m0 + wm * 64 + mt * 16 + quad * 4 + r;
                    qh[(size_t)gm * 1024 + gn] = f2b(tanhf(acc[mt][nt][r]) * 0.0225421100f);
                }
            }
    } else if (n0 < 1280) {     // K: tanh -> kh[m][n-1024], pitch 256
#pragma unroll
        for (int mt = 0; mt < 4; ++mt)
#pragma unroll
            for (int nt = 0; nt < 2; ++nt) {
                const int gn = n0 + wn * 32 + nt * 16 + l15 - 1024;
#pragma unroll
                for (int r = 0; r < 4; ++r) {
                    const int gm = m0 + wm * 64 + mt * 16 + quad * 4 + r;
                    kh[(size_t)gm * 256 + gn] = f2b(tanhf(acc[mt][nt][r]));
                }
            }
    } else {                    // V: sigmoid -> vtt[(b*4+g)*64+v][s]
#pragma unroll
        for (int mt = 0; mt < 4; ++mt)
#pragma unroll
            for (int nt = 0; nt < 2; ++nt) {
                const int gn = n0 + wn * 32 + nt * 16 + l15 - 1280;
                const int g = gn >> 6, vv = gn & 63;
                const int s0 = m0 + wm * 64 + mt * 16 + quad * 4;
                const int b = s0 >> 11, sl = s0 & 2047;
                ushort4 pk;
                unsigned short* pp = (unsigned short*)&pk;
#pragma unroll
                for (int r = 0; r < 4; ++r) {
                    float sv = 1.0f / (1.0f + __expf(-acc[mt][nt][r]));
                    pp[r] = f2b(sv);
                }
                *(ushort4*)&vtt[((size_t)(b * 4 + g) * 64 + vv) * 2048 + sl] = pk;
            }
    }
}

// ---------------------------------------------------------------------------
// GEMM 2 (output projection) — R9-proven, unchanged: 128x128, 2/CU balanced,
// counted vmcnt(8), XCD-chunked swizzle.
// ---------------------------------------------------------------------------
__device__ __forceinline__ void stage_out(const unsigned short* AgL, const unsigned short* BgL,
                                          int K, int k0s,
                                          unsigned short* Asb, unsigned short* Bsb, int w)
{
#pragma unroll
    for (int t = 0; t < 4; ++t) {
        const int sub = t >> 1, half = t & 1;
        gload16(AgL + (size_t)(half * 16) * K + k0s + sub * 32,
                Asb + sub * 4096 + (w * 2 + half) * 512);
        gload16(BgL + (size_t)(half * 16) * K + k0s + sub * 32,
                Bsb + sub * 4096 + (w * 2 + half) * 512);
    }
}

__global__ __launch_bounds__(256, 2) void gemm_out(
    const unsigned short* __restrict__ A,
    const unsigned short* __restrict__ Bt,
    float* __restrict__ Cf)
{
    __shared__ __align__(16) unsigned short As[2][8192];
    __shared__ __align__(16) unsigned short Bs[2][8192];

    const int K = 1024, N = 2048;
    const int tid = threadIdx.x;
    const int w = tid >> 6, lane = tid & 63, l15 = lane & 15, quad = lane >> 4;
    const int wm = w & 1, wn = w >> 1;

    const int orig = blockIdx.x + 16 * blockIdx.y;       // [0, 512)
    const int lb = (orig & 7) * 64 + (orig >> 3);
    const int m0 = (lb >> 4) * 128, n0 = (lb & 15) * 128;

    const int dsrow = lane >> 2;
    const int dscol = ((lane & 3) ^ ((lane >> 3) & 3)) * 8;
    const int sl8   = (((lane & 15) << 2) | ((lane >> 4) ^ ((lane >> 1) & 3))) * 8;

    f32x4 acc[4][4];
    const f32x4 zero4 = {0.f, 0.f, 0.f, 0.f};
#pragma unroll
    for (int i = 0; i < 4; ++i)
#pragma unroll
        for (int j = 0; j < 4; ++j) acc[i][j] = zero4;

    const unsigned short* AgL = A  + (size_t)(m0 + w * 32 + dsrow) * K + dscol;
    const unsigned short* BgL = Bt + (size_t)(n0 + w * 32 + dsrow) * K + dscol;

    const int NT = K >> 6;
    stage_out(AgL, BgL, K, 0, &As[0][0], &Bs[0][0], w);

    int cb = 0;
    for (int t = 0; t < NT; ++t) {
        if (t + 1 < NT) {
            stage_out(AgL, BgL, K, (t + 1) * 64, &As[cb ^ 1][0], &Bs[cb ^ 1][0], w);
            VMCNT(8);
        } else {
            VMCNT(0);
        }
        RBAR();

#pragma unroll
        for (int kk = 0; kk < 2; ++kk) {
            bf16x8 af[4], bf[4];
#pragma unroll
            for (int mt = 0; mt < 4; ++mt)
                af[mt] = *(const bf16x8*)&As[cb][kk * 4096 + (wm * 4 + mt) * 512 + sl8];
#pragma unroll
            for (int nt = 0; nt < 4; ++nt)
                bf[nt] = *(const bf16x8*)&Bs[cb][kk * 4096 + (wn * 4 + nt) * 512 + sl8];
#pragma unroll
            for (int mt = 0; mt < 4; ++mt)
#pragma unroll
                for (int nt = 0; nt < 4; ++nt)
                    acc[mt][nt] = MFMA_BF16(af[mt], bf[nt], acc[mt][nt]);
        }

        if (t + 1 < NT) RBAR();
        cb ^= 1;
    }

#pragma unroll
    for (int mt = 0; mt < 4; ++mt)
#pragma unroll
        for (int nt = 0; nt < 4; ++nt) {
            const int gn = n0 + wn * 64 + nt * 16 + l15;
#pragma unroll
            for (int r = 0; r < 4; ++r) {
                const int gm = m0 + wm * 64 + mt * 16 + quad * 4 + r;
                Cf[(size_t)gm * N + gn] = acc[mt][nt][r];
            }
        }
}

// ---------------------------------------------------------------------------
// MFMA flash attention — R10: 2 heads per block, 8 waves (512 thr), ONE K/V
// staging shared by both heads.  Grid (32,8,2) = 512 blocks = exactly 2/CU,
// 16 waves/CU (same as R9); stage bytes, DMA issues, barrier events and K/V
// L2 reads per head-work all halved.  Wave w: head-sel hs=w>>2, quadrant
// (kq,qq)=((w>>1)&1, w&1) — per-wave inner code identical to R9 (~56 VGPR).
// Balance: co-resident orbit {c, c+256} differs in b; qt(b=1)=31-qt(b=0) ->
// per-CU work = 33 k-tiles exactly; short block frees 8 waves for the long.
// ---------------------------------------------------------------------------
__global__ __launch_bounds__(512, 4) void rosa_attn_mfma(
    const unsigned short* __restrict__ qh,
    const unsigned short* __restrict__ kh,
    const unsigned short* __restrict__ vtt,
    const int* __restrict__ amask,
    const float* __restrict__ emb0,
    const float* __restrict__ emb1,
    unsigned short* __restrict__ ob)
{
    // K tile: KVs[buf*4096 + row*64 + d]; V tile: KVs[8192 + buf*4096 + row*64 + k]
    __shared__ __align__(16) unsigned short KVs[16384];    // 32 KB; reused as Ored (2x16KB)
    __shared__ unsigned int Mflg[8];
    __shared__ float Lred[2][2][2][32];                    // [hs][kq][qq][q_loc]

    const int a = blockIdx.x & 7, m = blockIdx.x >> 3;
    const int hp = blockIdx.y, b = blockIdx.z;
    const int g = hp >> 1, jp = hp & 1;
    const int qt0 = (m == 0) ? a : (m == 1) ? 15 - a : (m == 2) ? 16 + a : 31 - a;
    const int qt = b ? (31 - qt0) : qt0;

    const int tid = threadIdx.x;
    const int w = tid >> 6, lane = tid & 63;
    const int hs = w >> 2, kq = (w >> 1) & 1, qq = w & 1;
    const int h = g * 4 + jp * 2 + hs;
    const int l31 = lane & 31, H = lane >> 5, x7 = lane & 7;

    // staging lanes (two-sided XOR swizzle); wave w stages 16-row strip wr:
    // waves 0-3 -> K, waves 4-7 -> V
    const int srow = lane >> 3;
    const int scol = ((lane & 7) ^ srow) * 8;
    const int wr = (w & 3) * 16;
    const bool isv = (w >= 4);
    const unsigned short* kst0 = kh + ((size_t)(b * 2048) + wr + srow) * 256 + g * 64 + scol;
    const unsigned short* vst0 = vtt + ((size_t)(b * 4 + g) * 64 + wr + srow) * 2048 + scol;
    const int* mbase = amask + b * 2048;

    // fragment read addresses (elem index); row&7 == lane&7 matches swizzle
    int kadr[4];
#pragma unroll
    for (int mi = 0; mi < 4; ++mi)
        kadr[mi] = (kq * 32 + l31) * 64 + (((mi * 2 + H) ^ x7) * 8);
    int vadr[2][2];
#pragma unroll
    for (int vh = 0; vh < 2; ++vh)
#pragma unroll
        for (int kc = 0; kc < 2; ++kc)
            vadr[vh][kc] = 8192 + (vh * 32 + l31) * 64 + (((kq * 4 + kc * 2 + H) ^ x7) * 8);

    // causal bitmask for the kq==qq diagonal quadrant
    unsigned int cbits = 0;
#pragma unroll
    for (int r = 0; r < 16; ++r) {
        const int kl = (r & 3) + 8 * (r >> 2) + 4 * H;
        if (kl <= l31) cbits |= (1u << r);
    }

    const int q0 = qt * 64, nkt = qt + 1;

#define STAGE_TILE(k0s, buf)                                                        \
    if (!isv) {                                                                     \
        gload16(kst0 + (size_t)(k0s) * 256,        &KVs[(buf) * 4096 + wr * 64]);        \
        gload16(kst0 + (size_t)(k0s) * 256 + 2048, &KVs[(buf) * 4096 + (wr + 8) * 64]);  \
    } else {                                                                        \
        gload16(vst0 + (k0s),                      &KVs[8192 + (buf) * 4096 + wr * 64]);       \
        gload16(vst0 + (k0s) + 16384,              &KVs[8192 + (buf) * 4096 + (wr + 8) * 64]); \
    }

    const int4 mv = *(const int4*)(mbase + tid * 4);       // 512 thr x 4 = 2048

    STAGE_TILE(0, 0)

    // Q fragments (B operand: col=q=lane&31, k=d=(lane>>5)*8+j; cexp folded)
    const unsigned short* qp = qh + ((size_t)(b * 2048 + q0 + qq * 32 + l31) * 16 + h) * 64 + H * 8;
    const bf16x8 qf0 = *(const bf16x8*)(qp);
    const bf16x8 qf1 = *(const bf16x8*)(qp + 16);
    const bf16x8 qf2 = *(const bf16x8*)(qp + 32);
    const bf16x8 qf3 = *(const bf16x8*)(qp + 48);

    // mask chunk-full bitmap: wave w covers chunks 4w..4w+3 (16 lanes each)
    const bool f8 = mv.x && mv.y && mv.z && mv.w;
    const unsigned long long bal = __ballot(f8);
    bool cf = false;
    if (lane < 4) cf = ((bal >> (lane * 16)) & 0xFFFFull) == 0xFFFFull;
    const unsigned int wb = (unsigned int)(__ballot((lane < 4) && cf) & 0xFull);
    if (lane == 0) Mflg[w] = wb;
    RBAR();
    unsigned int mflags = 0;
#pragma unroll
    for (int i = 0; i < 8; ++i) mflags |= Mflg[i] << (i * 4);

    const f32x16 z16 = {0.f,0.f,0.f,0.f, 0.f,0.f,0.f,0.f, 0.f,0.f,0.f,0.f, 0.f,0.f,0.f,0.f};
    f32x16 oacc0 = z16, oacc1 = z16;
    float psum = 0.0f;
    const bool skipdiag = (kq > qq);

    int cb = 0;
    for (int kt = 0; kt < nkt; ++kt) {
        if (kt + 1 < nkt) {
            STAGE_TILE((kt + 1) * 64, cb ^ 1)
            VMCNT(2);              // tile kt's 2 loads landed; tile kt+1 in flight
        } else {
            VMCNT(0);
        }
        RBAR();

        const bool diag = (kt == qt);
        if (!(diag && skipdiag)) {
            // ---- QK^T quadrant: sc = S^T[k_loc][q], col=q=lane&31
            const bf16x8 kf0 = *(const bf16x8*)&KVs[cb * 4096 + kadr[0]];
            const bf16x8 kf1 = *(const bf16x8*)&KVs[cb * 4096 + kadr[1]];
            const bf16x8 kf2 = *(const bf16x8*)&KVs[cb * 4096 + kadr[2]];
            const bf16x8 kf3 = *(const bf16x8*)&KVs[cb * 4096 + kadr[3]];
            __builtin_amdgcn_s_setprio(1);
            f32x16 sc = MFMA32(kf0, qf0, z16);
            sc = MFMA32(kf1, qf1, sc);
            sc = MFMA32(kf2, qf2, sc);
            sc = MFMA32(kf3, qf3, sc);
            __builtin_amdgcn_s_setprio(0);

            // ---- softmax numerators (cexp pre-folded into qh)
            float p[16];
#pragma unroll
            for (int r = 0; r < 16; ++r) p[r] = __builtin_exp2f(sc[r]);
            if (diag && kq == qq) {
#pragma unroll
                for (int r = 0; r < 16; ++r)
                    if (!((cbits >> r) & 1u)) p[r] = 0.0f;
            }
            if (!((mflags >> kt) & 1u)) {      // padded-mask slow path
#pragma unroll
                for (int r = 0; r < 16; ++r) {
                    const int kgl = kt * 64 + kq * 32 + (r & 3) + 8 * (r >> 2) + 4 * H;
                    if (mbase[kgl] == 0) p[r] = 0.0f;
                }
            }
            psum += (((p[0]+p[1])+(p[2]+p[3])) + ((p[4]+p[5])+(p[6]+p[7])))
                  + (((p[8]+p[9])+(p[10]+p[11])) + ((p[12]+p[13])+(p[14]+p[15])));

            // ---- P -> PV A-operand, entirely in registers
            unsigned int W0 = cvtpk(p[0],  p[1]),  W1 = cvtpk(p[2],  p[3]);
            unsigned int W2 = cvtpk(p[4],  p[5]),  W3 = cvtpk(p[6],  p[7]);
            unsigned int W4 = cvtpk(p[8],  p[9]),  W5 = cvtpk(p[10], p[11]);
            unsigned int W6 = cvtpk(p[12], p[13]), W7 = cvtpk(p[14], p[15]);
            PERMSWAP(W0, W2);  PERMSWAP(W1, W3);
            PERMSWAP(W4, W6);  PERMSWAP(W5, W7);
            u32x4 paw0; paw0[0] = W0; paw0[1] = W1; paw0[2] = W2; paw0[3] = W3;
            u32x4 paw1; paw1[0] = W4; paw1[1] = W5; paw1[2] = W6; paw1[3] = W7;
            const bf16x8 pa0 = __builtin_bit_cast(bf16x8, paw0);
            const bf16x8 pa1 = __builtin_bit_cast(bf16x8, paw1);

            // ---- PV: O[q][v] partial for this wave's k-range
            const bf16x8 vb00 = *(const bf16x8*)&KVs[cb * 4096 + vadr[0][0]];
            const bf16x8 vb01 = *(const bf16x8*)&KVs[cb * 4096 + vadr[0][1]];
            const bf16x8 vb10 = *(const bf16x8*)&KVs[cb * 4096 + vadr[1][0]];
            const bf16x8 vb11 = *(const bf16x8*)&KVs[cb * 4096 + vadr[1][1]];
            __builtin_amdgcn_s_setprio(1);
            oacc0 = MFMA32(pa0, vb00, oacc0);
            oacc0 = MFMA32(pa1, vb01, oacc0);
            oacc1 = MFMA32(pa0, vb10, oacc1);
            oacc1 = MFMA32(pa1, vb11, oacc1);
            __builtin_amdgcn_s_setprio(0);
        }

        if (kt + 1 < nkt) { RBAR(); cb ^= 1; }
    }

    // ---- l: combine lane halves (lanes l, l^32 hold same q, disjoint k)
    psum += __shfl_xor(psum, 32);

    RBAR();                         // all K/V reads done -> reuse KVs as Ored

    if (H == 0) Lred[hs][kq][qq][l31] = psum;

    // O partial exchange within head hs: keep vh=kq, ship vh=1-kq
    float* Ored = (float*)&KVs[0] + hs * 4096;     // 16 KB per head
    const int slw = qq * 2 + (1 - kq);
    const int cx = (lane & 3) ^ ((lane >> 2) & 3);
    if (kq == 0) {
#pragma unroll
        for (int c = 0; c < 4; ++c) {
            float4 t = {oacc1[c*4+0], oacc1[c*4+1], oacc1[c*4+2], oacc1[c*4+3]};
            *(float4*)&Ored[slw * 1024 + lane * 16 + ((c ^ cx) * 4)] = t;
        }
    } else {
#pragma unroll
        for (int c = 0; c < 4; ++c) {
            float4 t = {oacc0[c*4+0], oacc0[c*4+1], oacc0[c*4+2], oacc0[c*4+3]};
            *(float4*)&Ored[slw * 1024 + lane * 16 + ((c ^ cx) * 4)] = t;
        }
    }
    RBAR();

    const int slr = qq * 2 + kq;
    f32x16 osum = (kq == 0) ? oacc0 : oacc1;
#pragma unroll
    for (int c = 0; c < 4; ++c) {
        float4 t = *(const float4*)&Ored[slr * 1024 + lane * 16 + ((c ^ cx) * 4)];
        osum[c*4+0] += t.x; osum[c*4+1] += t.y; osum[c*4+2] += t.z; osum[c*4+3] += t.w;
    }

    float rl[16];
#pragma unroll
    for (int r = 0; r < 16; ++r) {
        const int ql = (r & 3) + 8 * (r >> 2) + 4 * H;
        rl[r] = __builtin_amdgcn_rcpf(Lred[hs][0][qq][ql] + Lred[hs][1][qq][ql]);
    }

    // epilogue: lane holds v = kq*32 + l31 (fixed), q per reg -> coalesced
    const int vg = kq * 32 + l31;
    const float e0 = emb0[h * 64 + vg];
    const float ed = emb1[h * 64 + vg] - e0;
    unsigned short* obp = ob + ((size_t)(b * 2048 + q0 + qq * 32) * 16 + h) * 64 + vg;
#pragma unroll
    for (int r = 0; r < 16; ++r) {
        const int ql = (r & 3) + 8 * (r >> 2) + 4 * H;
        const float val = e0 + (osum[r] * rl[r]) * ed;
        obp[(size_t)ql * 1024] = f2b(val);
    }
#undef STAGE_TILE
}

// ---------------------------------------------------------------------------
extern "C" void kernel_launch(void* const* d_in, const int* in_sizes, int n_in,
                              void* d_out, int out_size, void* d_ws, size_t ws_size,
                              hipStream_t stream)
{
    const float* x    = (const float*)d_in[0];
    const int*   amask= (const int*)d_in[1];
    const float* Wq   = (const float*)d_in[2];
    const float* Wk   = (const float*)d_in[3];
    const float* Wv   = (const float*)d_in[4];
    const float* Wo   = (const float*)d_in[5];
    const float* emb0 = (const float*)d_in[6];
    const float* emb1 = (const float*)d_in[7];
    float* out = (float*)d_out;

    char* base = (char*)d_ws;
    unsigned short* xh    = (unsigned short*)(base);                      // 16 MB
    unsigned short* ob    = xh;                                           // aliases xh
    unsigned short* Wqkvt = (unsigned short*)(base + (16u << 20));        // 6 MB
    unsigned short* Wot   = (unsigned short*)(base + (22u << 20));        // 4 MB
    unsigned short* qh    = (unsigned short*)(base + (26u << 20));        // 8 MB
    unsigned short* kh    = (unsigned short*)(base + (34u << 20));        // 2 MB
    unsigned short* vtt   = (unsigned short*)(base + (36u << 20));        // 2 MB

    prep<<<7168, 256, 0, stream>>>(x, xh, Wq, Wk, Wv, Wqkvt, Wo, Wot);

    gemm_qkv<<<dim3(24, 32), 256, 0, stream>>>(xh, Wqkvt, qh, kh, vtt);
    rosa_attn_mfma<<<dim3(32, 8, 2), 512, 0, stream>>>(qh, kh, vtt, amask, emb0, emb1, ob);
    gemm_out<<<dim3(16, 32), 256, 0, stream>>>(ob, Wot, out);
}

// Round 11
// 205.297 us; speedup vs baseline: 1.5710x; 1.0260x over previous
//
#include <hip/hip_runtime.h>
#include <math.h>

typedef short bf16x8 __attribute__((ext_vector_type(8)));
typedef float f32x4 __attribute__((ext_vector_type(4)));
typedef float f32x16 __attribute__((ext_vector_type(16)));
typedef unsigned int u32x2 __attribute__((ext_vector_type(2)));
typedef unsigned int u32x4 __attribute__((ext_vector_type(4)));

#define MFMA_BF16(A,B,C) __builtin_amdgcn_mfma_f32_16x16x32_bf16(A,B,C,0,0,0)
#define MFMA32(A,B,C)    __builtin_amdgcn_mfma_f32_32x32x16_bf16(A,B,C,0,0,0)

// counted vmcnt wait: loads newer than the N most recent stay in flight
#define VMCNT(N) asm volatile("s_waitcnt vmcnt(" #N ")" ::: "memory")
// raw barrier (no vmcnt drain!) with compiler memory fences on both sides
#define RBAR() do { asm volatile("" ::: "memory"); __builtin_amdgcn_s_barrier(); \
                    asm volatile("" ::: "memory"); } while (0)
// in-place half-swap: a = [a_lo | b_lo], b = [a_hi | b_hi]
#define PERMSWAP(a, b) asm volatile("v_permlane32_swap_b32 %0, %1" : "+v"(a), "+v"(b))

__device__ __forceinline__ unsigned short f2b(float x) {
    union { float f; unsigned int u; } v; v.f = x;
    unsigned int r = v.u + 0x7FFFu + ((v.u >> 16) & 1u);
    return (unsigned short)(r >> 16);
}

// packed f32x2 -> bf16x2 (RNE), single instruction
__device__ __forceinline__ unsigned int cvtpk(float lo, float hi) {
    unsigned int r;
    asm("v_cvt_pk_bf16_f32 %0, %1, %2" : "=v"(r) : "v"(lo), "v"(hi));
    return r;
}

// async global->LDS DMA, 16B per lane; LDS dest = wave-uniform base + lane*16
__device__ __forceinline__ void gload16(const unsigned short* g, unsigned short* l) {
    __builtin_amdgcn_global_load_lds(
        (const __attribute__((address_space(1))) unsigned int*)(g),
        (__attribute__((address_space(3))) unsigned int*)(l),
        16, 0, 0);
}

// ---------------------------------------------------------------------------
// Fused preprocessing (R9-proven, unchanged).
// ---------------------------------------------------------------------------
__global__ __launch_bounds__(256) void prep(
    const float* __restrict__ x, unsigned short* __restrict__ xh,
    const float* __restrict__ Wq, const float* __restrict__ Wk,
    const float* __restrict__ Wv, unsigned short* __restrict__ Wqkvt,
    const float* __restrict__ Wo, unsigned short* __restrict__ Wot)
{
    __shared__ float t[32][33];
    const int bid = blockIdx.x, tid = threadIdx.x;

    if (bid < 2048) {                       // ---- conv_bf16(x -> xh)
        const int n = 4096 * 2048;
        int i = bid * 256 + tid;
        int stride = 2048 * 256;
        for (int idx = i * 4; idx < n; idx += stride * 4) {
            float4 v = *(const float4*)(x + idx);
            ushort4 o;
            o.x = f2b(v.x); o.y = f2b(v.y); o.z = f2b(v.z); o.w = f2b(v.w);
            *(ushort4*)(xh + idx) = o;
        }
        return;
    }

    const int tx = tid & 31, ty = tid >> 5;

    if (bid < 5120) {                       // ---- transp_conv_qkv
        const int idx = bid - 2048;
        const int bx = idx % 48, by = idx / 48;
        const float* src; int C, cb, dco;
        if (bx < 32)      { src = Wq; C = 1024; cb = bx;      dco = 0; }
        else if (bx < 40) { src = Wk; C = 256;  cb = bx - 32; dco = 1024; }
        else              { src = Wv; C = 256;  cb = bx - 40; dco = 1280; }
        const int c = cb * 32 + tx;
        const int r0 = by * 32;
#pragma unroll
        for (int i = 0; i < 4; ++i)
            t[ty + i * 8][tx] = src[(size_t)(r0 + ty + i * 8) * C + c];
        __syncthreads();
        const int cc = cb * 32 + ty;
#pragma unroll
        for (int i = 0; i < 4; ++i)
            Wqkvt[(size_t)(dco + cc + i * 8) * 2048 + r0 + tx] = f2b(t[tx][ty + i * 8]);
        return;
    }

    {                                       // ---- transp_conv(Wo -> Wot)
        const int idx = bid - 5120;
        const int bx = idx % 64, by = idx / 64;
        const int c = bx * 32 + tx;
        const int r0 = by * 32;
#pragma unroll
        for (int i = 0; i < 4; ++i)
            t[ty + i * 8][tx] = Wo[(size_t)(r0 + ty + i * 8) * 2048 + c];
        __syncthreads();
        const int cc = bx * 32 + ty;
#pragma unroll
        for (int i = 0; i < 4; ++i)
            Wot[(size_t)(cc + i * 8) * 1024 + r0 + tx] = f2b(t[tx][ty + i * 8]);
    }
}

// ---------------------------------------------------------------------------
// GEMM 1 (QKV projections) — R9-proven, unchanged.
// ---------------------------------------------------------------------------
__device__ __forceinline__ void stage_qkv(const unsigned short* AgL, const unsigned short* BgL,
                                          int K, int k0s,
                                          unsigned short* Asb, unsigned short* Bsb, int w)
{
#pragma unroll
    for (int t = 0; t < 4; ++t) {
        const int sub = t >> 1, half = t & 1;
        gload16(AgL + (size_t)(half * 16) * K + k0s + sub * 32,
                Asb + sub * 4096 + (w * 2 + half) * 512);
    }
#pragma unroll
    for (int kk = 0; kk < 2; ++kk)
        gload16(BgL + k0s + kk * 32, Bsb + kk * 2048 + w * 512);
}

__global__ __launch_bounds__(256, 3) void gemm_qkv(
    const unsigned short* __restrict__ A,
    const unsigned short* __restrict__ Bt,
    unsigned short* __restrict__ qh,
    unsigned short* __restrict__ kh,
    unsigned short* __restrict__ vtt)
{
    __shared__ __align__(16) unsigned short As[2][2 * 128 * 32];
    __shared__ __align__(16) unsigned short Bs[2][2 * 64 * 32];

    const int K = 2048;
    const int tid = threadIdx.x;
    const int w = tid >> 6, lane = tid & 63, l15 = lane & 15, quad = lane >> 4;
    const int wm = w & 1, wn = w >> 1;

    const int orig = blockIdx.x + 24 * blockIdx.y;       // [0, 768)
    const int lb = (orig & 7) * 96 + (orig >> 3);
    const int m0 = (lb / 24) * 128, n0 = (lb % 24) * 64;

    const int dsrow = lane >> 2;
    const int dscol = ((lane & 3) ^ ((lane >> 3) & 3)) * 8;
    const int sl8   = (((lane & 15) << 2) | ((lane >> 4) ^ ((lane >> 1) & 3))) * 8;

    f32x4 acc[4][2];
    const f32x4 zero4 = {0.f, 0.f, 0.f, 0.f};
#pragma unroll
    for (int i = 0; i < 4; ++i)
#pragma unroll
        for (int j = 0; j < 2; ++j) acc[i][j] = zero4;

    const unsigned short* AgL = A  + (size_t)(m0 + w * 32 + dsrow) * K + dscol;
    const unsigned short* BgL = Bt + (size_t)(n0 + w * 16 + dsrow) * K + dscol;

    const int NT = K >> 6;
    stage_qkv(AgL, BgL, K, 0, &As[0][0], &Bs[0][0], w);

    int cb = 0;
    for (int t = 0; t < NT; ++t) {
        if (t + 1 < NT) {
            stage_qkv(AgL, BgL, K, (t + 1) * 64, &As[cb ^ 1][0], &Bs[cb ^ 1][0], w);
            VMCNT(6);
        } else {
            VMCNT(0);
        }
        RBAR();

        bf16x8 af[4][2], bf[2][2];
#pragma unroll
        for (int kk = 0; kk < 2; ++kk) {
#pragma unroll
            for (int mt = 0; mt < 4; ++mt)
                af[mt][kk] = *(const bf16x8*)&As[cb][kk * 4096 + (wm * 4 + mt) * 512 + sl8];
#pragma unroll
            for (int nt = 0; nt < 2; ++nt)
                bf[nt][kk] = *(const bf16x8*)&Bs[cb][kk * 2048 + (wn * 2 + nt) * 512 + sl8];
        }
#pragma unroll
        for (int kk = 0; kk < 2; ++kk)
#pragma unroll
            for (int mt = 0; mt < 4; ++mt)
#pragma unroll
                for (int nt = 0; nt < 2; ++nt)
                    acc[mt][nt] = MFMA_BF16(af[mt][kk], bf[nt][kk], acc[mt][nt]);

        if (t + 1 < NT) RBAR();
        cb ^= 1;
    }

    if (n0 < 1024) {            // Q: tanh * cexp -> qh[m][n], pitch 1024
#pragma unroll
        for (int mt = 0; mt < 4; ++mt)
#pragma unroll
            for (int nt = 0; nt < 2; ++nt) {
                const int gn = n0 + wn * 32 + nt * 16 + l15;
#pragma unroll
                for (int r = 0; r < 4; ++r) {
                    const int gm = m0 + wm * 64 + mt * 16 + quad * 4 + r;
                    qh[(size_t)gm * 1024 + gn] = f2b(tanhf(acc[mt][nt][r]) * 0.0225421100f);
                }
            }
    } else if (n0 < 1280) {     // K: tanh -> kh[m][n-1024], pitch 256
#pragma unroll
        for (int mt = 0; mt < 4; ++mt)
#pragma unroll
            for (int nt = 0; nt < 2; ++nt) {
                const int gn = n0 + wn * 32 + nt * 16 + l15 - 1024;
#pragma unroll
                for (int r = 0; r < 4; ++r) {
                    const int gm = m0 + wm * 64 + mt * 16 + quad * 4 + r;
                    kh[(size_t)gm * 256 + gn] = f2b(tanhf(acc[mt][nt][r]));
                }
            }
    } else {                    // V: sigmoid -> vtt[(b*4+g)*64+v][s]
#pragma unroll
        for (int mt = 0; mt < 4; ++mt)
#pragma unroll
            for (int nt = 0; nt < 2; ++nt) {
                const int gn = n0 + wn * 32 + nt * 16 + l15 - 1280;
                const int g = gn >> 6, vv = gn & 63;
                const int s0 = m0 + wm * 64 + mt * 16 + quad * 4;
                const int b = s0 >> 11, sl = s0 & 2047;
                ushort4 pk;
                unsigned short* pp = (unsigned short*)&pk;
#pragma unroll
                for (int r = 0; r < 4; ++r) {
                    float sv = 1.0f / (1.0f + __expf(-acc[mt][nt][r]));
                    pp[r] = f2b(sv);
                }
                *(ushort4*)&vtt[((size_t)(b * 4 + g) * 64 + vv) * 2048 + sl] = pk;
            }
    }
}

// ---------------------------------------------------------------------------
// GEMM 2 (output projection) — R9-proven, unchanged.
// ---------------------------------------------------------------------------
__device__ __forceinline__ void stage_out(const unsigned short* AgL, const unsigned short* BgL,
                                          int K, int k0s,
                                          unsigned short* Asb, unsigned short* Bsb, int w)
{
#pragma unroll
    for (int t = 0; t < 4; ++t) {
        const int sub = t >> 1, half = t & 1;
        gload16(AgL + (size_t)(half * 16) * K + k0s + sub * 32,
                Asb + sub * 4096 + (w * 2 + half) * 512);
        gload16(BgL + (size_t)(half * 16) * K + k0s + sub * 32,
                Bsb + sub * 4096 + (w * 2 + half) * 512);
    }
}

__global__ __launch_bounds__(256, 2) void gemm_out(
    const unsigned short* __restrict__ A,
    const unsigned short* __restrict__ Bt,
    float* __restrict__ Cf)
{
    __shared__ __align__(16) unsigned short As[2][8192];
    __shared__ __align__(16) unsigned short Bs[2][8192];

    const int K = 1024, N = 2048;
    const int tid = threadIdx.x;
    const int w = tid >> 6, lane = tid & 63, l15 = lane & 15, quad = lane >> 4;
    const int wm = w & 1, wn = w >> 1;

    const int orig = blockIdx.x + 16 * blockIdx.y;       // [0, 512)
    const int lb = (orig & 7) * 64 + (orig >> 3);
    const int m0 = (lb >> 4) * 128, n0 = (lb & 15) * 128;

    const int dsrow = lane >> 2;
    const int dscol = ((lane & 3) ^ ((lane >> 3) & 3)) * 8;
    const int sl8   = (((lane & 15) << 2) | ((lane >> 4) ^ ((lane >> 1) & 3))) * 8;

    f32x4 acc[4][4];
    const f32x4 zero4 = {0.f, 0.f, 0.f, 0.f};
#pragma unroll
    for (int i = 0; i < 4; ++i)
#pragma unroll
        for (int j = 0; j < 4; ++j) acc[i][j] = zero4;

    const unsigned short* AgL = A  + (size_t)(m0 + w * 32 + dsrow) * K + dscol;
    const unsigned short* BgL = Bt + (size_t)(n0 + w * 32 + dsrow) * K + dscol;

    const int NT = K >> 6;
    stage_out(AgL, BgL, K, 0, &As[0][0], &Bs[0][0], w);

    int cb = 0;
    for (int t = 0; t < NT; ++t) {
        if (t + 1 < NT) {
            stage_out(AgL, BgL, K, (t + 1) * 64, &As[cb ^ 1][0], &Bs[cb ^ 1][0], w);
            VMCNT(8);
        } else {
            VMCNT(0);
        }
        RBAR();

#pragma unroll
        for (int kk = 0; kk < 2; ++kk) {
            bf16x8 af[4], bf[4];
#pragma unroll
            for (int mt = 0; mt < 4; ++mt)
                af[mt] = *(const bf16x8*)&As[cb][kk * 4096 + (wm * 4 + mt) * 512 + sl8];
#pragma unroll
            for (int nt = 0; nt < 4; ++nt)
                bf[nt] = *(const bf16x8*)&Bs[cb][kk * 4096 + (wn * 4 + nt) * 512 + sl8];
#pragma unroll
            for (int mt = 0; mt < 4; ++mt)
#pragma unroll
                for (int nt = 0; nt < 4; ++nt)
                    acc[mt][nt] = MFMA_BF16(af[mt], bf[nt], acc[mt][nt]);
        }

        if (t + 1 < NT) RBAR();
        cb ^= 1;
    }

#pragma unroll
    for (int mt = 0; mt < 4; ++mt)
#pragma unroll
        for (int nt = 0; nt < 4; ++nt) {
            const int gn = n0 + wn * 64 + nt * 16 + l15;
#pragma unroll
            for (int r = 0; r < 4; ++r) {
                const int gm = m0 + wm * 64 + mt * 16 + quad * 4 + r;
                Cf[(size_t)gm * N + gn] = acc[mt][nt][r];
            }
        }
}

// ---------------------------------------------------------------------------
// MFMA flash attention — R11: TRIPLE-buffered K/V staging -> ONE barrier per
// k-tile (was 2).  With 3 buffers, STAGE(t+1) targets buf[(t+1)%3] whose last
// readers were compute(t-2); every wave crossing iter t-1's barrier already
// finished compute(t-2), so the write-after-read barrier is redundant.
// Barrier events per CU-pair: 66 -> 33.  Per-wave vmcnt: 2 loads/stage,
// <=4 outstanding, VMCNT(2) waits exactly tile t.  Rest identical to R10
// (2 heads/block, 8 waves, shared staging, 32x32 MFMA, in-register P).
// ---------------------------------------------------------------------------
__global__ __launch_bounds__(512, 2) void rosa_attn_mfma(
    const unsigned short* __restrict__ qh,
    const unsigned short* __restrict__ kh,
    const unsigned short* __restrict__ vtt,
    const int* __restrict__ amask,
    const float* __restrict__ emb0,
    const float* __restrict__ emb1,
    unsigned short* __restrict__ ob)
{
    // buf b: K at KVs[b*8192 + row*64 + d], V at KVs[b*8192 + 4096 + row*64 + k]
    __shared__ __align__(16) unsigned short KVs[24576];    // 48 KB (3 bufs); Ored reuses 32 KB
    __shared__ unsigned int Mflg[8];
    __shared__ float Lred[2][2][2][32];                    // [hs][kq][qq][q_loc]

    const int a = blockIdx.x & 7, m = blockIdx.x >> 3;
    const int hp = blockIdx.y, b = blockIdx.z;
    const int g = hp >> 1, jp = hp & 1;
    const int qt0 = (m == 0) ? a : (m == 1) ? 15 - a : (m == 2) ? 16 + a : 31 - a;
    const int qt = b ? (31 - qt0) : qt0;

    const int tid = threadIdx.x;
    const int w = tid >> 6, lane = tid & 63;
    const int hs = w >> 2, kq = (w >> 1) & 1, qq = w & 1;
    const int h = g * 4 + jp * 2 + hs;
    const int l31 = lane & 31, H = lane >> 5, x7 = lane & 7;

    // staging lanes (two-sided XOR swizzle); waves 0-3 -> K, 4-7 -> V
    const int srow = lane >> 3;
    const int scol = ((lane & 7) ^ srow) * 8;
    const int wr = (w & 3) * 16;
    const bool isv = (w >= 4);
    const unsigned short* kst0 = kh + ((size_t)(b * 2048) + wr + srow) * 256 + g * 64 + scol;
    const unsigned short* vst0 = vtt + ((size_t)(b * 4 + g) * 64 + wr + srow) * 2048 + scol;
    const int* mbase = amask + b * 2048;

    // fragment read addresses (elem index, within a buf); row&7 == lane&7
    int kadr[4];
#pragma unroll
    for (int mi = 0; mi < 4; ++mi)
        kadr[mi] = (kq * 32 + l31) * 64 + (((mi * 2 + H) ^ x7) * 8);
    int vadr[2][2];
#pragma unroll
    for (int vh = 0; vh < 2; ++vh)
#pragma unroll
        for (int kc = 0; kc < 2; ++kc)
            vadr[vh][kc] = 4096 + (vh * 32 + l31) * 64 + (((kq * 4 + kc * 2 + H) ^ x7) * 8);

    // causal bitmask for the kq==qq diagonal quadrant
    unsigned int cbits = 0;
#pragma unroll
    for (int r = 0; r < 16; ++r) {
        const int kl = (r & 3) + 8 * (r >> 2) + 4 * H;
        if (kl <= l31) cbits |= (1u << r);
    }

    const int q0 = qt * 64, nkt = qt + 1;

#define STAGE_TILE(k0s, buf)                                                              \
    if (!isv) {                                                                           \
        gload16(kst0 + (size_t)(k0s) * 256,        &KVs[(buf) * 8192 + wr * 64]);         \
        gload16(kst0 + (size_t)(k0s) * 256 + 2048, &KVs[(buf) * 8192 + (wr + 8) * 64]);   \
    } else {                                                                              \
        gload16(vst0 + (k0s),                      &KVs[(buf) * 8192 + 4096 + wr * 64]);  \
        gload16(vst0 + (k0s) + 16384,              &KVs[(buf) * 8192 + 4096 + (wr + 8) * 64]); \
    }

    const int4 mv = *(const int4*)(mbase + tid * 4);       // 512 thr x 4 = 2048

    STAGE_TILE(0, 0)

    // Q fragments (B operand: col=q=lane&31, k=d=(lane>>5)*8+j; cexp folded)
    const unsigned short* qp = qh + ((size_t)(b * 2048 + q0 + qq * 32 + l31) * 16 + h) * 64 + H * 8;
    const bf16x8 qf0 = *(const bf16x8*)(qp);
    const bf16x8 qf1 = *(const bf16x8*)(qp + 16);
    const bf16x8 qf2 = *(const bf16x8*)(qp + 32);
    const bf16x8 qf3 = *(const bf16x8*)(qp + 48);

    // mask chunk-full bitmap: wave w covers chunks 4w..4w+3 (16 lanes each)
    const bool f8 = mv.x && mv.y && mv.z && mv.w;
    const unsigned long long bal = __ballot(f8);
    bool cf = false;
    if (lane < 4) cf = ((bal >> (lane * 16)) & 0xFFFFull) == 0xFFFFull;
    const unsigned int wb = (unsigned int)(__ballot((lane < 4) && cf) & 0xFull);
    if (lane == 0) Mflg[w] = wb;
    RBAR();
    unsigned int mflags = 0;
#pragma unroll
    for (int i = 0; i < 8; ++i) mflags |= Mflg[i] << (i * 4);

    const f32x16 z16 = {0.f,0.f,0.f,0.f, 0.f,0.f,0.f,0.f, 0.f,0.f,0.f,0.f, 0.f,0.f,0.f,0.f};
    f32x16 oacc0 = z16, oacc1 = z16;
    float psum = 0.0f;
    const bool skipdiag = (kq > qq);

    int cb = 0;
    for (int kt = 0; kt < nkt; ++kt) {
        const int nb = (cb == 2) ? 0 : cb + 1;
        if (kt + 1 < nkt) {
            STAGE_TILE((kt + 1) * 64, nb)
            VMCNT(2);              // tile kt's 2 loads landed; tile kt+1 in flight
        } else {
            VMCNT(0);
        }
        RBAR();                    // the ONLY barrier per k-tile

        const bool diag = (kt == qt);
        if (!(diag && skipdiag)) {
            // ---- QK^T quadrant: sc = S^T[k_loc][q], col=q=lane&31
            const bf16x8 kf0 = *(const bf16x8*)&KVs[cb * 8192 + kadr[0]];
            const bf16x8 kf1 = *(const bf16x8*)&KVs[cb * 8192 + kadr[1]];
            const bf16x8 kf2 = *(const bf16x8*)&KVs[cb * 8192 + kadr[2]];
            const bf16x8 kf3 = *(const bf16x8*)&KVs[cb * 8192 + kadr[3]];
            __builtin_amdgcn_s_setprio(1);
            f32x16 sc = MFMA32(kf0, qf0, z16);
            sc = MFMA32(kf1, qf1, sc);
            sc = MFMA32(kf2, qf2, sc);
            sc = MFMA32(kf3, qf3, sc);
            __builtin_amdgcn_s_setprio(0);

            // ---- softmax numerators (cexp pre-folded into qh)
            float p[16];
#pragma unroll
            for (int r = 0; r < 16; ++r) p[r] = __builtin_exp2f(sc[r]);
            if (diag && kq == qq) {
#pragma unroll
                for (int r = 0; r < 16; ++r)
                    if (!((cbits >> r) & 1u)) p[r] = 0.0f;
            }
            if (!((mflags >> kt) & 1u)) {      // padded-mask slow path
#pragma unroll
                for (int r = 0; r < 16; ++r) {
                    const int kgl = kt * 64 + kq * 32 + (r & 3) + 8 * (r >> 2) + 4 * H;
                    if (mbase[kgl] == 0) p[r] = 0.0f;
                }
            }
            psum += (((p[0]+p[1])+(p[2]+p[3])) + ((p[4]+p[5])+(p[6]+p[7])))
                  + (((p[8]+p[9])+(p[10]+p[11])) + ((p[12]+p[13])+(p[14]+p[15])));

            // ---- P -> PV A-operand, entirely in registers
            unsigned int W0 = cvtpk(p[0],  p[1]),  W1 = cvtpk(p[2],  p[3]);
            unsigned int W2 = cvtpk(p[4],  p[5]),  W3 = cvtpk(p[6],  p[7]);
            unsigned int W4 = cvtpk(p[8],  p[9]),  W5 = cvtpk(p[10], p[11]);
            unsigned int W6 = cvtpk(p[12], p[13]), W7 = cvtpk(p[14], p[15]);
            PERMSWAP(W0, W2);  PERMSWAP(W1, W3);
            PERMSWAP(W4, W6);  PERMSWAP(W5, W7);
            u32x4 paw0; paw0[0] = W0; paw0[1] = W1; paw0[2] = W2; paw0[3] = W3;
            u32x4 paw1; paw1[0] = W4; paw1[1] = W5; paw1[2] = W6; paw1[3] = W7;
            const bf16x8 pa0 = __builtin_bit_cast(bf16x8, paw0);
            const bf16x8 pa1 = __builtin_bit_cast(bf16x8, paw1);

            // ---- PV: O[q][v] partial for this wave's k-range
            const bf16x8 vb00 = *(const bf16x8*)&KVs[cb * 8192 + vadr[0][0]];
            const bf16x8 vb01 = *(const bf16x8*)&KVs[cb * 8192 + vadr[0][1]];
            const bf16x8 vb10 = *(const bf16x8*)&KVs[cb * 8192 + vadr[1][0]];
            const bf16x8 vb11 = *(const bf16x8*)&KVs[cb * 8192 + vadr[1][1]];
            __builtin_amdgcn_s_setprio(1);
            oacc0 = MFMA32(pa0, vb00, oacc0);
            oacc0 = MFMA32(pa1, vb01, oacc0);
            oacc1 = MFMA32(pa0, vb10, oacc1);
            oacc1 = MFMA32(pa1, vb11, oacc1);
            __builtin_amdgcn_s_setprio(0);
        }

        cb = nb;                   // rotate; no second barrier
    }

    // ---- l: combine lane halves (lanes l, l^32 hold same q, disjoint k)
    psum += __shfl_xor(psum, 32);

    RBAR();                         // all K/V reads done -> reuse KVs as Ored

    if (H == 0) Lred[hs][kq][qq][l31] = psum;

    // O partial exchange within head hs: keep vh=kq, ship vh=1-kq
    float* Ored = (float*)&KVs[0] + hs * 4096;     // 16 KB per head (bufs 0-1)
    const int slw = qq * 2 + (1 - kq);
    const int cx = (lane & 3) ^ ((lane >> 2) & 3);
    if (kq == 0) {
#pragma unroll
        for (int c = 0; c < 4; ++c) {
            float4 t = {oacc1[c*4+0], oacc1[c*4+1], oacc1[c*4+2], oacc1[c*4+3]};
            *(float4*)&Ored[slw * 1024 + lane * 16 + ((c ^ cx) * 4)] = t;
        }
    } else {
#pragma unroll
        for (int c = 0; c < 4; ++c) {
            float4 t = {oacc0[c*4+0], oacc0[c*4+1], oacc0[c*4+2], oacc0[c*4+3]};
            *(float4*)&Ored[slw * 1024 + lane * 16 + ((c ^ cx) * 4)] = t;
        }
    }
    RBAR();

    const int slr = qq * 2 + kq;
    f32x16 osum = (kq == 0) ? oacc0 : oacc1;
#pragma unroll
    for (int c = 0; c < 4; ++c) {
        float4 t = *(const float4*)&Ored[slr * 1024 + lane * 16 + ((c ^ cx) * 4)];
        osum[c*4+0] += t.x; osum[c*4+1] += t.y; osum[c*4+2] += t.z; osum[c*4+3] += t.w;
    }

    float rl[16];
#pragma unroll
    for (int r = 0; r < 16; ++r) {
        const int ql = (r & 3) + 8 * (r >> 2) + 4 * H;
        rl[r] = __builtin_amdgcn_rcpf(Lred[hs][0][qq][ql] + Lred[hs][1][qq][ql]);
    }

    // epilogue: lane holds v = kq*32 + l31 (fixed), q per reg -> coalesced
    const int vg = kq * 32 + l31;
    const float e0 = emb0[h * 64 + vg];
    const float ed = emb1[h * 64 + vg] - e0;
    unsigned short* obp = ob + ((size_t)(b * 2048 + q0 + qq * 32) * 16 + h) * 64 + vg;
#pragma unroll
    for (int r = 0; r < 16; ++r) {
        const int ql = (r & 3) + 8 * (r >> 2) + 4 * H;
        const float val = e0 + (osum[r] * rl[r]) * ed;
        obp[(size_t)ql * 1024] = f2b(val);
    }
#undef STAGE_TILE
}

// ---------------------------------------------------------------------------
extern "C" void kernel_launch(void* const* d_in, const int* in_sizes, int n_in,
                              void* d_out, int out_size, void* d_ws, size_t ws_size,
                              hipStream_t stream)
{
    const float* x    = (const float*)d_in[0];
    const int*   amask= (const int*)d_in[1];
    const float* Wq   = (const float*)d_in[2];
    const float* Wk   = (const float*)d_in[3];
    const float* Wv   = (const float*)d_in[4];
    const float* Wo   = (const float*)d_in[5];
    const float* emb0 = (const float*)d_in[6];
    const float* emb1 = (const float*)d_in[7];
    float* out = (float*)d_out;

    char* base = (char*)d_ws;
    unsigned short* xh    = (unsigned short*)(base);                      // 16 MB
    unsigned short* ob    = xh;                                           // aliases xh
    unsigned short* Wqkvt = (unsigned short*)(base + (16u << 20));        // 6 MB
    unsigned short* Wot   = (unsigned short*)(base + (22u << 20));        // 4 MB
    unsigned short* qh    = (unsigned short*)(base + (26u << 20));        // 8 MB
    unsigned short* kh    = (unsigned short*)(base + (34u << 20));        // 2 MB
    unsigned short* vtt   = (unsigned short*)(base + (36u << 20));        // 2 MB

    prep<<<7168, 256, 0, stream>>>(x, xh, Wq, Wk, Wv, Wqkvt, Wo, Wot);

    gemm_qkv<<<dim3(24, 32), 256, 0, stream>>>(xh, Wqkvt, qh, kh, vtt);
    rosa_attn_mfma<<<dim3(32, 8, 2), 512, 0, stream>>>(qh, kh, vtt, amask, emb0, emb1, ob);
    gemm_out<<<dim3(16, 32), 256, 0, stream>>>(ob, Wot, out);
}